// Round 6
// baseline (464.774 us; speedup 1.0000x reference)
//
#include <hip/hip_runtime.h>
#include <hip/hip_bf16.h>

typedef __hip_bfloat16 bf16;
typedef unsigned short u16;
typedef __attribute__((ext_vector_type(8))) short s8;   // 8 bf16 = one MFMA A/B fragment
typedef __attribute__((ext_vector_type(4))) float f4;   // MFMA C/D fragment

#define NRUNS 3
#define NTREE 128
#define TT    255
#define DD    256
#define VPAD  10016    /* vocab padded to 32 */
#define PAD   258      /* LDS row stride in u16 for 256-wide rows */
#define OPAD  264      /* output-staging stride: uint4-aligned (528B), bank-staggered */

__device__ __forceinline__ float bits2f(u16 b){ union{unsigned u; float f;} x; x.u = ((unsigned)b)<<16; return x.f; }
__device__ __forceinline__ u16   f2bits(float f){ bf16 h = __float2bfloat16(f); return *(u16*)&h; }
__device__ __forceinline__ float sigm(float x){ return 1.f/(1.f+__expf(-x)); }
__device__ __forceinline__ float tanh_(float x){ return 1.f - 2.f/(__expf(2.f*x)+1.f); }

// ---------------- dtype autodetect (proven) ----------------
__global__ void k_detect(const u16* __restrict__ raw, int* __restrict__ flag){
    int t = threadIdx.x;
    int hit = 0;
    if (t < 128){
        u16 w = raw[2*t];
        int e = (w >> 7) & 0xFF;
        hit = (e >= 100 && e <= 141) ? 1 : 0;
    }
    __shared__ int cnt;
    if (t == 0) cnt = 0;
    __syncthreads();
    atomicAdd(&cnt, hit);
    __syncthreads();
    if (t == 0) flag[0] = (cnt >= 64) ? 1 : 0;
}

__device__ __forceinline__ u16 cvt1b(const void* p, int i, int isb){
    return isb ? ((const u16*)p)[i] : f2bits(((const float*)p)[i]);
}
__device__ __forceinline__ float cvt1f(const void* p, int i, int isb){
    return isb ? bits2f(((const u16*)p)[i]) : ((const float*)p)[i];
}

// fused any->bf16 conversion: emb (zero-padded to VPAD rows) + 4 weights
#define L_EMB  (10000*256)
#define L_EMBP (VPAD*256)
#define L_WIOU (768*256)
#define L_UIOU (768*256)
#define L_WF   (256*256)
#define L_UF   (256*256)
#define L_ALL  (L_EMBP + L_WIOU + L_UIOU + L_WF + L_UF)
__global__ void k_cvtb(const void* __restrict__ s0, const void* __restrict__ s1,
                       const void* __restrict__ s2, const void* __restrict__ s3,
                       const void* __restrict__ s4,
                       u16* __restrict__ d0, u16* __restrict__ d1, u16* __restrict__ d2,
                       u16* __restrict__ d3, u16* __restrict__ d4,
                       const int* __restrict__ flag){
    int isb = flag[0];
    for (int i = blockIdx.x*blockDim.x + threadIdx.x; i < L_ALL; i += gridDim.x*blockDim.x){
        int j = i;
        if (j < L_EMBP){ d0[j] = (j < L_EMB) ? cvt1b(s0, j, isb) : (u16)0; continue; } j -= L_EMBP;
        if (j < L_WIOU){ d1[j] = cvt1b(s1, j, isb); continue; } j -= L_WIOU;
        if (j < L_UIOU){ d2[j] = cvt1b(s2, j, isb); continue; } j -= L_UIOU;
        if (j < L_WF){ d3[j] = cvt1b(s3, j, isb); continue; } j -= L_WF;
        d4[j] = cvt1b(s4, j, isb);
    }
}

// fused any->f32 conversion of biases + FC weights
#define S_BIOU 768
#define S_BF   256
#define S_F1W  (128*256)
#define S_F1B  128
#define S_F2W  (3*128)
#define S_F2B  3
#define S_ALL  (S_BIOU+S_BF+S_F1W+S_F1B+S_F2W+S_F2B)
__global__ void k_small(const void* __restrict__ s0, const void* __restrict__ s1,
                        const void* __restrict__ s2, const void* __restrict__ s3,
                        const void* __restrict__ s4, const void* __restrict__ s5,
                        float* __restrict__ d0, float* __restrict__ d1, float* __restrict__ d2,
                        float* __restrict__ d3, float* __restrict__ d4, float* __restrict__ d5,
                        const int* __restrict__ flag){
    int isb = flag[0];
    for (int i = blockIdx.x*blockDim.x + threadIdx.x; i < S_ALL; i += gridDim.x*blockDim.x){
        int j = i;
        if (j < S_BIOU){ d0[j] = cvt1f(s0, j, isb); continue; } j -= S_BIOU;
        if (j < S_BF){ d1[j] = cvt1f(s1, j, isb); continue; } j -= S_BF;
        if (j < S_F1W){ d2[j] = cvt1f(s2, j, isb); continue; } j -= S_F1W;
        if (j < S_F1B){ d3[j] = cvt1f(s3, j, isb); continue; } j -= S_F1B;
        if (j < S_F2W){ d4[j] = cvt1f(s4, j, isb); continue; } j -= S_F2W;
        d5[j] = cvt1f(s5, j, isb);
    }
}

__device__ __forceinline__ s8 ldB16(const u16* p){
    union { uint4 q; s8 v; } u;
    u.q = *(const uint4*)p;
    return u.v;
}
__device__ __forceinline__ s8 ldsA(const u16* p){
    union { unsigned w[4]; s8 v; } u;
    u.w[0] = *(const unsigned*)(p);
    u.w[1] = *(const unsigned*)(p+2);
    u.w[2] = *(const unsigned*)(p+4);
    u.w[3] = *(const unsigned*)(p+6);
    return u.v;
}
#define MFMA(acc,a,b) acc = __builtin_amdgcn_mfma_f32_16x16x32_bf16(a, b, acc, 0, 0, 0)

// ---------------- vocab-space precompute (packed E4[vocab][256][4] = {i,o,u,f}) ----------------
__global__ __launch_bounds__(512, 4)
void k_vocab2(const u16* __restrict__ embb,
              const u16* __restrict__ Wiou, const u16* __restrict__ Wfm,
              const u16* __restrict__ Ufm,  const float* __restrict__ biou_f,
              u16* __restrict__ E4, u16* __restrict__ E_f,
              u16* __restrict__ H0, u16* __restrict__ C0, u16* __restrict__ HU0)
{
    __shared__ u16 hs[32*PAD];    // h0 for the HU0 GEMM
    const int t = threadIdx.x, w = t>>6, lane = t&63, ln = lane&15, q = lane>>4;
    const int r0 = blockIdx.x*32, d0 = w*32;

    const u16* Bp[8];
    #pragma unroll
    for (int g = 0; g < 4; g++)
      #pragma unroll
      for (int nc = 0; nc < 2; nc++){
        int nn = d0 + nc*16 + ln;
        Bp[g*2+nc] = (g < 3) ? (Wiou + (size_t)(g*256+nn)*DD) : (Wfm + (size_t)nn*DD);
      }
    const u16* a0p = embb + (size_t)(r0+ln)*DD;
    const u16* a1p = embb + (size_t)(r0+16+ln)*DD;
    f4 acc[8][2];
    #pragma unroll
    for (int nt = 0; nt < 8; nt++){ acc[nt][0] = (f4){0,0,0,0}; acc[nt][1] = (f4){0,0,0,0}; }
    #pragma unroll 2
    for (int ks = 0; ks < 8; ks++){
        int ko = ks*32 + q*8;
        s8 a0 = ldB16(a0p + ko);
        s8 a1 = ldB16(a1p + ko);
        #pragma unroll
        for (int nt = 0; nt < 8; nt++){
            s8 bb = ldB16(Bp[nt] + ko);
            MFMA(acc[nt][0], a0, bb);
            MFMA(acc[nt][1], a1, bb);
        }
    }
    #pragma unroll
    for (int nc = 0; nc < 2; nc++){
        int d = d0 + nc*16 + ln;
        float bi = biou_f[d], bo = biou_f[256+d], bu = biou_f[512+d];
        #pragma unroll
        for (int ms = 0; ms < 2; ms++)
          #pragma unroll
          for (int r = 0; r < 4; r++){
            int vrow = r0 + ms*16 + q*4 + r;
            float ei = acc[0*2+nc][ms][r];
            float eo = acc[1*2+nc][ms][r];
            float eu = acc[2*2+nc][ms][r];
            float ef = acc[3*2+nc][ms][r];
            union { u16 a[4]; uint2 q2; } pk;
            pk.a[0] = f2bits(ei);
            pk.a[1] = f2bits(eo);
            pk.a[2] = f2bits(eu);
            pk.a[3] = f2bits(ef);
            *(uint2*)(E4 + ((size_t)vrow*DD + d)*4) = pk.q2;
            E_f[(size_t)vrow*DD + d] = f2bits(ef);
            float cc = sigm(ei + bi)*tanh_(eu + bu);
            float hh = sigm(eo + bo)*tanh_(cc);
            C0[(size_t)vrow*DD + d] = f2bits(cc);
            H0[(size_t)vrow*DD + d] = f2bits(hh);
            hs[(ms*16 + q*4 + r)*PAD + d] = f2bits(hh);
        }
    }
    __syncthreads();

    f4 hacc[2][2];
    #pragma unroll
    for (int nt = 0; nt < 2; nt++){ hacc[nt][0] = (f4){0,0,0,0}; hacc[nt][1] = (f4){0,0,0,0}; }
    const u16* Bf0 = Ufm + (size_t)(d0 + ln)*DD;
    const u16* Bf1 = Ufm + (size_t)(d0 + 16 + ln)*DD;
    #pragma unroll 2
    for (int ks = 0; ks < 8; ks++){
        int ko = ks*32 + q*8;
        s8 a0 = ldsA(&hs[ln*PAD + ko]);
        s8 a1 = ldsA(&hs[(16+ln)*PAD + ko]);
        s8 b0 = ldB16(Bf0 + ko);
        s8 b1 = ldB16(Bf1 + ko);
        MFMA(hacc[0][0], a0, b0); MFMA(hacc[0][1], a1, b0);
        MFMA(hacc[1][0], a0, b1); MFMA(hacc[1][1], a1, b1);
    }
    #pragma unroll
    for (int nc = 0; nc < 2; nc++){
        int d = d0 + nc*16 + ln;
        #pragma unroll
        for (int ms = 0; ms < 2; ms++)
          #pragma unroll
          for (int r = 0; r < 4; r++){
            int vrow = r0 + ms*16 + q*4 + r;
            HU0[(size_t)vrow*DD + d] = f2bits(hacc[nc][ms][r]);
        }
    }
}

// ---------------- k_edge0: assemble lvl-1 inputs from vocab tables (proven) ----------------
__global__ __launch_bounds__(512, 4)
void k_edge0(const int* __restrict__ f0, const int* __restrict__ f1, const int* __restrict__ f2,
             const u16* __restrict__ E_f, const u16* __restrict__ H0,
             const u16* __restrict__ C0,  const u16* __restrict__ HU0,
             const float* __restrict__ bf_f,
             u16* __restrict__ hsum_out, u16* __restrict__ fcsum_out)
{
    int gid = blockIdx.x*512 + threadIdx.x;
    int row = gid >> 5, ch = gid & 31, d = ch*8;
    int run = row >> 13, rem = row & 8191, b = rem >> 6, jj = rem & 63;
    const int* fp = (run==0) ? f0 : ((run==1) ? f1 : f2);
    int fo = fp[b*TT + 128 + jj];
    int v1 = fp[b*TT + 2*jj];
    int v2 = fp[b*TT + 2*jj + 1];
    s8 ef  = ldB16(E_f + (size_t)fo*DD + d);
    s8 hu1 = ldB16(HU0 + (size_t)v1*DD + d);
    s8 hu2 = ldB16(HU0 + (size_t)v2*DD + d);
    s8 c1  = ldB16(C0  + (size_t)v1*DD + d);
    s8 c2  = ldB16(C0  + (size_t)v2*DD + d);
    s8 h1  = ldB16(H0  + (size_t)v1*DD + d);
    s8 h2  = ldB16(H0  + (size_t)v2*DD + d);
    union { u16 a[8]; uint4 q4; } uh, uf;
    #pragma unroll
    for (int j = 0; j < 8; j++){
        float e  = bits2f((u16)ef[j]) + bf_f[d+j];
        float fa = sigm(e + bits2f((u16)hu1[j]));
        float fb = sigm(e + bits2f((u16)hu2[j]));
        float fc = fa*bits2f((u16)c1[j]) + fb*bits2f((u16)c2[j]);
        float hsv = bits2f((u16)h1[j]) + bits2f((u16)h2[j]);
        uf.a[j] = f2bits(fc);
        uh.a[j] = f2bits(hsv);
    }
    *(uint4*)(hsum_out  + (size_t)row*DD + d) = uh.q4;
    *(uint4*)(fcsum_out + (size_t)row*DD + d) = uf.q4;
}

// ---------------- per-level kernel (v7: E4 register-prefetch before GEMM-U) ----------------
// R5 confirmed spill-free (512,4): lvl-1 81 us, FETCH 42 MB, WRITE 12.3 MB (logical).
// Residual: latency-bound (MfmaUtil 6%, HBM 8.5%) -- the epilogue's 16 E4 gather
// loads are consumed a few instrs after issue with only ~12 waves/CU to hide them.
// Fix: issue all 16 uint2 E4 loads right after the first barrier, hold in regs
// across GEMM-U (static indices -> VGPRs). +32 VGPR => ~160 unified regs/wave,
// needs (512,3) [~170 budget] to avoid R2's forced-spill failure mode. 3 waves/SIMD
// = the 37% occupancy we already measure, so nothing is traded away.
__global__ __launch_bounds__(512, 3)
void k_lvl(int lvl, int cLog,
           const int* __restrict__ f0, const int* __restrict__ f1, const int* __restrict__ f2,
           const u16* __restrict__ E4, const u16* __restrict__ E_f,
           const u16* __restrict__ Uiou, const u16* __restrict__ Ufm,
           const float* __restrict__ biou_f, const float* __restrict__ bf_f,
           const u16* __restrict__ hsum_in, const u16* __restrict__ fcsum_in,
           u16* __restrict__ hsum_out, u16* __restrict__ fcsum_out,
           u16* __restrict__ hroot)
{
    __shared__ u16 hs[32*PAD];     // 16.5 KB: h transpose for GEMM-C
    __shared__ u16 hso[16*OPAD];   // 8.4 KB: staged hsum_out rows
    __shared__ u16 fco[16*OPAD];   // 8.4 KB: staged fcsum_out rows
    __shared__ int sfr[32];        // this block's 32 node feats (epilogue E4 rows)
    const int t = threadIdx.x, w = t>>6, lane = t&63, ln = lane&15, q = lane>>4;
    const int cnt = 1 << cLog, S = 256 - 2*cnt;
    const int r0 = blockIdx.x*32, d0 = w*32;
    const bool haveP = (lvl < 7);

    // ---- stage this block's 32 node feats into LDS (128 B) ----
    if (t < 32){
        int rho = r0 + t;
        int run = rho >> (7+cLog);
        int rem = rho & ((1<<(7+cLog)) - 1);
        int b = rem >> cLog, jj = rem & (cnt-1);
        const int* fp = (run==0) ? f0 : ((run==1) ? f1 : f2);
        sfr[t] = fp[b*TT + S + jj];
    }

    // parent feats for GEMM-C epilogue
    int featp[2][2];
    if (haveP){
        #pragma unroll
        for (int ms = 0; ms < 2; ms++)
          #pragma unroll
          for (int rr = 0; rr < 2; rr++){
            int rho = r0 + ms*16 + q*4 + rr*2;
            int run = rho >> (7+cLog);
            int rem = rho & ((1<<(7+cLog)) - 1);
            int b = rem >> cLog, jj = rem & (cnt-1);
            const int* fp = (run==0) ? f0 : ((run==1) ? f1 : f2);
            featp[ms][rr] = fp[b*TT + (256-cnt) + (jj>>1)];
          }
    }
    __syncthreads();   // sfr visible to all

    // ---- prefetch ALL 16 E4 gathers into registers (latency hides under GEMM-U) ----
    uint2 epf[2][2][4];   // [nc][ms][r] -- fully unrolled static indexing => VGPRs
    #pragma unroll
    for (int nc = 0; nc < 2; nc++){
        int d = d0 + nc*16 + ln;
        #pragma unroll
        for (int ms = 0; ms < 2; ms++)
          #pragma unroll
          for (int r = 0; r < 4; r++){
            int m = ms*16 + q*4 + r;
            epf[nc][ms][r] = *(const uint2*)(E4 + ((size_t)sfr[m]*DD + d)*4);
          }
    }

    // ---- GEMM-U: hsum_in @ Uiou^T ----
    f4 acc[6][2];
    #pragma unroll
    for (int nt = 0; nt < 6; nt++){ acc[nt][0] = (f4){0,0,0,0}; acc[nt][1] = (f4){0,0,0,0}; }
    {
        const u16* a0p = hsum_in + (size_t)(r0+ln)*DD;
        const u16* a1p = hsum_in + (size_t)(r0+16+ln)*DD;
        const u16* Bp[6];
        #pragma unroll
        for (int nt = 0; nt < 6; nt++){
            int n = (nt>>1)*256 + d0 + (nt&1)*16 + ln;
            Bp[nt] = Uiou + (size_t)n*DD;
        }
        #pragma unroll 2
        for (int ks = 0; ks < 8; ks++){
            int ko = ks*32 + q*8;
            s8 a0 = ldB16(a0p + ko);
            s8 a1 = ldB16(a1p + ko);
            #pragma unroll
            for (int nt = 0; nt < 6; nt++){
                s8 bb = ldB16(Bp[nt] + ko);
                MFMA(acc[nt][0], a0, bb);
                MFMA(acc[nt][1], a1, bb);
            }
        }
    }

    // ---- epilogue: cell update from prefetched E4 regs ----
    float cv[2][2][4];
    #pragma unroll
    for (int nc = 0; nc < 2; nc++){
        int d = d0 + nc*16 + ln;
        float bi = biou_f[d], bo = biou_f[256+d], bu = biou_f[512+d];
        #pragma unroll
        for (int ms = 0; ms < 2; ms++){
            float hv[4];
            #pragma unroll
            for (int r = 0; r < 4; r++){
                int m   = ms*16 + q*4 + r;
                int rho = r0 + m;
                union { uint2 q2; u16 a[4]; } ev;
                ev.q2 = epf[nc][ms][r];
                float iv = acc[0+nc][ms][r] + bits2f(ev.a[0]) + bi;
                float ov = acc[2+nc][ms][r] + bits2f(ev.a[1]) + bo;
                float uv = acc[4+nc][ms][r] + bits2f(ev.a[2]) + bu;
                float cs = bits2f(fcsum_in[(size_t)rho*DD + d]);
                float c = sigm(iv)*tanh_(uv) + cs;
                float h = sigm(ov)*tanh_(c);
                cv[nc][ms][r] = c;
                hv[r] = h;
                if (haveP) hs[m*PAD + d] = f2bits(h);
                else       hroot[(size_t)rho*DD + d] = f2bits(h);
            }
            if (haveP){
                int lr = ms*8 + q*2;
                hso[lr*OPAD + d]     = f2bits(hv[0] + hv[1]);
                hso[(lr+1)*OPAD + d] = f2bits(hv[2] + hv[3]);
            }
        }
    }

    // ---- GEMM-C: hU = h@Uf^T, fc = sig(E_f[parent]+bf+hU)*c, pair-reduce ----
    if (haveP){
        __syncthreads();
        f4 hacc[2][2];
        #pragma unroll
        for (int nt = 0; nt < 2; nt++){ hacc[nt][0] = (f4){0,0,0,0}; hacc[nt][1] = (f4){0,0,0,0}; }
        const u16* Bf0 = Ufm + (size_t)(d0 + ln)*DD;
        const u16* Bf1 = Ufm + (size_t)(d0 + 16 + ln)*DD;
        #pragma unroll 2
        for (int ks = 0; ks < 8; ks++){
            int ko = ks*32 + q*8;
            s8 a0 = ldsA(&hs[ln*PAD + ko]);
            s8 a1 = ldsA(&hs[(16+ln)*PAD + ko]);
            s8 b0 = ldB16(Bf0 + ko);
            s8 b1 = ldB16(Bf1 + ko);
            MFMA(hacc[0][0], a0, b0); MFMA(hacc[0][1], a1, b0);
            MFMA(hacc[1][0], a0, b1); MFMA(hacc[1][1], a1, b1);
        }
        #pragma unroll
        for (int nc = 0; nc < 2; nc++){
            int d = d0 + nc*16 + ln;
            float bfv = bf_f[d];
            #pragma unroll
            for (int ms = 0; ms < 2; ms++){
                float fs0, fs1;
                #pragma unroll
                for (int r = 0; r < 4; r++){
                    float ef = bits2f(E_f[(size_t)featp[ms][r>>1]*DD + d]);
                    float fc = sigm(ef + bfv + hacc[nc][ms][r]) * cv[nc][ms][r];
                    if (r == 0) fs0 = fc;
                    else if (r == 1) fs0 += fc;
                    else if (r == 2) fs1 = fc;
                    else fs1 += fc;
                }
                int lr = ms*8 + q*2;
                fco[lr*OPAD + d]     = f2bits(fs0);
                fco[(lr+1)*OPAD + d] = f2bits(fs1);
            }
        }

        // ---- single coalesced write pass: full 128B lines, written once ----
        __syncthreads();
        {
            int row = t >> 5, c = (t & 31) * 8;
            int prow = (r0 >> 1) + row;
            uint4 vh = *(const uint4*)&hso[row*OPAD + c];
            uint4 vf = *(const uint4*)&fco[row*OPAD + c];
            *(uint4*)(hsum_out  + (size_t)prow*DD + c) = vh;
            *(uint4*)(fcsum_out + (size_t)prow*DD + c) = vf;
        }
    }
}

// ---------------- final: bilinear combine + MLP (proven epilogue) ----------------
__global__ __launch_bounds__(256)
void k_final(const u16* __restrict__ hroot,
             const float* __restrict__ fc1w, const float* __restrict__ fc1b,
             const float* __restrict__ fc2w, const float* __restrict__ fc2b,
             void* __restrict__ out, const int* __restrict__ flag)
{
    int b = blockIdx.x, t = threadIdx.x;
    __shared__ float sprod[DD];
    __shared__ float shb[DD];
    __shared__ float shid[128];
    float hc  = bits2f(hroot[(0*NTREE + b)*DD + t]);
    float ha  = bits2f(hroot[(1*NTREE + b)*DD + t]);
    float hbv = bits2f(hroot[(2*NTREE + b)*DD + t]);
    sprod[t] = hc * ha;
    shb[t]   = hbv;
    __syncthreads();
    for (int s = 128; s > 0; s >>= 1){
        if (t < s) sprod[t] += sprod[t + s];
        __syncthreads();
    }
    float dot = sprod[0];
    if (t < 128){
        float acc = fc1b[t];
        for (int k = 0; k < DD; k++)
            acc = fmaf(dot * shb[k], fc1w[t*DD + k], acc);
        shid[t] = fmaxf(acc, 0.f);
    }
    __syncthreads();
    if (t < 3){
        float acc = fc2b[t];
        for (int j = 0; j < 128; j++)
            acc = fmaf(fc2w[t*128 + j], shid[j], acc);
        float v = fmaxf(acc, 0.f);
        if (flag[0]) ((bf16*)out)[b*3 + t] = __float2bfloat16(v);
        else         ((float*)out)[b*3 + t] = v;
    }
}

extern "C" void kernel_launch(void* const* d_in, const int* in_sizes, int n_in,
                              void* d_out, int out_size, void* d_ws, size_t ws_size,
                              hipStream_t stream)
{
    const int* f0 = (const int*)d_in[0];
    const int* f1 = (const int*)d_in[1];
    const int* f2 = (const int*)d_in[2];
    // d_in[3..7] static forest metadata — unused (structure compile-time known)
    const void* emb  = d_in[8];
    const void* Wiou = d_in[9];
    const void* biou = d_in[10];
    const void* Uiou = d_in[11];
    const void* Wf   = d_in[12];
    const void* bfv  = d_in[13];
    const void* Uf   = d_in[14];
    const void* fc1w = d_in[15];
    const void* fc1b = d_in[16];
    const void* fc2w = d_in[17];
    const void* fc2b = d_in[18];

    char* base = (char*)d_ws;
    size_t off = 0;
    auto take = [&](size_t bytes) -> char* {
        char* p = base + off;
        off = (off + bytes + 255) & ~(size_t)255;
        return p;
    };
    int*   flag   = (int*)  take(256);
    u16*   embb   = (u16*)  take((size_t)L_EMBP*2);
    u16*   wioub  = (u16*)  take((size_t)L_WIOU*2);
    u16*   uioub  = (u16*)  take((size_t)L_UIOU*2);
    u16*   wfb    = (u16*)  take((size_t)L_WF*2);
    u16*   ufb    = (u16*)  take((size_t)L_UF*2);
    float* biou_f = (float*)take(S_BIOU*4);
    float* bf_f   = (float*)take(S_BF*4);
    float* fc1w_f = (float*)take(S_F1W*4);
    float* fc1b_f = (float*)take(S_F1B*4);
    float* fc2w_f = (float*)take(S_F2W*4);
    float* fc2b_f = (float*)take(S_F2B*4);
    u16*   E4     = (u16*)  take((size_t)VPAD*DD*4*2);     // 20.5 MB packed {i,o,u,f}
    u16*   E_f    = (u16*)  take((size_t)VPAD*DD*2);       // 5.13 MB
    u16*   H0     = (u16*)  take((size_t)VPAD*DD*2);
    u16*   C0     = (u16*)  take((size_t)VPAD*DD*2);
    u16*   HU0    = (u16*)  take((size_t)VPAD*DD*2);
    u16*   HA     = (u16*)  take((size_t)24576*DD*2);
    u16*   HB     = (u16*)  take((size_t)12288*DD*2);
    u16*   FA     = (u16*)  take((size_t)24576*DD*2);
    u16*   FB     = (u16*)  take((size_t)12288*DD*2);
    u16*   hroot  = (u16*)  take((size_t)NRUNS*NTREE*DD*2);
    // total ~85 MB (< proven 119 MB)

    k_detect<<<1, 256, 0, stream>>>((const u16*)emb, flag);
    k_cvtb<<<2048, 256, 0, stream>>>(emb, Wiou, Uiou, Wf, Uf,
                                     embb, wioub, uioub, wfb, ufb, flag);
    k_small<<<135, 256, 0, stream>>>(biou, bfv, fc1w, fc1b, fc2w, fc2b,
                                     biou_f, bf_f, fc1w_f, fc1b_f, fc2w_f, fc2b_f, flag);
    k_vocab2<<<VPAD/32, 512, 0, stream>>>(embb, wioub, wfb, ufb, biou_f,
                                          E4, E_f, H0, C0, HU0);
    k_edge0<<<24576*32/512, 512, 0, stream>>>(f0, f1, f2, E_f, H0, C0, HU0, bf_f, HA, FA);

    for (int lvl = 1; lvl <= 7; lvl++){
        int cLog = 7 - lvl;
        int rows = NRUNS*NTREE*(128 >> lvl);
        int blocks = rows / 32;
        int pe = lvl & 1;
        u16* hs_o = pe ? HB : HA;
        u16* fc_o = pe ? FB : FA;
        const u16* hs_i = pe ? HA : HB;
        const u16* fc_i = pe ? FA : FB;
        k_lvl<<<blocks, 512, 0, stream>>>(lvl, cLog, f0, f1, f2,
                                          E4, E_f, uioub, ufb,
                                          biou_f, bf_f,
                                          hs_i, fc_i, hs_o, fc_o, hroot);
    }
    k_final<<<NTREE, 256, 0, stream>>>(hroot, fc1w_f, fc1b_f, fc2w_f, fc2b_f, d_out, flag);
}

// Round 7
// 432.771 us; speedup vs baseline: 1.0739x; 1.0739x over previous
//
#include <hip/hip_runtime.h>
#include <hip/hip_bf16.h>

typedef __hip_bfloat16 bf16;
typedef unsigned short u16;
typedef __attribute__((ext_vector_type(8))) short s8;   // 8 bf16 = one MFMA A/B fragment
typedef __attribute__((ext_vector_type(4))) float f4;   // MFMA C/D fragment

#define NRUNS 3
#define NTREE 128
#define TT    255
#define DD    256
#define VPAD  10016    /* vocab padded to 32 */
#define PAD   258      /* LDS row stride in u16 for 256-wide rows */
#define OPAD  264      /* output-staging stride: uint4-aligned (528B), bank-staggered */
#define FPAD  264      /* fcP carry stride in k_tail (528B breaks 512B bank aliasing) */

__device__ __forceinline__ float bits2f(u16 b){ union{unsigned u; float f;} x; x.u = ((unsigned)b)<<16; return x.f; }
__device__ __forceinline__ u16   f2bits(float f){ bf16 h = __float2bfloat16(f); return *(u16*)&h; }
__device__ __forceinline__ float sigm(float x){ return 1.f/(1.f+__expf(-x)); }
__device__ __forceinline__ float tanh_(float x){ return 1.f - 2.f/(__expf(2.f*x)+1.f); }

// ---------------- dtype autodetect (proven) ----------------
__global__ void k_detect(const u16* __restrict__ raw, int* __restrict__ flag){
    int t = threadIdx.x;
    int hit = 0;
    if (t < 128){
        u16 w = raw[2*t];
        int e = (w >> 7) & 0xFF;
        hit = (e >= 100 && e <= 141) ? 1 : 0;
    }
    __shared__ int cnt;
    if (t == 0) cnt = 0;
    __syncthreads();
    atomicAdd(&cnt, hit);
    __syncthreads();
    if (t == 0) flag[0] = (cnt >= 64) ? 1 : 0;
}

__device__ __forceinline__ u16 cvt1b(const void* p, int i, int isb){
    return isb ? ((const u16*)p)[i] : f2bits(((const float*)p)[i]);
}
__device__ __forceinline__ float cvt1f(const void* p, int i, int isb){
    return isb ? bits2f(((const u16*)p)[i]) : ((const float*)p)[i];
}

// fused any->bf16 conversion: emb (zero-padded to VPAD rows) + 4 weights
#define L_EMB  (10000*256)
#define L_EMBP (VPAD*256)
#define L_WIOU (768*256)
#define L_UIOU (768*256)
#define L_WF   (256*256)
#define L_UF   (256*256)
#define L_ALL  (L_EMBP + L_WIOU + L_UIOU + L_WF + L_UF)
__global__ void k_cvtb(const void* __restrict__ s0, const void* __restrict__ s1,
                       const void* __restrict__ s2, const void* __restrict__ s3,
                       const void* __restrict__ s4,
                       u16* __restrict__ d0, u16* __restrict__ d1, u16* __restrict__ d2,
                       u16* __restrict__ d3, u16* __restrict__ d4,
                       const int* __restrict__ flag){
    int isb = flag[0];
    for (int i = blockIdx.x*blockDim.x + threadIdx.x; i < L_ALL; i += gridDim.x*blockDim.x){
        int j = i;
        if (j < L_EMBP){ d0[j] = (j < L_EMB) ? cvt1b(s0, j, isb) : (u16)0; continue; } j -= L_EMBP;
        if (j < L_WIOU){ d1[j] = cvt1b(s1, j, isb); continue; } j -= L_WIOU;
        if (j < L_UIOU){ d2[j] = cvt1b(s2, j, isb); continue; } j -= L_UIOU;
        if (j < L_WF){ d3[j] = cvt1b(s3, j, isb); continue; } j -= L_WF;
        d4[j] = cvt1b(s4, j, isb);
    }
}

// fused any->f32 conversion of biases + FC weights
#define S_BIOU 768
#define S_BF   256
#define S_F1W  (128*256)
#define S_F1B  128
#define S_F2W  (3*128)
#define S_F2B  3
#define S_ALL  (S_BIOU+S_BF+S_F1W+S_F1B+S_F2W+S_F2B)
__global__ void k_small(const void* __restrict__ s0, const void* __restrict__ s1,
                        const void* __restrict__ s2, const void* __restrict__ s3,
                        const void* __restrict__ s4, const void* __restrict__ s5,
                        float* __restrict__ d0, float* __restrict__ d1, float* __restrict__ d2,
                        float* __restrict__ d3, float* __restrict__ d4, float* __restrict__ d5,
                        const int* __restrict__ flag){
    int isb = flag[0];
    for (int i = blockIdx.x*blockDim.x + threadIdx.x; i < S_ALL; i += gridDim.x*blockDim.x){
        int j = i;
        if (j < S_BIOU){ d0[j] = cvt1f(s0, j, isb); continue; } j -= S_BIOU;
        if (j < S_BF){ d1[j] = cvt1f(s1, j, isb); continue; } j -= S_BF;
        if (j < S_F1W){ d2[j] = cvt1f(s2, j, isb); continue; } j -= S_F1W;
        if (j < S_F1B){ d3[j] = cvt1f(s3, j, isb); continue; } j -= S_F1B;
        if (j < S_F2W){ d4[j] = cvt1f(s4, j, isb); continue; } j -= S_F2W;
        d5[j] = cvt1f(s5, j, isb);
    }
}

__device__ __forceinline__ s8 ldB16(const u16* p){
    union { uint4 q; s8 v; } u;
    u.q = *(const uint4*)p;
    return u.v;
}
__device__ __forceinline__ s8 ldsA(const u16* p){
    union { unsigned w[4]; s8 v; } u;
    u.w[0] = *(const unsigned*)(p);
    u.w[1] = *(const unsigned*)(p+2);
    u.w[2] = *(const unsigned*)(p+4);
    u.w[3] = *(const unsigned*)(p+6);
    return u.v;
}
#define MFMA(acc,a,b) acc = __builtin_amdgcn_mfma_f32_16x16x32_bf16(a, b, acc, 0, 0, 0)

// ---------------- vocab-space precompute (packed E4[vocab][256][4] = {i,o,u,f}) ----------------
__global__ __launch_bounds__(512, 4)
void k_vocab2(const u16* __restrict__ embb,
              const u16* __restrict__ Wiou, const u16* __restrict__ Wfm,
              const u16* __restrict__ Ufm,  const float* __restrict__ biou_f,
              u16* __restrict__ E4, u16* __restrict__ E_f,
              u16* __restrict__ H0, u16* __restrict__ C0, u16* __restrict__ HU0)
{
    __shared__ u16 hs[32*PAD];    // h0 for the HU0 GEMM
    const int t = threadIdx.x, w = t>>6, lane = t&63, ln = lane&15, q = lane>>4;
    const int r0 = blockIdx.x*32, d0 = w*32;

    const u16* Bp[8];
    #pragma unroll
    for (int g = 0; g < 4; g++)
      #pragma unroll
      for (int nc = 0; nc < 2; nc++){
        int nn = d0 + nc*16 + ln;
        Bp[g*2+nc] = (g < 3) ? (Wiou + (size_t)(g*256+nn)*DD) : (Wfm + (size_t)nn*DD);
      }
    const u16* a0p = embb + (size_t)(r0+ln)*DD;
    const u16* a1p = embb + (size_t)(r0+16+ln)*DD;
    f4 acc[8][2];
    #pragma unroll
    for (int nt = 0; nt < 8; nt++){ acc[nt][0] = (f4){0,0,0,0}; acc[nt][1] = (f4){0,0,0,0}; }
    #pragma unroll 2
    for (int ks = 0; ks < 8; ks++){
        int ko = ks*32 + q*8;
        s8 a0 = ldB16(a0p + ko);
        s8 a1 = ldB16(a1p + ko);
        #pragma unroll
        for (int nt = 0; nt < 8; nt++){
            s8 bb = ldB16(Bp[nt] + ko);
            MFMA(acc[nt][0], a0, bb);
            MFMA(acc[nt][1], a1, bb);
        }
    }
    #pragma unroll
    for (int nc = 0; nc < 2; nc++){
        int d = d0 + nc*16 + ln;
        float bi = biou_f[d], bo = biou_f[256+d], bu = biou_f[512+d];
        #pragma unroll
        for (int ms = 0; ms < 2; ms++)
          #pragma unroll
          for (int r = 0; r < 4; r++){
            int vrow = r0 + ms*16 + q*4 + r;
            float ei = acc[0*2+nc][ms][r];
            float eo = acc[1*2+nc][ms][r];
            float eu = acc[2*2+nc][ms][r];
            float ef = acc[3*2+nc][ms][r];
            union { u16 a[4]; uint2 q2; } pk;
            pk.a[0] = f2bits(ei);
            pk.a[1] = f2bits(eo);
            pk.a[2] = f2bits(eu);
            pk.a[3] = f2bits(ef);
            *(uint2*)(E4 + ((size_t)vrow*DD + d)*4) = pk.q2;
            E_f[(size_t)vrow*DD + d] = f2bits(ef);
            float cc = sigm(ei + bi)*tanh_(eu + bu);
            float hh = sigm(eo + bo)*tanh_(cc);
            C0[(size_t)vrow*DD + d] = f2bits(cc);
            H0[(size_t)vrow*DD + d] = f2bits(hh);
            hs[(ms*16 + q*4 + r)*PAD + d] = f2bits(hh);
        }
    }
    __syncthreads();

    f4 hacc[2][2];
    #pragma unroll
    for (int nt = 0; nt < 2; nt++){ hacc[nt][0] = (f4){0,0,0,0}; hacc[nt][1] = (f4){0,0,0,0}; }
    const u16* Bf0 = Ufm + (size_t)(d0 + ln)*DD;
    const u16* Bf1 = Ufm + (size_t)(d0 + 16 + ln)*DD;
    #pragma unroll 2
    for (int ks = 0; ks < 8; ks++){
        int ko = ks*32 + q*8;
        s8 a0 = ldsA(&hs[ln*PAD + ko]);
        s8 a1 = ldsA(&hs[(16+ln)*PAD + ko]);
        s8 b0 = ldB16(Bf0 + ko);
        s8 b1 = ldB16(Bf1 + ko);
        MFMA(hacc[0][0], a0, b0); MFMA(hacc[0][1], a1, b0);
        MFMA(hacc[1][0], a0, b1); MFMA(hacc[1][1], a1, b1);
    }
    #pragma unroll
    for (int nc = 0; nc < 2; nc++){
        int d = d0 + nc*16 + ln;
        #pragma unroll
        for (int ms = 0; ms < 2; ms++)
          #pragma unroll
          for (int r = 0; r < 4; r++){
            int vrow = r0 + ms*16 + q*4 + r;
            HU0[(size_t)vrow*DD + d] = f2bits(hacc[nc][ms][r]);
        }
    }
}

// ---------------- k_edge0: assemble lvl-1 inputs from vocab tables (proven) ----------------
__global__ __launch_bounds__(512, 4)
void k_edge0(const int* __restrict__ f0, const int* __restrict__ f1, const int* __restrict__ f2,
             const u16* __restrict__ E_f, const u16* __restrict__ H0,
             const u16* __restrict__ C0,  const u16* __restrict__ HU0,
             const float* __restrict__ bf_f,
             u16* __restrict__ hsum_out, u16* __restrict__ fcsum_out)
{
    int gid = blockIdx.x*512 + threadIdx.x;
    int row = gid >> 5, ch = gid & 31, d = ch*8;
    int run = row >> 13, rem = row & 8191, b = rem >> 6, jj = rem & 63;
    const int* fp = (run==0) ? f0 : ((run==1) ? f1 : f2);
    int fo = fp[b*TT + 128 + jj];
    int v1 = fp[b*TT + 2*jj];
    int v2 = fp[b*TT + 2*jj + 1];
    s8 ef  = ldB16(E_f + (size_t)fo*DD + d);
    s8 hu1 = ldB16(HU0 + (size_t)v1*DD + d);
    s8 hu2 = ldB16(HU0 + (size_t)v2*DD + d);
    s8 c1  = ldB16(C0  + (size_t)v1*DD + d);
    s8 c2  = ldB16(C0  + (size_t)v2*DD + d);
    s8 h1  = ldB16(H0  + (size_t)v1*DD + d);
    s8 h2  = ldB16(H0  + (size_t)v2*DD + d);
    union { u16 a[8]; uint4 q4; } uh, uf;
    #pragma unroll
    for (int j = 0; j < 8; j++){
        float e  = bits2f((u16)ef[j]) + bf_f[d+j];
        float fa = sigm(e + bits2f((u16)hu1[j]));
        float fb = sigm(e + bits2f((u16)hu2[j]));
        float fc = fa*bits2f((u16)c1[j]) + fb*bits2f((u16)c2[j]);
        float hsv = bits2f((u16)h1[j]) + bits2f((u16)h2[j]);
        uf.a[j] = f2bits(fc);
        uh.a[j] = f2bits(hsv);
    }
    *(uint4*)(hsum_out  + (size_t)row*DD + d) = uh.q4;
    *(uint4*)(fcsum_out + (size_t)row*DD + d) = uf.q4;
}

// ---------------- per-level kernel (v6 == R5 proven: 81us lvl-1, VGPR 64) ----------------
// R6 post-mortem: register-prefetch of E4 was sunk by the scheduler (VGPR 68, not 96)
// and (512,3) let the allocator balloon -> occupancy 37->22%, dur 81->108. Reverted.
__global__ __launch_bounds__(512, 4)
void k_lvl(int lvl, int cLog,
           const int* __restrict__ f0, const int* __restrict__ f1, const int* __restrict__ f2,
           const u16* __restrict__ E4, const u16* __restrict__ E_f,
           const u16* __restrict__ Uiou, const u16* __restrict__ Ufm,
           const float* __restrict__ biou_f, const float* __restrict__ bf_f,
           const u16* __restrict__ hsum_in, const u16* __restrict__ fcsum_in,
           u16* __restrict__ hsum_out, u16* __restrict__ fcsum_out,
           u16* __restrict__ hroot)
{
    __shared__ u16 hs[32*PAD];     // 16.5 KB: h transpose for GEMM-C
    __shared__ u16 hso[16*OPAD];   // 8.4 KB: staged hsum_out rows
    __shared__ u16 fco[16*OPAD];   // 8.4 KB: staged fcsum_out rows
    __shared__ int sfr[32];        // this block's 32 node feats (epilogue E4 rows)
    const int t = threadIdx.x, w = t>>6, lane = t&63, ln = lane&15, q = lane>>4;
    const int cnt = 1 << cLog, S = 256 - 2*cnt;
    const int r0 = blockIdx.x*32, d0 = w*32;
    const bool haveP = (lvl < 7);

    // ---- stage this block's 32 node feats into LDS (128 B) ----
    if (t < 32){
        int rho = r0 + t;
        int run = rho >> (7+cLog);
        int rem = rho & ((1<<(7+cLog)) - 1);
        int b = rem >> cLog, jj = rem & (cnt-1);
        const int* fp = (run==0) ? f0 : ((run==1) ? f1 : f2);
        sfr[t] = fp[b*TT + S + jj];
    }

    // parent feats for GEMM-C epilogue
    int featp[2][2];
    if (haveP){
        #pragma unroll
        for (int ms = 0; ms < 2; ms++)
          #pragma unroll
          for (int rr = 0; rr < 2; rr++){
            int rho = r0 + ms*16 + q*4 + rr*2;
            int run = rho >> (7+cLog);
            int rem = rho & ((1<<(7+cLog)) - 1);
            int b = rem >> cLog, jj = rem & (cnt-1);
            const int* fp = (run==0) ? f0 : ((run==1) ? f1 : f2);
            featp[ms][rr] = fp[b*TT + (256-cnt) + (jj>>1)];
          }
    }
    __syncthreads();   // sfr visible to all

    // ---- GEMM-U: hsum_in @ Uiou^T ----
    f4 acc[6][2];
    #pragma unroll
    for (int nt = 0; nt < 6; nt++){ acc[nt][0] = (f4){0,0,0,0}; acc[nt][1] = (f4){0,0,0,0}; }
    {
        const u16* a0p = hsum_in + (size_t)(r0+ln)*DD;
        const u16* a1p = hsum_in + (size_t)(r0+16+ln)*DD;
        const u16* Bp[6];
        #pragma unroll
        for (int nt = 0; nt < 6; nt++){
            int n = (nt>>1)*256 + d0 + (nt&1)*16 + ln;
            Bp[nt] = Uiou + (size_t)n*DD;
        }
        #pragma unroll 2
        for (int ks = 0; ks < 8; ks++){
            int ko = ks*32 + q*8;
            s8 a0 = ldB16(a0p + ko);
            s8 a1 = ldB16(a1p + ko);
            #pragma unroll
            for (int nt = 0; nt < 6; nt++){
                s8 bb = ldB16(Bp[nt] + ko);
                MFMA(acc[nt][0], a0, bb);
                MFMA(acc[nt][1], a1, bb);
            }
        }
    }

    // ---- epilogue: cell update with packed E4 read (one uint2/thread/iter) ----
    float cv[2][2][4];
    #pragma unroll
    for (int nc = 0; nc < 2; nc++){
        int d = d0 + nc*16 + ln;
        float bi = biou_f[d], bo = biou_f[256+d], bu = biou_f[512+d];
        #pragma unroll
        for (int ms = 0; ms < 2; ms++){
            float hv[4];
            #pragma unroll
            for (int r = 0; r < 4; r++){
                int m   = ms*16 + q*4 + r;
                int rho = r0 + m;
                union { uint2 q2; u16 a[4]; } ev;
                ev.q2 = *(const uint2*)(E4 + ((size_t)sfr[m]*DD + d)*4);
                float iv = acc[0+nc][ms][r] + bits2f(ev.a[0]) + bi;
                float ov = acc[2+nc][ms][r] + bits2f(ev.a[1]) + bo;
                float uv = acc[4+nc][ms][r] + bits2f(ev.a[2]) + bu;
                float cs = bits2f(fcsum_in[(size_t)rho*DD + d]);
                float c = sigm(iv)*tanh_(uv) + cs;
                float h = sigm(ov)*tanh_(c);
                cv[nc][ms][r] = c;
                hv[r] = h;
                if (haveP) hs[m*PAD + d] = f2bits(h);
                else       hroot[(size_t)rho*DD + d] = f2bits(h);
            }
            if (haveP){
                int lr = ms*8 + q*2;
                hso[lr*OPAD + d]     = f2bits(hv[0] + hv[1]);
                hso[(lr+1)*OPAD + d] = f2bits(hv[2] + hv[3]);
            }
        }
    }

    // ---- GEMM-C: hU = h@Uf^T, fc = sig(E_f[parent]+bf+hU)*c, pair-reduce ----
    if (haveP){
        __syncthreads();
        f4 hacc[2][2];
        #pragma unroll
        for (int nt = 0; nt < 2; nt++){ hacc[nt][0] = (f4){0,0,0,0}; hacc[nt][1] = (f4){0,0,0,0}; }
        const u16* Bf0 = Ufm + (size_t)(d0 + ln)*DD;
        const u16* Bf1 = Ufm + (size_t)(d0 + 16 + ln)*DD;
        #pragma unroll 2
        for (int ks = 0; ks < 8; ks++){
            int ko = ks*32 + q*8;
            s8 a0 = ldsA(&hs[ln*PAD + ko]);
            s8 a1 = ldsA(&hs[(16+ln)*PAD + ko]);
            s8 b0 = ldB16(Bf0 + ko);
            s8 b1 = ldB16(Bf1 + ko);
            MFMA(hacc[0][0], a0, b0); MFMA(hacc[0][1], a1, b0);
            MFMA(hacc[1][0], a0, b1); MFMA(hacc[1][1], a1, b1);
        }
        #pragma unroll
        for (int nc = 0; nc < 2; nc++){
            int d = d0 + nc*16 + ln;
            float bfv = bf_f[d];
            #pragma unroll
            for (int ms = 0; ms < 2; ms++){
                float fs0, fs1;
                #pragma unroll
                for (int r = 0; r < 4; r++){
                    float ef = bits2f(E_f[(size_t)featp[ms][r>>1]*DD + d]);
                    float fc = sigm(ef + bfv + hacc[nc][ms][r]) * cv[nc][ms][r];
                    if (r == 0) fs0 = fc;
                    else if (r == 1) fs0 += fc;
                    else if (r == 2) fs1 = fc;
                    else fs1 += fc;
                }
                int lr = ms*8 + q*2;
                fco[lr*OPAD + d]     = f2bits(fs0);
                fco[(lr+1)*OPAD + d] = f2bits(fs1);
            }
        }

        // ---- single coalesced write pass: full 128B lines, written once ----
        __syncthreads();
        {
            int row = t >> 5, c = (t & 31) * 8;
            int prow = (r0 >> 1) + row;
            uint4 vh = *(const uint4*)&hso[row*OPAD + c];
            uint4 vf = *(const uint4*)&fco[row*OPAD + c];
            *(uint4*)(hsum_out  + (size_t)prow*DD + c) = vh;
            *(uint4*)(fcsum_out + (size_t)prow*DD + c) = vf;
        }
    }
}

// ---------------- k_tail: levels 4..7 fused, block = 4 trees (machine underfilled here) ----------------
// lvl 4-7 have 96/48/24/12 blocks on 256 CUs -- each separate dispatch is mostly
// launch+drain latency. One block carries 4 trees' state (32 rows at lvl4, masked
// sub-tiles after) in LDS ping-pong across the 4 levels. Garbage rows (m >= nrows)
// cannot contaminate valid MFMA output rows (per-row dot products); feat indices
// are clamped so no OOB global gathers. LDS 83 KB -> 1 block/CU (irrelevant at 96 blocks).
__global__ __launch_bounds__(512, 4)
void k_tail(const int* __restrict__ f0, const int* __restrict__ f1, const int* __restrict__ f2,
            const u16* __restrict__ E4, const u16* __restrict__ E_f,
            const u16* __restrict__ Uiou, const u16* __restrict__ Ufm,
            const float* __restrict__ biou_f, const float* __restrict__ bf_f,
            const u16* __restrict__ hsum_in, const u16* __restrict__ fcsum_in,
            u16* __restrict__ hroot)
{
    __shared__ u16 hs[32*PAD];        // 16.5 KB: h transpose for GEMM-C
    __shared__ u16 hsP[2][32*PAD];    // 33 KB: hsum carry ping-pong
    __shared__ u16 fcP[2][32*FPAD];   // 33.8 KB: fcsum carry ping-pong
    __shared__ int sf[64];            // 4 trees x 16 feats (heap slots 240..254)
    const int t = threadIdx.x, w = t>>6, lane = t&63, ln = lane&15, q = lane>>4;
    const int d0 = w*32;
    const int r0 = blockIdx.x*32;                 // lvl-4 global row base
    const int run = (blockIdx.x*4) >> 7;          // all 4 trees share one run
    const int* __restrict__ fp = (run==0) ? f0 : ((run==1) ? f1 : f2);

    if (t < 64){
        int ti = t >> 4, idx = t & 15;
        int b = (blockIdx.x*4 + ti) & 127;
        sf[t] = (idx < 15) ? fp[b*TT + 240 + idx] : 0;
    }
    __syncthreads();

    // B pointers constant across levels
    const u16* Bp[6];
    #pragma unroll
    for (int nt = 0; nt < 6; nt++){
        int n = (nt>>1)*256 + d0 + (nt&1)*16 + ln;
        Bp[nt] = Uiou + (size_t)n*DD;
    }
    const u16* Bf0 = Ufm + (size_t)(d0 + ln)*DD;
    const u16* Bf1 = Ufm + (size_t)(d0 + 16 + ln)*DD;

    for (int l = 4; l <= 7; l++){
        const int nl = 128 >> l;        // nodes per tree at this level (8,4,2,1)
        const int nrows = 4*nl;         // valid rows in block (32,16,8,4)
        const int sh = 7 - l;           // local m -> tree index shift
        const int inb = (l-1) & 1, outb = l & 1;
        const bool haveP = (l < 7);

        // ---- GEMM-U: A from global (lvl4) or LDS carry ----
        f4 acc[6][2];
        #pragma unroll
        for (int nt = 0; nt < 6; nt++){ acc[nt][0] = (f4){0,0,0,0}; acc[nt][1] = (f4){0,0,0,0}; }
        if (l == 4){
            const u16* a0p = hsum_in + (size_t)(r0+ln)*DD;
            const u16* a1p = hsum_in + (size_t)(r0+16+ln)*DD;
            #pragma unroll 2
            for (int ks = 0; ks < 8; ks++){
                int ko = ks*32 + q*8;
                s8 a0 = ldB16(a0p + ko);
                s8 a1 = ldB16(a1p + ko);
                #pragma unroll
                for (int nt = 0; nt < 6; nt++){
                    s8 bb = ldB16(Bp[nt] + ko);
                    MFMA(acc[nt][0], a0, bb);
                    MFMA(acc[nt][1], a1, bb);
                }
            }
        } else {
            const u16* a0l = &hsP[inb][ln*PAD];
            const u16* a1l = &hsP[inb][(16+ln)*PAD];
            #pragma unroll 2
            for (int ks = 0; ks < 8; ks++){
                int ko = ks*32 + q*8;
                s8 a0 = ldsA(a0l + ko);
                s8 a1 = ldsA(a1l + ko);
                #pragma unroll
                for (int nt = 0; nt < 6; nt++){
                    s8 bb = ldB16(Bp[nt] + ko);
                    MFMA(acc[nt][0], a0, bb);
                    MFMA(acc[nt][1], a1, bb);
                }
            }
        }

        // ---- epilogue: cell update; hsum pair-reduce into hsP[outb] ----
        float cv[2][2][4];
        #pragma unroll
        for (int nc = 0; nc < 2; nc++){
            int d = d0 + nc*16 + ln;
            float bi = biou_f[d], bo = biou_f[256+d], bu = biou_f[512+d];
            #pragma unroll
            for (int ms = 0; ms < 2; ms++){
                float hv[4];
                #pragma unroll
                for (int r = 0; r < 4; r++){
                    int m = ms*16 + q*4 + r;
                    bool vld = (m < nrows);
                    int mc = vld ? m : 0;
                    int ti = mc >> sh, jj = mc & (nl-1);
                    int fidx = sf[ti*16 + (16 - 2*nl) + jj];
                    union { uint2 q2; u16 a[4]; } ev;
                    ev.q2 = *(const uint2*)(E4 + ((size_t)fidx*DD + d)*4);
                    float iv = acc[0+nc][ms][r] + bits2f(ev.a[0]) + bi;
                    float ov = acc[2+nc][ms][r] + bits2f(ev.a[1]) + bo;
                    float uv = acc[4+nc][ms][r] + bits2f(ev.a[2]) + bu;
                    float cs = (l == 4) ? bits2f(fcsum_in[(size_t)(r0+m)*DD + d])
                                        : bits2f(fcP[inb][m*FPAD + d]);
                    float c = sigm(iv)*tanh_(uv) + cs;
                    float h = sigm(ov)*tanh_(c);
                    cv[nc][ms][r] = c;
                    hv[r] = h;
                    if (haveP) hs[m*PAD + d] = f2bits(h);
                    else if (vld) hroot[(size_t)(blockIdx.x*4 + m)*DD + d] = f2bits(h);
                }
                if (haveP){
                    int lr = ms*8 + q*2;
                    hsP[outb][lr*PAD + d]     = f2bits(hv[0] + hv[1]);
                    hsP[outb][(lr+1)*PAD + d] = f2bits(hv[2] + hv[3]);
                }
            }
        }

        // ---- GEMM-C -> fcP[outb] ----
        if (haveP){
            __syncthreads();
            f4 hacc[2][2];
            #pragma unroll
            for (int nt = 0; nt < 2; nt++){ hacc[nt][0] = (f4){0,0,0,0}; hacc[nt][1] = (f4){0,0,0,0}; }
            #pragma unroll 2
            for (int ks = 0; ks < 8; ks++){
                int ko = ks*32 + q*8;
                s8 a0 = ldsA(&hs[ln*PAD + ko]);
                s8 a1 = ldsA(&hs[(16+ln)*PAD + ko]);
                s8 b0 = ldB16(Bf0 + ko);
                s8 b1 = ldB16(Bf1 + ko);
                MFMA(hacc[0][0], a0, b0); MFMA(hacc[0][1], a1, b0);
                MFMA(hacc[1][0], a0, b1); MFMA(hacc[1][1], a1, b1);
            }
            #pragma unroll
            for (int nc = 0; nc < 2; nc++){
                int d = d0 + nc*16 + ln;
                float bfv = bf_f[d];
                #pragma unroll
                for (int ms = 0; ms < 2; ms++){
                    float fs0, fs1;
                    #pragma unroll
                    for (int r = 0; r < 4; r++){
                        int m2 = ms*16 + q*4 + (r & 2);
                        int mc2 = (m2 < nrows) ? m2 : 0;
                        int ti2 = mc2 >> sh, jj2 = mc2 & (nl-1);
                        int fpar = sf[ti2*16 + (16 - nl) + (jj2 >> 1)];
                        float ef = bits2f(E_f[(size_t)fpar*DD + d]);
                        float fc = sigm(ef + bfv + hacc[nc][ms][r]) * cv[nc][ms][r];
                        if (r == 0) fs0 = fc;
                        else if (r == 1) fs0 += fc;
                        else if (r == 2) fs1 = fc;
                        else fs1 += fc;
                    }
                    int lr = ms*8 + q*2;
                    fcP[outb][lr*FPAD + d]     = f2bits(fs0);
                    fcP[outb][(lr+1)*FPAD + d] = f2bits(fs1);
                }
            }
            __syncthreads();   // carry buffers ready for next level
        }
    }
}

// ---------------- final: bilinear combine + MLP (proven epilogue) ----------------
__global__ __launch_bounds__(256)
void k_final(const u16* __restrict__ hroot,
             const float* __restrict__ fc1w, const float* __restrict__ fc1b,
             const float* __restrict__ fc2w, const float* __restrict__ fc2b,
             void* __restrict__ out, const int* __restrict__ flag)
{
    int b = blockIdx.x, t = threadIdx.x;
    __shared__ float sprod[DD];
    __shared__ float shb[DD];
    __shared__ float shid[128];
    float hc  = bits2f(hroot[(0*NTREE + b)*DD + t]);
    float ha  = bits2f(hroot[(1*NTREE + b)*DD + t]);
    float hbv = bits2f(hroot[(2*NTREE + b)*DD + t]);
    sprod[t] = hc * ha;
    shb[t]   = hbv;
    __syncthreads();
    for (int s = 128; s > 0; s >>= 1){
        if (t < s) sprod[t] += sprod[t + s];
        __syncthreads();
    }
    float dot = sprod[0];
    if (t < 128){
        float acc = fc1b[t];
        for (int k = 0; k < DD; k++)
            acc = fmaf(dot * shb[k], fc1w[t*DD + k], acc);
        shid[t] = fmaxf(acc, 0.f);
    }
    __syncthreads();
    if (t < 3){
        float acc = fc2b[t];
        for (int j = 0; j < 128; j++)
            acc = fmaf(fc2w[t*128 + j], shid[j], acc);
        float v = fmaxf(acc, 0.f);
        if (flag[0]) ((bf16*)out)[b*3 + t] = __float2bfloat16(v);
        else         ((float*)out)[b*3 + t] = v;
    }
}

extern "C" void kernel_launch(void* const* d_in, const int* in_sizes, int n_in,
                              void* d_out, int out_size, void* d_ws, size_t ws_size,
                              hipStream_t stream)
{
    const int* f0 = (const int*)d_in[0];
    const int* f1 = (const int*)d_in[1];
    const int* f2 = (const int*)d_in[2];
    // d_in[3..7] static forest metadata — unused (structure compile-time known)
    const void* emb  = d_in[8];
    const void* Wiou = d_in[9];
    const void* biou = d_in[10];
    const void* Uiou = d_in[11];
    const void* Wf   = d_in[12];
    const void* bfv  = d_in[13];
    const void* Uf   = d_in[14];
    const void* fc1w = d_in[15];
    const void* fc1b = d_in[16];
    const void* fc2w = d_in[17];
    const void* fc2b = d_in[18];

    char* base = (char*)d_ws;
    size_t off = 0;
    auto take = [&](size_t bytes) -> char* {
        char* p = base + off;
        off = (off + bytes + 255) & ~(size_t)255;
        return p;
    };
    int*   flag   = (int*)  take(256);
    u16*   embb   = (u16*)  take((size_t)L_EMBP*2);
    u16*   wioub  = (u16*)  take((size_t)L_WIOU*2);
    u16*   uioub  = (u16*)  take((size_t)L_UIOU*2);
    u16*   wfb    = (u16*)  take((size_t)L_WF*2);
    u16*   ufb    = (u16*)  take((size_t)L_UF*2);
    float* biou_f = (float*)take(S_BIOU*4);
    float* bf_f   = (float*)take(S_BF*4);
    float* fc1w_f = (float*)take(S_F1W*4);
    float* fc1b_f = (float*)take(S_F1B*4);
    float* fc2w_f = (float*)take(S_F2W*4);
    float* fc2b_f = (float*)take(S_F2B*4);
    u16*   E4     = (u16*)  take((size_t)VPAD*DD*4*2);     // 20.5 MB packed {i,o,u,f}
    u16*   E_f    = (u16*)  take((size_t)VPAD*DD*2);       // 5.13 MB
    u16*   H0     = (u16*)  take((size_t)VPAD*DD*2);
    u16*   C0     = (u16*)  take((size_t)VPAD*DD*2);
    u16*   HU0    = (u16*)  take((size_t)VPAD*DD*2);
    u16*   HA     = (u16*)  take((size_t)24576*DD*2);
    u16*   HB     = (u16*)  take((size_t)12288*DD*2);
    u16*   FA     = (u16*)  take((size_t)24576*DD*2);
    u16*   FB     = (u16*)  take((size_t)12288*DD*2);
    u16*   hroot  = (u16*)  take((size_t)NRUNS*NTREE*DD*2);
    // total ~85 MB (< proven 119 MB)

    k_detect<<<1, 256, 0, stream>>>((const u16*)emb, flag);
    k_cvtb<<<2048, 256, 0, stream>>>(emb, Wiou, Uiou, Wf, Uf,
                                     embb, wioub, uioub, wfb, ufb, flag);
    k_small<<<135, 256, 0, stream>>>(biou, bfv, fc1w, fc1b, fc2w, fc2b,
                                     biou_f, bf_f, fc1w_f, fc1b_f, fc2w_f, fc2b_f, flag);
    k_vocab2<<<VPAD/32, 512, 0, stream>>>(embb, wioub, wfb, ufb, biou_f,
                                          E4, E_f, H0, C0, HU0);
    k_edge0<<<24576*32/512, 512, 0, stream>>>(f0, f1, f2, E_f, H0, C0, HU0, bf_f, HA, FA);

    for (int lvl = 1; lvl <= 3; lvl++){
        int cLog = 7 - lvl;
        int rows = NRUNS*NTREE*(128 >> lvl);
        int blocks = rows / 32;
        int pe = lvl & 1;
        u16* hs_o = pe ? HB : HA;
        u16* fc_o = pe ? FB : FA;
        const u16* hs_i = pe ? HA : HB;
        const u16* fc_i = pe ? FA : FB;
        k_lvl<<<blocks, 512, 0, stream>>>(lvl, cLog, f0, f1, f2,
                                          E4, E_f, uioub, ufb,
                                          biou_f, bf_f,
                                          hs_i, fc_i, hs_o, fc_o, hroot);
    }
    // lvl3 (pe=1) wrote HB/FB -> k_tail consumes them for lvl4..7
    k_tail<<<(NRUNS*NTREE)/4, 512, 0, stream>>>(f0, f1, f2, E4, E_f, uioub, ufb,
                                                biou_f, bf_f, HB, FB, hroot);
    k_final<<<NTREE, 256, 0, stream>>>(hroot, fc1w_f, fc1b_f, fc2w_f, fc2b_f, d_out, flag);
}

// Round 8
// 431.240 us; speedup vs baseline: 1.0778x; 1.0035x over previous
//
#include <hip/hip_runtime.h>
#include <hip/hip_bf16.h>

typedef __hip_bfloat16 bf16;
typedef unsigned short u16;
typedef __attribute__((ext_vector_type(8))) short s8;   // 8 bf16 = one MFMA A/B fragment
typedef __attribute__((ext_vector_type(4))) float f4;   // MFMA C/D fragment

#define NRUNS 3
#define NTREE 128
#define TT    255
#define DD    256
#define VPAD  10016    /* vocab padded to 32 */
#define PAD   258      /* LDS row stride in u16 for 256-wide rows */
#define OPAD  264      /* output-staging stride: uint4-aligned (528B), bank-staggered */
#define FPAD  264      /* fcP carry stride in k_tail (528B breaks 512B bank aliasing) */

__device__ __forceinline__ float bits2f(u16 b){ union{unsigned u; float f;} x; x.u = ((unsigned)b)<<16; return x.f; }
__device__ __forceinline__ u16   f2bits(float f){ bf16 h = __float2bfloat16(f); return *(u16*)&h; }
__device__ __forceinline__ float sigm(float x){ return 1.f/(1.f+__expf(-x)); }
__device__ __forceinline__ float tanh_(float x){ return 1.f - 2.f/(__expf(2.f*x)+1.f); }

// ---------------- dtype autodetect (proven) ----------------
__global__ void k_detect(const u16* __restrict__ raw, int* __restrict__ flag){
    int t = threadIdx.x;
    int hit = 0;
    if (t < 128){
        u16 w = raw[2*t];
        int e = (w >> 7) & 0xFF;
        hit = (e >= 100 && e <= 141) ? 1 : 0;
    }
    __shared__ int cnt;
    if (t == 0) cnt = 0;
    __syncthreads();
    atomicAdd(&cnt, hit);
    __syncthreads();
    if (t == 0) flag[0] = (cnt >= 64) ? 1 : 0;
}

__device__ __forceinline__ u16 cvt1b(const void* p, int i, int isb){
    return isb ? ((const u16*)p)[i] : f2bits(((const float*)p)[i]);
}
__device__ __forceinline__ float cvt1f(const void* p, int i, int isb){
    return isb ? bits2f(((const u16*)p)[i]) : ((const float*)p)[i];
}

// fused any->bf16 conversion: emb (zero-padded to VPAD rows) + 4 weights
#define L_EMB  (10000*256)
#define L_EMBP (VPAD*256)
#define L_WIOU (768*256)
#define L_UIOU (768*256)
#define L_WF   (256*256)
#define L_UF   (256*256)
#define L_ALL  (L_EMBP + L_WIOU + L_UIOU + L_WF + L_UF)
__global__ void k_cvtb(const void* __restrict__ s0, const void* __restrict__ s1,
                       const void* __restrict__ s2, const void* __restrict__ s3,
                       const void* __restrict__ s4,
                       u16* __restrict__ d0, u16* __restrict__ d1, u16* __restrict__ d2,
                       u16* __restrict__ d3, u16* __restrict__ d4,
                       const int* __restrict__ flag){
    int isb = flag[0];
    for (int i = blockIdx.x*blockDim.x + threadIdx.x; i < L_ALL; i += gridDim.x*blockDim.x){
        int j = i;
        if (j < L_EMBP){ d0[j] = (j < L_EMB) ? cvt1b(s0, j, isb) : (u16)0; continue; } j -= L_EMBP;
        if (j < L_WIOU){ d1[j] = cvt1b(s1, j, isb); continue; } j -= L_WIOU;
        if (j < L_UIOU){ d2[j] = cvt1b(s2, j, isb); continue; } j -= L_UIOU;
        if (j < L_WF){ d3[j] = cvt1b(s3, j, isb); continue; } j -= L_WF;
        d4[j] = cvt1b(s4, j, isb);
    }
}

// fused any->f32 conversion of biases + FC weights
#define S_BIOU 768
#define S_BF   256
#define S_F1W  (128*256)
#define S_F1B  128
#define S_F2W  (3*128)
#define S_F2B  3
#define S_ALL  (S_BIOU+S_BF+S_F1W+S_F1B+S_F2W+S_F2B)
__global__ void k_small(const void* __restrict__ s0, const void* __restrict__ s1,
                        const void* __restrict__ s2, const void* __restrict__ s3,
                        const void* __restrict__ s4, const void* __restrict__ s5,
                        float* __restrict__ d0, float* __restrict__ d1, float* __restrict__ d2,
                        float* __restrict__ d3, float* __restrict__ d4, float* __restrict__ d5,
                        const int* __restrict__ flag){
    int isb = flag[0];
    for (int i = blockIdx.x*blockDim.x + threadIdx.x; i < S_ALL; i += gridDim.x*blockDim.x){
        int j = i;
        if (j < S_BIOU){ d0[j] = cvt1f(s0, j, isb); continue; } j -= S_BIOU;
        if (j < S_BF){ d1[j] = cvt1f(s1, j, isb); continue; } j -= S_BF;
        if (j < S_F1W){ d2[j] = cvt1f(s2, j, isb); continue; } j -= S_F1W;
        if (j < S_F1B){ d3[j] = cvt1f(s3, j, isb); continue; } j -= S_F1B;
        if (j < S_F2W){ d4[j] = cvt1f(s4, j, isb); continue; } j -= S_F2W;
        d5[j] = cvt1f(s5, j, isb);
    }
}

__device__ __forceinline__ s8 ldB16(const u16* p){
    union { uint4 q; s8 v; } u;
    u.q = *(const uint4*)p;
    return u.v;
}
__device__ __forceinline__ s8 ldsA(const u16* p){
    union { unsigned w[4]; s8 v; } u;
    u.w[0] = *(const unsigned*)(p);
    u.w[1] = *(const unsigned*)(p+2);
    u.w[2] = *(const unsigned*)(p+4);
    u.w[3] = *(const unsigned*)(p+6);
    return u.v;
}
#define MFMA(acc,a,b) acc = __builtin_amdgcn_mfma_f32_16x16x32_bf16(a, b, acc, 0, 0, 0)

// ---------------- vocab-space precompute (packed E4[vocab][256][4] = {i,o,u,f}) ----------------
__global__ __launch_bounds__(512, 4)
void k_vocab2(const u16* __restrict__ embb,
              const u16* __restrict__ Wiou, const u16* __restrict__ Wfm,
              const u16* __restrict__ Ufm,  const float* __restrict__ biou_f,
              u16* __restrict__ E4, u16* __restrict__ E_f,
              u16* __restrict__ H0, u16* __restrict__ C0, u16* __restrict__ HU0)
{
    __shared__ u16 hs[32*PAD];    // h0 for the HU0 GEMM
    const int t = threadIdx.x, w = t>>6, lane = t&63, ln = lane&15, q = lane>>4;
    const int r0 = blockIdx.x*32, d0 = w*32;

    const u16* Bp[8];
    #pragma unroll
    for (int g = 0; g < 4; g++)
      #pragma unroll
      for (int nc = 0; nc < 2; nc++){
        int nn = d0 + nc*16 + ln;
        Bp[g*2+nc] = (g < 3) ? (Wiou + (size_t)(g*256+nn)*DD) : (Wfm + (size_t)nn*DD);
      }
    const u16* a0p = embb + (size_t)(r0+ln)*DD;
    const u16* a1p = embb + (size_t)(r0+16+ln)*DD;
    f4 acc[8][2];
    #pragma unroll
    for (int nt = 0; nt < 8; nt++){ acc[nt][0] = (f4){0,0,0,0}; acc[nt][1] = (f4){0,0,0,0}; }
    #pragma unroll 2
    for (int ks = 0; ks < 8; ks++){
        int ko = ks*32 + q*8;
        s8 a0 = ldB16(a0p + ko);
        s8 a1 = ldB16(a1p + ko);
        #pragma unroll
        for (int nt = 0; nt < 8; nt++){
            s8 bb = ldB16(Bp[nt] + ko);
            MFMA(acc[nt][0], a0, bb);
            MFMA(acc[nt][1], a1, bb);
        }
    }
    #pragma unroll
    for (int nc = 0; nc < 2; nc++){
        int d = d0 + nc*16 + ln;
        float bi = biou_f[d], bo = biou_f[256+d], bu = biou_f[512+d];
        #pragma unroll
        for (int ms = 0; ms < 2; ms++)
          #pragma unroll
          for (int r = 0; r < 4; r++){
            int vrow = r0 + ms*16 + q*4 + r;
            float ei = acc[0*2+nc][ms][r];
            float eo = acc[1*2+nc][ms][r];
            float eu = acc[2*2+nc][ms][r];
            float ef = acc[3*2+nc][ms][r];
            union { u16 a[4]; uint2 q2; } pk;
            pk.a[0] = f2bits(ei);
            pk.a[1] = f2bits(eo);
            pk.a[2] = f2bits(eu);
            pk.a[3] = f2bits(ef);
            *(uint2*)(E4 + ((size_t)vrow*DD + d)*4) = pk.q2;
            E_f[(size_t)vrow*DD + d] = f2bits(ef);
            float cc = sigm(ei + bi)*tanh_(eu + bu);
            float hh = sigm(eo + bo)*tanh_(cc);
            C0[(size_t)vrow*DD + d] = f2bits(cc);
            H0[(size_t)vrow*DD + d] = f2bits(hh);
            hs[(ms*16 + q*4 + r)*PAD + d] = f2bits(hh);
        }
    }
    __syncthreads();

    f4 hacc[2][2];
    #pragma unroll
    for (int nt = 0; nt < 2; nt++){ hacc[nt][0] = (f4){0,0,0,0}; hacc[nt][1] = (f4){0,0,0,0}; }
    const u16* Bf0 = Ufm + (size_t)(d0 + ln)*DD;
    const u16* Bf1 = Ufm + (size_t)(d0 + 16 + ln)*DD;
    #pragma unroll 2
    for (int ks = 0; ks < 8; ks++){
        int ko = ks*32 + q*8;
        s8 a0 = ldsA(&hs[ln*PAD + ko]);
        s8 a1 = ldsA(&hs[(16+ln)*PAD + ko]);
        s8 b0 = ldB16(Bf0 + ko);
        s8 b1 = ldB16(Bf1 + ko);
        MFMA(hacc[0][0], a0, b0); MFMA(hacc[0][1], a1, b0);
        MFMA(hacc[1][0], a0, b1); MFMA(hacc[1][1], a1, b1);
    }
    #pragma unroll
    for (int nc = 0; nc < 2; nc++){
        int d = d0 + nc*16 + ln;
        #pragma unroll
        for (int ms = 0; ms < 2; ms++)
          #pragma unroll
          for (int r = 0; r < 4; r++){
            int vrow = r0 + ms*16 + q*4 + r;
            HU0[(size_t)vrow*DD + d] = f2bits(hacc[nc][ms][r]);
        }
    }
}

// ---------------- k_edge0: assemble lvl-1 inputs from vocab tables (proven) ----------------
__global__ __launch_bounds__(512, 4)
void k_edge0(const int* __restrict__ f0, const int* __restrict__ f1, const int* __restrict__ f2,
             const u16* __restrict__ E_f, const u16* __restrict__ H0,
             const u16* __restrict__ C0,  const u16* __restrict__ HU0,
             const float* __restrict__ bf_f,
             u16* __restrict__ hsum_out, u16* __restrict__ fcsum_out)
{
    int gid = blockIdx.x*512 + threadIdx.x;
    int row = gid >> 5, ch = gid & 31, d = ch*8;
    int run = row >> 13, rem = row & 8191, b = rem >> 6, jj = rem & 63;
    const int* fp = (run==0) ? f0 : ((run==1) ? f1 : f2);
    int fo = fp[b*TT + 128 + jj];
    int v1 = fp[b*TT + 2*jj];
    int v2 = fp[b*TT + 2*jj + 1];
    s8 ef  = ldB16(E_f + (size_t)fo*DD + d);
    s8 hu1 = ldB16(HU0 + (size_t)v1*DD + d);
    s8 hu2 = ldB16(HU0 + (size_t)v2*DD + d);
    s8 c1  = ldB16(C0  + (size_t)v1*DD + d);
    s8 c2  = ldB16(C0  + (size_t)v2*DD + d);
    s8 h1  = ldB16(H0  + (size_t)v1*DD + d);
    s8 h2  = ldB16(H0  + (size_t)v2*DD + d);
    union { u16 a[8]; uint4 q4; } uh, uf;
    #pragma unroll
    for (int j = 0; j < 8; j++){
        float e  = bits2f((u16)ef[j]) + bf_f[d+j];
        float fa = sigm(e + bits2f((u16)hu1[j]));
        float fb = sigm(e + bits2f((u16)hu2[j]));
        float fc = fa*bits2f((u16)c1[j]) + fb*bits2f((u16)c2[j]);
        float hsv = bits2f((u16)h1[j]) + bits2f((u16)h2[j]);
        uf.a[j] = f2bits(fc);
        uh.a[j] = f2bits(hsv);
    }
    *(uint4*)(hsum_out  + (size_t)row*DD + d) = uh.q4;
    *(uint4*)(fcsum_out + (size_t)row*DD + d) = uf.q4;
}

// ---------------- per-level kernel (v6 == R5 proven: 81us lvl-1, VGPR 64) ----------------
__global__ __launch_bounds__(512, 4)
void k_lvl(int lvl, int cLog,
           const int* __restrict__ f0, const int* __restrict__ f1, const int* __restrict__ f2,
           const u16* __restrict__ E4, const u16* __restrict__ E_f,
           const u16* __restrict__ Uiou, const u16* __restrict__ Ufm,
           const float* __restrict__ biou_f, const float* __restrict__ bf_f,
           const u16* __restrict__ hsum_in, const u16* __restrict__ fcsum_in,
           u16* __restrict__ hsum_out, u16* __restrict__ fcsum_out,
           u16* __restrict__ hroot)
{
    __shared__ u16 hs[32*PAD];     // 16.5 KB: h transpose for GEMM-C
    __shared__ u16 hso[16*OPAD];   // 8.4 KB: staged hsum_out rows
    __shared__ u16 fco[16*OPAD];   // 8.4 KB: staged fcsum_out rows
    __shared__ int sfr[32];        // this block's 32 node feats (epilogue E4 rows)
    const int t = threadIdx.x, w = t>>6, lane = t&63, ln = lane&15, q = lane>>4;
    const int cnt = 1 << cLog, S = 256 - 2*cnt;
    const int r0 = blockIdx.x*32, d0 = w*32;
    const bool haveP = (lvl < 7);

    // ---- stage this block's 32 node feats into LDS (128 B) ----
    if (t < 32){
        int rho = r0 + t;
        int run = rho >> (7+cLog);
        int rem = rho & ((1<<(7+cLog)) - 1);
        int b = rem >> cLog, jj = rem & (cnt-1);
        const int* fp = (run==0) ? f0 : ((run==1) ? f1 : f2);
        sfr[t] = fp[b*TT + S + jj];
    }

    // parent feats for GEMM-C epilogue
    int featp[2][2];
    if (haveP){
        #pragma unroll
        for (int ms = 0; ms < 2; ms++)
          #pragma unroll
          for (int rr = 0; rr < 2; rr++){
            int rho = r0 + ms*16 + q*4 + rr*2;
            int run = rho >> (7+cLog);
            int rem = rho & ((1<<(7+cLog)) - 1);
            int b = rem >> cLog, jj = rem & (cnt-1);
            const int* fp = (run==0) ? f0 : ((run==1) ? f1 : f2);
            featp[ms][rr] = fp[b*TT + (256-cnt) + (jj>>1)];
          }
    }
    __syncthreads();   // sfr visible to all

    // ---- GEMM-U: hsum_in @ Uiou^T ----
    f4 acc[6][2];
    #pragma unroll
    for (int nt = 0; nt < 6; nt++){ acc[nt][0] = (f4){0,0,0,0}; acc[nt][1] = (f4){0,0,0,0}; }
    {
        const u16* a0p = hsum_in + (size_t)(r0+ln)*DD;
        const u16* a1p = hsum_in + (size_t)(r0+16+ln)*DD;
        const u16* Bp[6];
        #pragma unroll
        for (int nt = 0; nt < 6; nt++){
            int n = (nt>>1)*256 + d0 + (nt&1)*16 + ln;
            Bp[nt] = Uiou + (size_t)n*DD;
        }
        #pragma unroll 2
        for (int ks = 0; ks < 8; ks++){
            int ko = ks*32 + q*8;
            s8 a0 = ldB16(a0p + ko);
            s8 a1 = ldB16(a1p + ko);
            #pragma unroll
            for (int nt = 0; nt < 6; nt++){
                s8 bb = ldB16(Bp[nt] + ko);
                MFMA(acc[nt][0], a0, bb);
                MFMA(acc[nt][1], a1, bb);
            }
        }
    }

    // ---- epilogue: cell update with packed E4 read (one uint2/thread/iter) ----
    float cv[2][2][4];
    #pragma unroll
    for (int nc = 0; nc < 2; nc++){
        int d = d0 + nc*16 + ln;
        float bi = biou_f[d], bo = biou_f[256+d], bu = biou_f[512+d];
        #pragma unroll
        for (int ms = 0; ms < 2; ms++){
            float hv[4];
            #pragma unroll
            for (int r = 0; r < 4; r++){
                int m   = ms*16 + q*4 + r;
                int rho = r0 + m;
                union { uint2 q2; u16 a[4]; } ev;
                ev.q2 = *(const uint2*)(E4 + ((size_t)sfr[m]*DD + d)*4);
                float iv = acc[0+nc][ms][r] + bits2f(ev.a[0]) + bi;
                float ov = acc[2+nc][ms][r] + bits2f(ev.a[1]) + bo;
                float uv = acc[4+nc][ms][r] + bits2f(ev.a[2]) + bu;
                float cs = bits2f(fcsum_in[(size_t)rho*DD + d]);
                float c = sigm(iv)*tanh_(uv) + cs;
                float h = sigm(ov)*tanh_(c);
                cv[nc][ms][r] = c;
                hv[r] = h;
                if (haveP) hs[m*PAD + d] = f2bits(h);
                else       hroot[(size_t)rho*DD + d] = f2bits(h);
            }
            if (haveP){
                int lr = ms*8 + q*2;
                hso[lr*OPAD + d]     = f2bits(hv[0] + hv[1]);
                hso[(lr+1)*OPAD + d] = f2bits(hv[2] + hv[3]);
            }
        }
    }

    // ---- GEMM-C: hU = h@Uf^T, fc = sig(E_f[parent]+bf+hU)*c, pair-reduce ----
    if (haveP){
        __syncthreads();
        f4 hacc[2][2];
        #pragma unroll
        for (int nt = 0; nt < 2; nt++){ hacc[nt][0] = (f4){0,0,0,0}; hacc[nt][1] = (f4){0,0,0,0}; }
        const u16* Bf0 = Ufm + (size_t)(d0 + ln)*DD;
        const u16* Bf1 = Ufm + (size_t)(d0 + 16 + ln)*DD;
        #pragma unroll 2
        for (int ks = 0; ks < 8; ks++){
            int ko = ks*32 + q*8;
            s8 a0 = ldsA(&hs[ln*PAD + ko]);
            s8 a1 = ldsA(&hs[(16+ln)*PAD + ko]);
            s8 b0 = ldB16(Bf0 + ko);
            s8 b1 = ldB16(Bf1 + ko);
            MFMA(hacc[0][0], a0, b0); MFMA(hacc[0][1], a1, b0);
            MFMA(hacc[1][0], a0, b1); MFMA(hacc[1][1], a1, b1);
        }
        #pragma unroll
        for (int nc = 0; nc < 2; nc++){
            int d = d0 + nc*16 + ln;
            float bfv = bf_f[d];
            #pragma unroll
            for (int ms = 0; ms < 2; ms++){
                float fs0, fs1;
                #pragma unroll
                for (int r = 0; r < 4; r++){
                    float ef = bits2f(E_f[(size_t)featp[ms][r>>1]*DD + d]);
                    float fc = sigm(ef + bfv + hacc[nc][ms][r]) * cv[nc][ms][r];
                    if (r == 0) fs0 = fc;
                    else if (r == 1) fs0 += fc;
                    else if (r == 2) fs1 = fc;
                    else fs1 += fc;
                }
                int lr = ms*8 + q*2;
                fco[lr*OPAD + d]     = f2bits(fs0);
                fco[(lr+1)*OPAD + d] = f2bits(fs1);
            }
        }

        // ---- single coalesced write pass: full 128B lines, written once ----
        __syncthreads();
        {
            int row = t >> 5, c = (t & 31) * 8;
            int prow = (r0 >> 1) + row;
            uint4 vh = *(const uint4*)&hso[row*OPAD + c];
            uint4 vf = *(const uint4*)&fco[row*OPAD + c];
            *(uint4*)(hsum_out  + (size_t)prow*DD + c) = vh;
            *(uint4*)(fcsum_out + (size_t)prow*DD + c) = vf;
        }
    }
}

// ---------------- k_tail: levels 4..7 fused, block = 4 trees ----------------
// R7 post-mortem: k_tail at (512,4) reported VGPR 92 -- its live state (acc 48 +
// hacc 16 + cv 16 acc-class regs + pointers/staging) exceeds the 128-reg budget
// -> scratch spills. Spill working set (~50 KB/CU) is L2-resident so it never
// showed in FETCH/WRITE, but each reload injects a serialized L2 round trip into
// the per-level chain (observed ~24 us/level vs ~5 us first-principles).
// k_tail's LDS (84 KB) already caps it at 1 block/CU = 8 waves, so unlike k_lvl
// (R6 lesson) there is NO occupancy to lose: (512,2) = 256 regs/wave, spill-free,
// same residency.
__global__ __launch_bounds__(512, 2)
void k_tail(const int* __restrict__ f0, const int* __restrict__ f1, const int* __restrict__ f2,
            const u16* __restrict__ E4, const u16* __restrict__ E_f,
            const u16* __restrict__ Uiou, const u16* __restrict__ Ufm,
            const float* __restrict__ biou_f, const float* __restrict__ bf_f,
            const u16* __restrict__ hsum_in, const u16* __restrict__ fcsum_in,
            u16* __restrict__ hroot)
{
    __shared__ u16 hs[32*PAD];        // 16.5 KB: h transpose for GEMM-C
    __shared__ u16 hsP[2][32*PAD];    // 33 KB: hsum carry ping-pong
    __shared__ u16 fcP[2][32*FPAD];   // 33.8 KB: fcsum carry ping-pong
    __shared__ int sf[64];            // 4 trees x 16 feats (heap slots 240..254)
    const int t = threadIdx.x, w = t>>6, lane = t&63, ln = lane&15, q = lane>>4;
    const int d0 = w*32;
    const int r0 = blockIdx.x*32;                 // lvl-4 global row base
    const int run = (blockIdx.x*4) >> 7;          // all 4 trees share one run
    const int* __restrict__ fp = (run==0) ? f0 : ((run==1) ? f1 : f2);

    if (t < 64){
        int ti = t >> 4, idx = t & 15;
        int b = (blockIdx.x*4 + ti) & 127;
        sf[t] = (idx < 15) ? fp[b*TT + 240 + idx] : 0;
    }
    __syncthreads();

    // B pointers constant across levels
    const u16* Bp[6];
    #pragma unroll
    for (int nt = 0; nt < 6; nt++){
        int n = (nt>>1)*256 + d0 + (nt&1)*16 + ln;
        Bp[nt] = Uiou + (size_t)n*DD;
    }
    const u16* Bf0 = Ufm + (size_t)(d0 + ln)*DD;
    const u16* Bf1 = Ufm + (size_t)(d0 + 16 + ln)*DD;

    for (int l = 4; l <= 7; l++){
        const int nl = 128 >> l;        // nodes per tree at this level (8,4,2,1)
        const int nrows = 4*nl;         // valid rows in block (32,16,8,4)
        const int sh = 7 - l;           // local m -> tree index shift
        const int inb = (l-1) & 1, outb = l & 1;
        const bool haveP = (l < 7);

        // ---- GEMM-U: A from global (lvl4) or LDS carry ----
        f4 acc[6][2];
        #pragma unroll
        for (int nt = 0; nt < 6; nt++){ acc[nt][0] = (f4){0,0,0,0}; acc[nt][1] = (f4){0,0,0,0}; }
        if (l == 4){
            const u16* a0p = hsum_in + (size_t)(r0+ln)*DD;
            const u16* a1p = hsum_in + (size_t)(r0+16+ln)*DD;
            #pragma unroll 2
            for (int ks = 0; ks < 8; ks++){
                int ko = ks*32 + q*8;
                s8 a0 = ldB16(a0p + ko);
                s8 a1 = ldB16(a1p + ko);
                #pragma unroll
                for (int nt = 0; nt < 6; nt++){
                    s8 bb = ldB16(Bp[nt] + ko);
                    MFMA(acc[nt][0], a0, bb);
                    MFMA(acc[nt][1], a1, bb);
                }
            }
        } else {
            const u16* a0l = &hsP[inb][ln*PAD];
            const u16* a1l = &hsP[inb][(16+ln)*PAD];
            #pragma unroll 2
            for (int ks = 0; ks < 8; ks++){
                int ko = ks*32 + q*8;
                s8 a0 = ldsA(a0l + ko);
                s8 a1 = ldsA(a1l + ko);
                #pragma unroll
                for (int nt = 0; nt < 6; nt++){
                    s8 bb = ldB16(Bp[nt] + ko);
                    MFMA(acc[nt][0], a0, bb);
                    MFMA(acc[nt][1], a1, bb);
                }
            }
        }

        // ---- epilogue: cell update; hsum pair-reduce into hsP[outb] ----
        float cv[2][2][4];
        #pragma unroll
        for (int nc = 0; nc < 2; nc++){
            int d = d0 + nc*16 + ln;
            float bi = biou_f[d], bo = biou_f[256+d], bu = biou_f[512+d];
            #pragma unroll
            for (int ms = 0; ms < 2; ms++){
                float hv[4];
                #pragma unroll
                for (int r = 0; r < 4; r++){
                    int m = ms*16 + q*4 + r;
                    bool vld = (m < nrows);
                    int mc = vld ? m : 0;
                    int ti = mc >> sh, jj = mc & (nl-1);
                    int fidx = sf[ti*16 + (16 - 2*nl) + jj];
                    union { uint2 q2; u16 a[4]; } ev;
                    ev.q2 = *(const uint2*)(E4 + ((size_t)fidx*DD + d)*4);
                    float iv = acc[0+nc][ms][r] + bits2f(ev.a[0]) + bi;
                    float ov = acc[2+nc][ms][r] + bits2f(ev.a[1]) + bo;
                    float uv = acc[4+nc][ms][r] + bits2f(ev.a[2]) + bu;
                    float cs = (l == 4) ? bits2f(fcsum_in[(size_t)(r0+m)*DD + d])
                                        : bits2f(fcP[inb][m*FPAD + d]);
                    float c = sigm(iv)*tanh_(uv) + cs;
                    float h = sigm(ov)*tanh_(c);
                    cv[nc][ms][r] = c;
                    hv[r] = h;
                    if (haveP) hs[m*PAD + d] = f2bits(h);
                    else if (vld) hroot[(size_t)(blockIdx.x*4 + m)*DD + d] = f2bits(h);
                }
                if (haveP){
                    int lr = ms*8 + q*2;
                    hsP[outb][lr*PAD + d]     = f2bits(hv[0] + hv[1]);
                    hsP[outb][(lr+1)*PAD + d] = f2bits(hv[2] + hv[3]);
                }
            }
        }

        // ---- GEMM-C -> fcP[outb] ----
        if (haveP){
            __syncthreads();
            f4 hacc[2][2];
            #pragma unroll
            for (int nt = 0; nt < 2; nt++){ hacc[nt][0] = (f4){0,0,0,0}; hacc[nt][1] = (f4){0,0,0,0}; }
            #pragma unroll 2
            for (int ks = 0; ks < 8; ks++){
                int ko = ks*32 + q*8;
                s8 a0 = ldsA(&hs[ln*PAD + ko]);
                s8 a1 = ldsA(&hs[(16+ln)*PAD + ko]);
                s8 b0 = ldB16(Bf0 + ko);
                s8 b1 = ldB16(Bf1 + ko);
                MFMA(hacc[0][0], a0, b0); MFMA(hacc[0][1], a1, b0);
                MFMA(hacc[1][0], a0, b1); MFMA(hacc[1][1], a1, b1);
            }
            #pragma unroll
            for (int nc = 0; nc < 2; nc++){
                int d = d0 + nc*16 + ln;
                float bfv = bf_f[d];
                #pragma unroll
                for (int ms = 0; ms < 2; ms++){
                    float fs0, fs1;
                    #pragma unroll
                    for (int r = 0; r < 4; r++){
                        int m2 = ms*16 + q*4 + (r & 2);
                        int mc2 = (m2 < nrows) ? m2 : 0;
                        int ti2 = mc2 >> sh, jj2 = mc2 & (nl-1);
                        int fpar = sf[ti2*16 + (16 - nl) + (jj2 >> 1)];
                        float ef = bits2f(E_f[(size_t)fpar*DD + d]);
                        float fc = sigm(ef + bfv + hacc[nc][ms][r]) * cv[nc][ms][r];
                        if (r == 0) fs0 = fc;
                        else if (r == 1) fs0 += fc;
                        else if (r == 2) fs1 = fc;
                        else fs1 += fc;
                    }
                    int lr = ms*8 + q*2;
                    fcP[outb][lr*FPAD + d]     = f2bits(fs0);
                    fcP[outb][(lr+1)*FPAD + d] = f2bits(fs1);
                }
            }
            __syncthreads();   // carry buffers ready for next level
        }
    }
}

// ---------------- final: bilinear combine + MLP (proven epilogue) ----------------
__global__ __launch_bounds__(256)
void k_final(const u16* __restrict__ hroot,
             const float* __restrict__ fc1w, const float* __restrict__ fc1b,
             const float* __restrict__ fc2w, const float* __restrict__ fc2b,
             void* __restrict__ out, const int* __restrict__ flag)
{
    int b = blockIdx.x, t = threadIdx.x;
    __shared__ float sprod[DD];
    __shared__ float shb[DD];
    __shared__ float shid[128];
    float hc  = bits2f(hroot[(0*NTREE + b)*DD + t]);
    float ha  = bits2f(hroot[(1*NTREE + b)*DD + t]);
    float hbv = bits2f(hroot[(2*NTREE + b)*DD + t]);
    sprod[t] = hc * ha;
    shb[t]   = hbv;
    __syncthreads();
    for (int s = 128; s > 0; s >>= 1){
        if (t < s) sprod[t] += sprod[t + s];
        __syncthreads();
    }
    float dot = sprod[0];
    if (t < 128){
        float acc = fc1b[t];
        for (int k = 0; k < DD; k++)
            acc = fmaf(dot * shb[k], fc1w[t*DD + k], acc);
        shid[t] = fmaxf(acc, 0.f);
    }
    __syncthreads();
    if (t < 3){
        float acc = fc2b[t];
        for (int j = 0; j < 128; j++)
            acc = fmaf(fc2w[t*128 + j], shid[j], acc);
        float v = fmaxf(acc, 0.f);
        if (flag[0]) ((bf16*)out)[b*3 + t] = __float2bfloat16(v);
        else         ((float*)out)[b*3 + t] = v;
    }
}

extern "C" void kernel_launch(void* const* d_in, const int* in_sizes, int n_in,
                              void* d_out, int out_size, void* d_ws, size_t ws_size,
                              hipStream_t stream)
{
    const int* f0 = (const int*)d_in[0];
    const int* f1 = (const int*)d_in[1];
    const int* f2 = (const int*)d_in[2];
    // d_in[3..7] static forest metadata — unused (structure compile-time known)
    const void* emb  = d_in[8];
    const void* Wiou = d_in[9];
    const void* biou = d_in[10];
    const void* Uiou = d_in[11];
    const void* Wf   = d_in[12];
    const void* bfv  = d_in[13];
    const void* Uf   = d_in[14];
    const void* fc1w = d_in[15];
    const void* fc1b = d_in[16];
    const void* fc2w = d_in[17];
    const void* fc2b = d_in[18];

    char* base = (char*)d_ws;
    size_t off = 0;
    auto take = [&](size_t bytes) -> char* {
        char* p = base + off;
        off = (off + bytes + 255) & ~(size_t)255;
        return p;
    };
    int*   flag   = (int*)  take(256);
    u16*   embb   = (u16*)  take((size_t)L_EMBP*2);
    u16*   wioub  = (u16*)  take((size_t)L_WIOU*2);
    u16*   uioub  = (u16*)  take((size_t)L_UIOU*2);
    u16*   wfb    = (u16*)  take((size_t)L_WF*2);
    u16*   ufb    = (u16*)  take((size_t)L_UF*2);
    float* biou_f = (float*)take(S_BIOU*4);
    float* bf_f   = (float*)take(S_BF*4);
    float* fc1w_f = (float*)take(S_F1W*4);
    float* fc1b_f = (float*)take(S_F1B*4);
    float* fc2w_f = (float*)take(S_F2W*4);
    float* fc2b_f = (float*)take(S_F2B*4);
    u16*   E4     = (u16*)  take((size_t)VPAD*DD*4*2);     // 20.5 MB packed {i,o,u,f}
    u16*   E_f    = (u16*)  take((size_t)VPAD*DD*2);       // 5.13 MB
    u16*   H0     = (u16*)  take((size_t)VPAD*DD*2);
    u16*   C0     = (u16*)  take((size_t)VPAD*DD*2);
    u16*   HU0    = (u16*)  take((size_t)VPAD*DD*2);
    u16*   HA     = (u16*)  take((size_t)24576*DD*2);
    u16*   HB     = (u16*)  take((size_t)12288*DD*2);
    u16*   FA     = (u16*)  take((size_t)24576*DD*2);
    u16*   FB     = (u16*)  take((size_t)12288*DD*2);
    u16*   hroot  = (u16*)  take((size_t)NRUNS*NTREE*DD*2);
    // total ~85 MB (< proven 119 MB)

    k_detect<<<1, 256, 0, stream>>>((const u16*)emb, flag);
    k_cvtb<<<2048, 256, 0, stream>>>(emb, Wiou, Uiou, Wf, Uf,
                                     embb, wioub, uioub, wfb, ufb, flag);
    k_small<<<135, 256, 0, stream>>>(biou, bfv, fc1w, fc1b, fc2w, fc2b,
                                     biou_f, bf_f, fc1w_f, fc1b_f, fc2w_f, fc2b_f, flag);
    k_vocab2<<<VPAD/32, 512, 0, stream>>>(embb, wioub, wfb, ufb, biou_f,
                                          E4, E_f, H0, C0, HU0);
    k_edge0<<<24576*32/512, 512, 0, stream>>>(f0, f1, f2, E_f, H0, C0, HU0, bf_f, HA, FA);

    for (int lvl = 1; lvl <= 3; lvl++){
        int cLog = 7 - lvl;
        int rows = NRUNS*NTREE*(128 >> lvl);
        int blocks = rows / 32;
        int pe = lvl & 1;
        u16* hs_o = pe ? HB : HA;
        u16* fc_o = pe ? FB : FA;
        const u16* hs_i = pe ? HA : HB;
        const u16* fc_i = pe ? FA : FB;
        k_lvl<<<blocks, 512, 0, stream>>>(lvl, cLog, f0, f1, f2,
                                          E4, E_f, uioub, ufb,
                                          biou_f, bf_f,
                                          hs_i, fc_i, hs_o, fc_o, hroot);
    }
    // lvl3 (pe=1) wrote HB/FB -> k_tail consumes them for lvl4..7
    k_tail<<<(NRUNS*NTREE)/4, 512, 0, stream>>>(f0, f1, f2, E4, E_f, uioub, ufb,
                                                biou_f, bf_f, HB, FB, hroot);
    k_final<<<NTREE, 256, 0, stream>>>(hroot, fc1w_f, fc1b_f, fc2w_f, fc2b_f, d_out, flag);
}

// Round 9
// 423.123 us; speedup vs baseline: 1.0984x; 1.0192x over previous
//
#include <hip/hip_runtime.h>
#include <hip/hip_bf16.h>

typedef __hip_bfloat16 bf16;
typedef unsigned short u16;
typedef __attribute__((ext_vector_type(8))) short s8;   // 8 bf16 = one MFMA A/B fragment
typedef __attribute__((ext_vector_type(4))) float f4;   // MFMA C/D fragment

#define NRUNS 3
#define NTREE 128
#define TT    255
#define DD    256
#define VPAD  10016    /* vocab padded to 32 */
#define PAD   258      /* LDS row stride in u16 for 256-wide rows */
#define OPAD  264      /* output-staging stride: uint4-aligned (528B), bank-staggered */
#define FPAD  264      /* fcP carry stride in k_tail (528B breaks 512B bank aliasing) */

__device__ __forceinline__ float bits2f(u16 b){ union{unsigned u; float f;} x; x.u = ((unsigned)b)<<16; return x.f; }
__device__ __forceinline__ u16   f2bits(float f){ bf16 h = __float2bfloat16(f); return *(u16*)&h; }
__device__ __forceinline__ float sigm(float x){ return 1.f/(1.f+__expf(-x)); }
__device__ __forceinline__ float tanh_(float x){ return 1.f - 2.f/(__expf(2.f*x)+1.f); }

// ---------------- dtype autodetect (proven) ----------------
__global__ void k_detect(const u16* __restrict__ raw, int* __restrict__ flag){
    int t = threadIdx.x;
    int hit = 0;
    if (t < 128){
        u16 w = raw[2*t];
        int e = (w >> 7) & 0xFF;
        hit = (e >= 100 && e <= 141) ? 1 : 0;
    }
    __shared__ int cnt;
    if (t == 0) cnt = 0;
    __syncthreads();
    atomicAdd(&cnt, hit);
    __syncthreads();
    if (t == 0) flag[0] = (cnt >= 64) ? 1 : 0;
}

__device__ __forceinline__ u16 cvt1b(const void* p, int i, int isb){
    return isb ? ((const u16*)p)[i] : f2bits(((const float*)p)[i]);
}
__device__ __forceinline__ float cvt1f(const void* p, int i, int isb){
    return isb ? bits2f(((const u16*)p)[i]) : ((const float*)p)[i];
}

// fused any->bf16 conversion: emb (zero-padded to VPAD rows) + 4 weights
#define L_EMB  (10000*256)
#define L_EMBP (VPAD*256)
#define L_WIOU (768*256)
#define L_UIOU (768*256)
#define L_WF   (256*256)
#define L_UF   (256*256)
#define L_ALL  (L_EMBP + L_WIOU + L_UIOU + L_WF + L_UF)
__global__ void k_cvtb(const void* __restrict__ s0, const void* __restrict__ s1,
                       const void* __restrict__ s2, const void* __restrict__ s3,
                       const void* __restrict__ s4,
                       u16* __restrict__ d0, u16* __restrict__ d1, u16* __restrict__ d2,
                       u16* __restrict__ d3, u16* __restrict__ d4,
                       const int* __restrict__ flag){
    int isb = flag[0];
    for (int i = blockIdx.x*blockDim.x + threadIdx.x; i < L_ALL; i += gridDim.x*blockDim.x){
        int j = i;
        if (j < L_EMBP){ d0[j] = (j < L_EMB) ? cvt1b(s0, j, isb) : (u16)0; continue; } j -= L_EMBP;
        if (j < L_WIOU){ d1[j] = cvt1b(s1, j, isb); continue; } j -= L_WIOU;
        if (j < L_UIOU){ d2[j] = cvt1b(s2, j, isb); continue; } j -= L_UIOU;
        if (j < L_WF){ d3[j] = cvt1b(s3, j, isb); continue; } j -= L_WF;
        d4[j] = cvt1b(s4, j, isb);
    }
}

// fused any->f32 conversion of biases + FC weights
#define S_BIOU 768
#define S_BF   256
#define S_F1W  (128*256)
#define S_F1B  128
#define S_F2W  (3*128)
#define S_F2B  3
#define S_ALL  (S_BIOU+S_BF+S_F1W+S_F1B+S_F2W+S_F2B)
__global__ void k_small(const void* __restrict__ s0, const void* __restrict__ s1,
                        const void* __restrict__ s2, const void* __restrict__ s3,
                        const void* __restrict__ s4, const void* __restrict__ s5,
                        float* __restrict__ d0, float* __restrict__ d1, float* __restrict__ d2,
                        float* __restrict__ d3, float* __restrict__ d4, float* __restrict__ d5,
                        const int* __restrict__ flag){
    int isb = flag[0];
    for (int i = blockIdx.x*blockDim.x + threadIdx.x; i < S_ALL; i += gridDim.x*blockDim.x){
        int j = i;
        if (j < S_BIOU){ d0[j] = cvt1f(s0, j, isb); continue; } j -= S_BIOU;
        if (j < S_BF){ d1[j] = cvt1f(s1, j, isb); continue; } j -= S_BF;
        if (j < S_F1W){ d2[j] = cvt1f(s2, j, isb); continue; } j -= S_F1W;
        if (j < S_F1B){ d3[j] = cvt1f(s3, j, isb); continue; } j -= S_F1B;
        if (j < S_F2W){ d4[j] = cvt1f(s4, j, isb); continue; } j -= S_F2W;
        d5[j] = cvt1f(s5, j, isb);
    }
}

__device__ __forceinline__ s8 ldB16(const u16* p){
    union { uint4 q; s8 v; } u;
    u.q = *(const uint4*)p;
    return u.v;
}
__device__ __forceinline__ s8 ldsA(const u16* p){
    union { unsigned w[4]; s8 v; } u;
    u.w[0] = *(const unsigned*)(p);
    u.w[1] = *(const unsigned*)(p+2);
    u.w[2] = *(const unsigned*)(p+4);
    u.w[3] = *(const unsigned*)(p+6);
    return u.v;
}
#define MFMA(acc,a,b) acc = __builtin_amdgcn_mfma_f32_16x16x32_bf16(a, b, acc, 0, 0, 0)

// ---------------- vocab-space precompute (packed E4[vocab][256][4] = {i,o,u,f}) ----------------
__global__ __launch_bounds__(512, 4)
void k_vocab2(const u16* __restrict__ embb,
              const u16* __restrict__ Wiou, const u16* __restrict__ Wfm,
              const u16* __restrict__ Ufm,  const float* __restrict__ biou_f,
              u16* __restrict__ E4, u16* __restrict__ E_f,
              u16* __restrict__ H0, u16* __restrict__ C0, u16* __restrict__ HU0)
{
    __shared__ u16 hs[32*PAD];    // h0 for the HU0 GEMM
    const int t = threadIdx.x, w = t>>6, lane = t&63, ln = lane&15, q = lane>>4;
    const int r0 = blockIdx.x*32, d0 = w*32;

    const u16* Bp[8];
    #pragma unroll
    for (int g = 0; g < 4; g++)
      #pragma unroll
      for (int nc = 0; nc < 2; nc++){
        int nn = d0 + nc*16 + ln;
        Bp[g*2+nc] = (g < 3) ? (Wiou + (size_t)(g*256+nn)*DD) : (Wfm + (size_t)nn*DD);
      }
    const u16* a0p = embb + (size_t)(r0+ln)*DD;
    const u16* a1p = embb + (size_t)(r0+16+ln)*DD;
    f4 acc[8][2];
    #pragma unroll
    for (int nt = 0; nt < 8; nt++){ acc[nt][0] = (f4){0,0,0,0}; acc[nt][1] = (f4){0,0,0,0}; }
    #pragma unroll 2
    for (int ks = 0; ks < 8; ks++){
        int ko = ks*32 + q*8;
        s8 a0 = ldB16(a0p + ko);
        s8 a1 = ldB16(a1p + ko);
        #pragma unroll
        for (int nt = 0; nt < 8; nt++){
            s8 bb = ldB16(Bp[nt] + ko);
            MFMA(acc[nt][0], a0, bb);
            MFMA(acc[nt][1], a1, bb);
        }
    }
    #pragma unroll
    for (int nc = 0; nc < 2; nc++){
        int d = d0 + nc*16 + ln;
        float bi = biou_f[d], bo = biou_f[256+d], bu = biou_f[512+d];
        #pragma unroll
        for (int ms = 0; ms < 2; ms++)
          #pragma unroll
          for (int r = 0; r < 4; r++){
            int vrow = r0 + ms*16 + q*4 + r;
            float ei = acc[0*2+nc][ms][r];
            float eo = acc[1*2+nc][ms][r];
            float eu = acc[2*2+nc][ms][r];
            float ef = acc[3*2+nc][ms][r];
            union { u16 a[4]; uint2 q2; } pk;
            pk.a[0] = f2bits(ei);
            pk.a[1] = f2bits(eo);
            pk.a[2] = f2bits(eu);
            pk.a[3] = f2bits(ef);
            *(uint2*)(E4 + ((size_t)vrow*DD + d)*4) = pk.q2;
            E_f[(size_t)vrow*DD + d] = f2bits(ef);
            float cc = sigm(ei + bi)*tanh_(eu + bu);
            float hh = sigm(eo + bo)*tanh_(cc);
            C0[(size_t)vrow*DD + d] = f2bits(cc);
            H0[(size_t)vrow*DD + d] = f2bits(hh);
            hs[(ms*16 + q*4 + r)*PAD + d] = f2bits(hh);
        }
    }
    __syncthreads();

    f4 hacc[2][2];
    #pragma unroll
    for (int nt = 0; nt < 2; nt++){ hacc[nt][0] = (f4){0,0,0,0}; hacc[nt][1] = (f4){0,0,0,0}; }
    const u16* Bf0 = Ufm + (size_t)(d0 + ln)*DD;
    const u16* Bf1 = Ufm + (size_t)(d0 + 16 + ln)*DD;
    #pragma unroll 2
    for (int ks = 0; ks < 8; ks++){
        int ko = ks*32 + q*8;
        s8 a0 = ldsA(&hs[ln*PAD + ko]);
        s8 a1 = ldsA(&hs[(16+ln)*PAD + ko]);
        s8 b0 = ldB16(Bf0 + ko);
        s8 b1 = ldB16(Bf1 + ko);
        MFMA(hacc[0][0], a0, b0); MFMA(hacc[0][1], a1, b0);
        MFMA(hacc[1][0], a0, b1); MFMA(hacc[1][1], a1, b1);
    }
    #pragma unroll
    for (int nc = 0; nc < 2; nc++){
        int d = d0 + nc*16 + ln;
        #pragma unroll
        for (int ms = 0; ms < 2; ms++)
          #pragma unroll
          for (int r = 0; r < 4; r++){
            int vrow = r0 + ms*16 + q*4 + r;
            HU0[(size_t)vrow*DD + d] = f2bits(hacc[nc][ms][r]);
        }
    }
}

// ---------------- k_edge0: assemble lvl-1 inputs from vocab tables (proven) ----------------
__global__ __launch_bounds__(512, 4)
void k_edge0(const int* __restrict__ f0, const int* __restrict__ f1, const int* __restrict__ f2,
             const u16* __restrict__ E_f, const u16* __restrict__ H0,
             const u16* __restrict__ C0,  const u16* __restrict__ HU0,
             const float* __restrict__ bf_f,
             u16* __restrict__ hsum_out, u16* __restrict__ fcsum_out)
{
    int gid = blockIdx.x*512 + threadIdx.x;
    int row = gid >> 5, ch = gid & 31, d = ch*8;
    int run = row >> 13, rem = row & 8191, b = rem >> 6, jj = rem & 63;
    const int* fp = (run==0) ? f0 : ((run==1) ? f1 : f2);
    int fo = fp[b*TT + 128 + jj];
    int v1 = fp[b*TT + 2*jj];
    int v2 = fp[b*TT + 2*jj + 1];
    s8 ef  = ldB16(E_f + (size_t)fo*DD + d);
    s8 hu1 = ldB16(HU0 + (size_t)v1*DD + d);
    s8 hu2 = ldB16(HU0 + (size_t)v2*DD + d);
    s8 c1  = ldB16(C0  + (size_t)v1*DD + d);
    s8 c2  = ldB16(C0  + (size_t)v2*DD + d);
    s8 h1  = ldB16(H0  + (size_t)v1*DD + d);
    s8 h2  = ldB16(H0  + (size_t)v2*DD + d);
    union { u16 a[8]; uint4 q4; } uh, uf;
    #pragma unroll
    for (int j = 0; j < 8; j++){
        float e  = bits2f((u16)ef[j]) + bf_f[d+j];
        float fa = sigm(e + bits2f((u16)hu1[j]));
        float fb = sigm(e + bits2f((u16)hu2[j]));
        float fc = fa*bits2f((u16)c1[j]) + fb*bits2f((u16)c2[j]);
        float hsv = bits2f((u16)h1[j]) + bits2f((u16)h2[j]);
        uf.a[j] = f2bits(fc);
        uh.a[j] = f2bits(hsv);
    }
    *(uint4*)(hsum_out  + (size_t)row*DD + d) = uh.q4;
    *(uint4*)(fcsum_out + (size_t)row*DD + d) = uf.q4;
}

// ---------------- per-level kernel (v6 == R5 proven: 81us lvl-1, VGPR 64) ----------------
__global__ __launch_bounds__(512, 4)
void k_lvl(int lvl, int cLog,
           const int* __restrict__ f0, const int* __restrict__ f1, const int* __restrict__ f2,
           const u16* __restrict__ E4, const u16* __restrict__ E_f,
           const u16* __restrict__ Uiou, const u16* __restrict__ Ufm,
           const float* __restrict__ biou_f, const float* __restrict__ bf_f,
           const u16* __restrict__ hsum_in, const u16* __restrict__ fcsum_in,
           u16* __restrict__ hsum_out, u16* __restrict__ fcsum_out,
           u16* __restrict__ hroot)
{
    __shared__ u16 hs[32*PAD];     // 16.5 KB: h transpose for GEMM-C
    __shared__ u16 hso[16*OPAD];   // 8.4 KB: staged hsum_out rows
    __shared__ u16 fco[16*OPAD];   // 8.4 KB: staged fcsum_out rows
    __shared__ int sfr[32];        // this block's 32 node feats (epilogue E4 rows)
    const int t = threadIdx.x, w = t>>6, lane = t&63, ln = lane&15, q = lane>>4;
    const int cnt = 1 << cLog, S = 256 - 2*cnt;
    const int r0 = blockIdx.x*32, d0 = w*32;
    const bool haveP = (lvl < 7);

    // ---- stage this block's 32 node feats into LDS (128 B) ----
    if (t < 32){
        int rho = r0 + t;
        int run = rho >> (7+cLog);
        int rem = rho & ((1<<(7+cLog)) - 1);
        int b = rem >> cLog, jj = rem & (cnt-1);
        const int* fp = (run==0) ? f0 : ((run==1) ? f1 : f2);
        sfr[t] = fp[b*TT + S + jj];
    }

    // parent feats for GEMM-C epilogue
    int featp[2][2];
    if (haveP){
        #pragma unroll
        for (int ms = 0; ms < 2; ms++)
          #pragma unroll
          for (int rr = 0; rr < 2; rr++){
            int rho = r0 + ms*16 + q*4 + rr*2;
            int run = rho >> (7+cLog);
            int rem = rho & ((1<<(7+cLog)) - 1);
            int b = rem >> cLog, jj = rem & (cnt-1);
            const int* fp = (run==0) ? f0 : ((run==1) ? f1 : f2);
            featp[ms][rr] = fp[b*TT + (256-cnt) + (jj>>1)];
          }
    }
    __syncthreads();   // sfr visible to all

    // ---- GEMM-U: hsum_in @ Uiou^T ----
    f4 acc[6][2];
    #pragma unroll
    for (int nt = 0; nt < 6; nt++){ acc[nt][0] = (f4){0,0,0,0}; acc[nt][1] = (f4){0,0,0,0}; }
    {
        const u16* a0p = hsum_in + (size_t)(r0+ln)*DD;
        const u16* a1p = hsum_in + (size_t)(r0+16+ln)*DD;
        const u16* Bp[6];
        #pragma unroll
        for (int nt = 0; nt < 6; nt++){
            int n = (nt>>1)*256 + d0 + (nt&1)*16 + ln;
            Bp[nt] = Uiou + (size_t)n*DD;
        }
        #pragma unroll 2
        for (int ks = 0; ks < 8; ks++){
            int ko = ks*32 + q*8;
            s8 a0 = ldB16(a0p + ko);
            s8 a1 = ldB16(a1p + ko);
            #pragma unroll
            for (int nt = 0; nt < 6; nt++){
                s8 bb = ldB16(Bp[nt] + ko);
                MFMA(acc[nt][0], a0, bb);
                MFMA(acc[nt][1], a1, bb);
            }
        }
    }

    // ---- epilogue: cell update with packed E4 read (one uint2/thread/iter) ----
    float cv[2][2][4];
    #pragma unroll
    for (int nc = 0; nc < 2; nc++){
        int d = d0 + nc*16 + ln;
        float bi = biou_f[d], bo = biou_f[256+d], bu = biou_f[512+d];
        #pragma unroll
        for (int ms = 0; ms < 2; ms++){
            float hv[4];
            #pragma unroll
            for (int r = 0; r < 4; r++){
                int m   = ms*16 + q*4 + r;
                int rho = r0 + m;
                union { uint2 q2; u16 a[4]; } ev;
                ev.q2 = *(const uint2*)(E4 + ((size_t)sfr[m]*DD + d)*4);
                float iv = acc[0+nc][ms][r] + bits2f(ev.a[0]) + bi;
                float ov = acc[2+nc][ms][r] + bits2f(ev.a[1]) + bo;
                float uv = acc[4+nc][ms][r] + bits2f(ev.a[2]) + bu;
                float cs = bits2f(fcsum_in[(size_t)rho*DD + d]);
                float c = sigm(iv)*tanh_(uv) + cs;
                float h = sigm(ov)*tanh_(c);
                cv[nc][ms][r] = c;
                hv[r] = h;
                if (haveP) hs[m*PAD + d] = f2bits(h);
                else       hroot[(size_t)rho*DD + d] = f2bits(h);
            }
            if (haveP){
                int lr = ms*8 + q*2;
                hso[lr*OPAD + d]     = f2bits(hv[0] + hv[1]);
                hso[(lr+1)*OPAD + d] = f2bits(hv[2] + hv[3]);
            }
        }
    }

    // ---- GEMM-C: hU = h@Uf^T, fc = sig(E_f[parent]+bf+hU)*c, pair-reduce ----
    if (haveP){
        __syncthreads();
        f4 hacc[2][2];
        #pragma unroll
        for (int nt = 0; nt < 2; nt++){ hacc[nt][0] = (f4){0,0,0,0}; hacc[nt][1] = (f4){0,0,0,0}; }
        const u16* Bf0 = Ufm + (size_t)(d0 + ln)*DD;
        const u16* Bf1 = Ufm + (size_t)(d0 + 16 + ln)*DD;
        #pragma unroll 2
        for (int ks = 0; ks < 8; ks++){
            int ko = ks*32 + q*8;
            s8 a0 = ldsA(&hs[ln*PAD + ko]);
            s8 a1 = ldsA(&hs[(16+ln)*PAD + ko]);
            s8 b0 = ldB16(Bf0 + ko);
            s8 b1 = ldB16(Bf1 + ko);
            MFMA(hacc[0][0], a0, b0); MFMA(hacc[0][1], a1, b0);
            MFMA(hacc[1][0], a0, b1); MFMA(hacc[1][1], a1, b1);
        }
        #pragma unroll
        for (int nc = 0; nc < 2; nc++){
            int d = d0 + nc*16 + ln;
            float bfv = bf_f[d];
            #pragma unroll
            for (int ms = 0; ms < 2; ms++){
                float fs0, fs1;
                #pragma unroll
                for (int r = 0; r < 4; r++){
                    float ef = bits2f(E_f[(size_t)featp[ms][r>>1]*DD + d]);
                    float fc = sigm(ef + bfv + hacc[nc][ms][r]) * cv[nc][ms][r];
                    if (r == 0) fs0 = fc;
                    else if (r == 1) fs0 += fc;
                    else if (r == 2) fs1 = fc;
                    else fs1 += fc;
                }
                int lr = ms*8 + q*2;
                fco[lr*OPAD + d]     = f2bits(fs0);
                fco[(lr+1)*OPAD + d] = f2bits(fs1);
            }
        }

        // ---- single coalesced write pass: full 128B lines, written once ----
        __syncthreads();
        {
            int row = t >> 5, c = (t & 31) * 8;
            int prow = (r0 >> 1) + row;
            uint4 vh = *(const uint4*)&hso[row*OPAD + c];
            uint4 vf = *(const uint4*)&fco[row*OPAD + c];
            *(uint4*)(hsum_out  + (size_t)prow*DD + c) = vh;
            *(uint4*)(fcsum_out + (size_t)prow*DD + c) = vf;
        }
    }
}

// ---------------- k_tail: levels 4..7 fused, block = 4 trees ----------------
// R8 post-mortem: (512,2) left VGPR at 92 and dur at 96.5us -> k_tail was never
// spill-bound; the ~24us/level is SERIALIZED GATHER LATENCY: the epilogue's 16 E4
// gathers + 16 carry reads (+8 E_f in GEMM-C) are each consumed a few instrs after
// issue, and at 2 waves/SIMD nothing hides the ~400-900cy each. The 256-reg budget
// (512,2) provides is now used deliberately: each epilogue is split into a batched
// LOAD phase (all gathers issued back-to-back into static-indexed register arrays)
// and a COMPUTE phase -> one latency exposure instead of 16. Adjacent load-all/
// use-all cannot be sunk like R6's cross-GEMM prefetch (no MFMA region between).
__global__ __launch_bounds__(512, 2)
void k_tail(const int* __restrict__ f0, const int* __restrict__ f1, const int* __restrict__ f2,
            const u16* __restrict__ E4, const u16* __restrict__ E_f,
            const u16* __restrict__ Uiou, const u16* __restrict__ Ufm,
            const float* __restrict__ biou_f, const float* __restrict__ bf_f,
            const u16* __restrict__ hsum_in, const u16* __restrict__ fcsum_in,
            u16* __restrict__ hroot)
{
    __shared__ u16 hs[32*PAD];        // 16.5 KB: h transpose for GEMM-C
    __shared__ u16 hsP[2][32*PAD];    // 33 KB: hsum carry ping-pong
    __shared__ u16 fcP[2][32*FPAD];   // 33.8 KB: fcsum carry ping-pong
    __shared__ int sf[64];            // 4 trees x 16 feats (heap slots 240..254)
    const int t = threadIdx.x, w = t>>6, lane = t&63, ln = lane&15, q = lane>>4;
    const int d0 = w*32;
    const int r0 = blockIdx.x*32;                 // lvl-4 global row base
    const int run = (blockIdx.x*4) >> 7;          // all 4 trees share one run
    const int* __restrict__ fp = (run==0) ? f0 : ((run==1) ? f1 : f2);

    if (t < 64){
        int ti = t >> 4, idx = t & 15;
        int b = (blockIdx.x*4 + ti) & 127;
        sf[t] = (idx < 15) ? fp[b*TT + 240 + idx] : 0;
    }
    __syncthreads();

    // B pointers constant across levels
    const u16* Bp[6];
    #pragma unroll
    for (int nt = 0; nt < 6; nt++){
        int n = (nt>>1)*256 + d0 + (nt&1)*16 + ln;
        Bp[nt] = Uiou + (size_t)n*DD;
    }
    const u16* Bf0 = Ufm + (size_t)(d0 + ln)*DD;
    const u16* Bf1 = Ufm + (size_t)(d0 + 16 + ln)*DD;

    for (int l = 4; l <= 7; l++){
        const int nl = 128 >> l;        // nodes per tree at this level (8,4,2,1)
        const int nrows = 4*nl;         // valid rows in block (32,16,8,4)
        const int sh = 7 - l;           // local m -> tree index shift
        const int inb = (l-1) & 1, outb = l & 1;
        const bool haveP = (l < 7);

        // ---- GEMM-U: A from global (lvl4) or LDS carry ----
        f4 acc[6][2];
        #pragma unroll
        for (int nt = 0; nt < 6; nt++){ acc[nt][0] = (f4){0,0,0,0}; acc[nt][1] = (f4){0,0,0,0}; }
        if (l == 4){
            const u16* a0p = hsum_in + (size_t)(r0+ln)*DD;
            const u16* a1p = hsum_in + (size_t)(r0+16+ln)*DD;
            #pragma unroll 2
            for (int ks = 0; ks < 8; ks++){
                int ko = ks*32 + q*8;
                s8 a0 = ldB16(a0p + ko);
                s8 a1 = ldB16(a1p + ko);
                #pragma unroll
                for (int nt = 0; nt < 6; nt++){
                    s8 bb = ldB16(Bp[nt] + ko);
                    MFMA(acc[nt][0], a0, bb);
                    MFMA(acc[nt][1], a1, bb);
                }
            }
        } else {
            const u16* a0l = &hsP[inb][ln*PAD];
            const u16* a1l = &hsP[inb][(16+ln)*PAD];
            #pragma unroll 2
            for (int ks = 0; ks < 8; ks++){
                int ko = ks*32 + q*8;
                s8 a0 = ldsA(a0l + ko);
                s8 a1 = ldsA(a1l + ko);
                #pragma unroll
                for (int nt = 0; nt < 6; nt++){
                    s8 bb = ldB16(Bp[nt] + ko);
                    MFMA(acc[nt][0], a0, bb);
                    MFMA(acc[nt][1], a1, bb);
                }
            }
        }

        // ---- BATCHED LOAD PHASE: all E4 gathers + carry reads issued together ----
        uint2 ev[2][2][4];    // static-indexed -> VGPRs (48 regs transient; budget 256)
        float csv[2][2][4];
        #pragma unroll
        for (int nc = 0; nc < 2; nc++){
            int d = d0 + nc*16 + ln;
            #pragma unroll
            for (int ms = 0; ms < 2; ms++)
              #pragma unroll
              for (int r = 0; r < 4; r++){
                int m = ms*16 + q*4 + r;
                int mc = (m < nrows) ? m : 0;
                int ti = mc >> sh, jj = mc & (nl-1);
                int fidx = sf[ti*16 + (16 - 2*nl) + jj];
                ev[nc][ms][r] = *(const uint2*)(E4 + ((size_t)fidx*DD + d)*4);
                csv[nc][ms][r] = (l == 4) ? bits2f(fcsum_in[(size_t)(r0+m)*DD + d])
                                          : bits2f(fcP[inb][m*FPAD + d]);
            }
        }

        // ---- COMPUTE PHASE: cell update; hsum pair-reduce into hsP[outb] ----
        float cv[2][2][4];
        #pragma unroll
        for (int nc = 0; nc < 2; nc++){
            int d = d0 + nc*16 + ln;
            float bi = biou_f[d], bo = biou_f[256+d], bu = biou_f[512+d];
            #pragma unroll
            for (int ms = 0; ms < 2; ms++){
                float hv[4];
                #pragma unroll
                for (int r = 0; r < 4; r++){
                    int m = ms*16 + q*4 + r;
                    bool vld = (m < nrows);
                    union { uint2 q2; u16 a[4]; } u2;
                    u2.q2 = ev[nc][ms][r];
                    float iv = acc[0+nc][ms][r] + bits2f(u2.a[0]) + bi;
                    float ov = acc[2+nc][ms][r] + bits2f(u2.a[1]) + bo;
                    float uv = acc[4+nc][ms][r] + bits2f(u2.a[2]) + bu;
                    float c = sigm(iv)*tanh_(uv) + csv[nc][ms][r];
                    float h = sigm(ov)*tanh_(c);
                    cv[nc][ms][r] = c;
                    hv[r] = h;
                    if (haveP) hs[m*PAD + d] = f2bits(h);
                    else if (vld) hroot[(size_t)(blockIdx.x*4 + m)*DD + d] = f2bits(h);
                }
                if (haveP){
                    int lr = ms*8 + q*2;
                    hsP[outb][lr*PAD + d]     = f2bits(hv[0] + hv[1]);
                    hsP[outb][(lr+1)*PAD + d] = f2bits(hv[2] + hv[3]);
                }
            }
        }

        // ---- GEMM-C -> fcP[outb] ----
        if (haveP){
            __syncthreads();
            f4 hacc[2][2];
            #pragma unroll
            for (int nt = 0; nt < 2; nt++){ hacc[nt][0] = (f4){0,0,0,0}; hacc[nt][1] = (f4){0,0,0,0}; }
            #pragma unroll 2
            for (int ks = 0; ks < 8; ks++){
                int ko = ks*32 + q*8;
                s8 a0 = ldsA(&hs[ln*PAD + ko]);
                s8 a1 = ldsA(&hs[(16+ln)*PAD + ko]);
                s8 b0 = ldB16(Bf0 + ko);
                s8 b1 = ldB16(Bf1 + ko);
                MFMA(hacc[0][0], a0, b0); MFMA(hacc[0][1], a1, b0);
                MFMA(hacc[1][0], a0, b1); MFMA(hacc[1][1], a1, b1);
            }

            // batched E_f gather (8 loads issued together)
            float efv[2][2][2];
            #pragma unroll
            for (int nc = 0; nc < 2; nc++){
                int d = d0 + nc*16 + ln;
                #pragma unroll
                for (int ms = 0; ms < 2; ms++)
                  #pragma unroll
                  for (int rr = 0; rr < 2; rr++){
                    int m2 = ms*16 + q*4 + rr*2;
                    int mc2 = (m2 < nrows) ? m2 : 0;
                    int ti2 = mc2 >> sh, jj2 = mc2 & (nl-1);
                    int fpar = sf[ti2*16 + (16 - nl) + (jj2 >> 1)];
                    efv[nc][ms][rr] = bits2f(E_f[(size_t)fpar*DD + d]);
                }
            }
            #pragma unroll
            for (int nc = 0; nc < 2; nc++){
                int d = d0 + nc*16 + ln;
                float bfv = bf_f[d];
                #pragma unroll
                for (int ms = 0; ms < 2; ms++){
                    float fs0, fs1;
                    #pragma unroll
                    for (int r = 0; r < 4; r++){
                        float ef = efv[nc][ms][r>>1];
                        float fc = sigm(ef + bfv + hacc[nc][ms][r]) * cv[nc][ms][r];
                        if (r == 0) fs0 = fc;
                        else if (r == 1) fs0 += fc;
                        else if (r == 2) fs1 = fc;
                        else fs1 += fc;
                    }
                    int lr = ms*8 + q*2;
                    fcP[outb][lr*FPAD + d]     = f2bits(fs0);
                    fcP[outb][(lr+1)*FPAD + d] = f2bits(fs1);
                }
            }
            __syncthreads();   // carry buffers ready for next level
        }
    }
}

// ---------------- final: bilinear combine + MLP (proven epilogue) ----------------
__global__ __launch_bounds__(256)
void k_final(const u16* __restrict__ hroot,
             const float* __restrict__ fc1w, const float* __restrict__ fc1b,
             const float* __restrict__ fc2w, const float* __restrict__ fc2b,
             void* __restrict__ out, const int* __restrict__ flag)
{
    int b = blockIdx.x, t = threadIdx.x;
    __shared__ float sprod[DD];
    __shared__ float shb[DD];
    __shared__ float shid[128];
    float hc  = bits2f(hroot[(0*NTREE + b)*DD + t]);
    float ha  = bits2f(hroot[(1*NTREE + b)*DD + t]);
    float hbv = bits2f(hroot[(2*NTREE + b)*DD + t]);
    sprod[t] = hc * ha;
    shb[t]   = hbv;
    __syncthreads();
    for (int s = 128; s > 0; s >>= 1){
        if (t < s) sprod[t] += sprod[t + s];
        __syncthreads();
    }
    float dot = sprod[0];
    if (t < 128){
        float acc = fc1b[t];
        for (int k = 0; k < DD; k++)
            acc = fmaf(dot * shb[k], fc1w[t*DD + k], acc);
        shid[t] = fmaxf(acc, 0.f);
    }
    __syncthreads();
    if (t < 3){
        float acc = fc2b[t];
        for (int j = 0; j < 128; j++)
            acc = fmaf(fc2w[t*128 + j], shid[j], acc);
        float v = fmaxf(acc, 0.f);
        if (flag[0]) ((bf16*)out)[b*3 + t] = __float2bfloat16(v);
        else         ((float*)out)[b*3 + t] = v;
    }
}

extern "C" void kernel_launch(void* const* d_in, const int* in_sizes, int n_in,
                              void* d_out, int out_size, void* d_ws, size_t ws_size,
                              hipStream_t stream)
{
    const int* f0 = (const int*)d_in[0];
    const int* f1 = (const int*)d_in[1];
    const int* f2 = (const int*)d_in[2];
    // d_in[3..7] static forest metadata — unused (structure compile-time known)
    const void* emb  = d_in[8];
    const void* Wiou = d_in[9];
    const void* biou = d_in[10];
    const void* Uiou = d_in[11];
    const void* Wf   = d_in[12];
    const void* bfv  = d_in[13];
    const void* Uf   = d_in[14];
    const void* fc1w = d_in[15];
    const void* fc1b = d_in[16];
    const void* fc2w = d_in[17];
    const void* fc2b = d_in[18];

    char* base = (char*)d_ws;
    size_t off = 0;
    auto take = [&](size_t bytes) -> char* {
        char* p = base + off;
        off = (off + bytes + 255) & ~(size_t)255;
        return p;
    };
    int*   flag   = (int*)  take(256);
    u16*   embb   = (u16*)  take((size_t)L_EMBP*2);
    u16*   wioub  = (u16*)  take((size_t)L_WIOU*2);
    u16*   uioub  = (u16*)  take((size_t)L_UIOU*2);
    u16*   wfb    = (u16*)  take((size_t)L_WF*2);
    u16*   ufb    = (u16*)  take((size_t)L_UF*2);
    float* biou_f = (float*)take(S_BIOU*4);
    float* bf_f   = (float*)take(S_BF*4);
    float* fc1w_f = (float*)take(S_F1W*4);
    float* fc1b_f = (float*)take(S_F1B*4);
    float* fc2w_f = (float*)take(S_F2W*4);
    float* fc2b_f = (float*)take(S_F2B*4);
    u16*   E4     = (u16*)  take((size_t)VPAD*DD*4*2);     // 20.5 MB packed {i,o,u,f}
    u16*   E_f    = (u16*)  take((size_t)VPAD*DD*2);       // 5.13 MB
    u16*   H0     = (u16*)  take((size_t)VPAD*DD*2);
    u16*   C0     = (u16*)  take((size_t)VPAD*DD*2);
    u16*   HU0    = (u16*)  take((size_t)VPAD*DD*2);
    u16*   HA     = (u16*)  take((size_t)24576*DD*2);
    u16*   HB     = (u16*)  take((size_t)12288*DD*2);
    u16*   FA     = (u16*)  take((size_t)24576*DD*2);
    u16*   FB     = (u16*)  take((size_t)12288*DD*2);
    u16*   hroot  = (u16*)  take((size_t)NRUNS*NTREE*DD*2);
    // total ~85 MB (< proven 119 MB)

    k_detect<<<1, 256, 0, stream>>>((const u16*)emb, flag);
    k_cvtb<<<2048, 256, 0, stream>>>(emb, Wiou, Uiou, Wf, Uf,
                                     embb, wioub, uioub, wfb, ufb, flag);
    k_small<<<135, 256, 0, stream>>>(biou, bfv, fc1w, fc1b, fc2w, fc2b,
                                     biou_f, bf_f, fc1w_f, fc1b_f, fc2w_f, fc2b_f, flag);
    k_vocab2<<<VPAD/32, 512, 0, stream>>>(embb, wioub, wfb, ufb, biou_f,
                                          E4, E_f, H0, C0, HU0);
    k_edge0<<<24576*32/512, 512, 0, stream>>>(f0, f1, f2, E_f, H0, C0, HU0, bf_f, HA, FA);

    for (int lvl = 1; lvl <= 3; lvl++){
        int cLog = 7 - lvl;
        int rows = NRUNS*NTREE*(128 >> lvl);
        int blocks = rows / 32;
        int pe = lvl & 1;
        u16* hs_o = pe ? HB : HA;
        u16* fc_o = pe ? FB : FA;
        const u16* hs_i = pe ? HA : HB;
        const u16* fc_i = pe ? FA : FB;
        k_lvl<<<blocks, 512, 0, stream>>>(lvl, cLog, f0, f1, f2,
                                          E4, E_f, uioub, ufb,
                                          biou_f, bf_f,
                                          hs_i, fc_i, hs_o, fc_o, hroot);
    }
    // lvl3 (pe=1) wrote HB/FB -> k_tail consumes them for lvl4..7
    k_tail<<<(NRUNS*NTREE)/4, 512, 0, stream>>>(f0, f1, f2, E4, E_f, uioub, ufb,
                                                biou_f, bf_f, HB, FB, hroot);
    k_final<<<NTREE, 256, 0, stream>>>(hroot, fc1w_f, fc1b_f, fc2w_f, fc2b_f, d_out, flag);
}

// Round 10
// 421.285 us; speedup vs baseline: 1.1032x; 1.0044x over previous
//
#include <hip/hip_runtime.h>
#include <hip/hip_bf16.h>

typedef __hip_bfloat16 bf16;
typedef unsigned short u16;
typedef __attribute__((ext_vector_type(8))) short s8;   // 8 bf16 = one MFMA A/B fragment
typedef __attribute__((ext_vector_type(4))) float f4;   // MFMA C/D fragment

#define NRUNS 3
#define NTREE 128
#define TT    255
#define DD    256
#define VPAD  10016    /* vocab padded to 32 */
#define PAD   258      /* LDS row stride in u16 for 256-wide rows */
#define OPAD  264      /* output-staging stride: uint4-aligned (528B), bank-staggered */
#define FPAD  264      /* fcP carry stride in k_tail (528B breaks 512B bank aliasing) */

__device__ __forceinline__ float bits2f(u16 b){ union{unsigned u; float f;} x; x.u = ((unsigned)b)<<16; return x.f; }
__device__ __forceinline__ u16   f2bits(float f){ bf16 h = __float2bfloat16(f); return *(u16*)&h; }
__device__ __forceinline__ float sigm(float x){ return 1.f/(1.f+__expf(-x)); }
__device__ __forceinline__ float tanh_(float x){ return 1.f - 2.f/(__expf(2.f*x)+1.f); }

// ---------------- dtype autodetect (proven) ----------------
__global__ void k_detect(const u16* __restrict__ raw, int* __restrict__ flag){
    int t = threadIdx.x;
    int hit = 0;
    if (t < 128){
        u16 w = raw[2*t];
        int e = (w >> 7) & 0xFF;
        hit = (e >= 100 && e <= 141) ? 1 : 0;
    }
    __shared__ int cnt;
    if (t == 0) cnt = 0;
    __syncthreads();
    atomicAdd(&cnt, hit);
    __syncthreads();
    if (t == 0) flag[0] = (cnt >= 64) ? 1 : 0;
}

__device__ __forceinline__ u16 cvt1b(const void* p, int i, int isb){
    return isb ? ((const u16*)p)[i] : f2bits(((const float*)p)[i]);
}
__device__ __forceinline__ float cvt1f(const void* p, int i, int isb){
    return isb ? bits2f(((const u16*)p)[i]) : ((const float*)p)[i];
}

// fused any->bf16 conversion: emb (zero-padded to VPAD rows) + 4 weights
#define L_EMB  (10000*256)
#define L_EMBP (VPAD*256)
#define L_WIOU (768*256)
#define L_UIOU (768*256)
#define L_WF   (256*256)
#define L_UF   (256*256)
#define L_ALL  (L_EMBP + L_WIOU + L_UIOU + L_WF + L_UF)
__global__ void k_cvtb(const void* __restrict__ s0, const void* __restrict__ s1,
                       const void* __restrict__ s2, const void* __restrict__ s3,
                       const void* __restrict__ s4,
                       u16* __restrict__ d0, u16* __restrict__ d1, u16* __restrict__ d2,
                       u16* __restrict__ d3, u16* __restrict__ d4,
                       const int* __restrict__ flag){
    int isb = flag[0];
    for (int i = blockIdx.x*blockDim.x + threadIdx.x; i < L_ALL; i += gridDim.x*blockDim.x){
        int j = i;
        if (j < L_EMBP){ d0[j] = (j < L_EMB) ? cvt1b(s0, j, isb) : (u16)0; continue; } j -= L_EMBP;
        if (j < L_WIOU){ d1[j] = cvt1b(s1, j, isb); continue; } j -= L_WIOU;
        if (j < L_UIOU){ d2[j] = cvt1b(s2, j, isb); continue; } j -= L_UIOU;
        if (j < L_WF){ d3[j] = cvt1b(s3, j, isb); continue; } j -= L_WF;
        d4[j] = cvt1b(s4, j, isb);
    }
}

// fused any->f32 conversion of biases + FC weights
#define S_BIOU 768
#define S_BF   256
#define S_F1W  (128*256)
#define S_F1B  128
#define S_F2W  (3*128)
#define S_F2B  3
#define S_ALL  (S_BIOU+S_BF+S_F1W+S_F1B+S_F2W+S_F2B)
__global__ void k_small(const void* __restrict__ s0, const void* __restrict__ s1,
                        const void* __restrict__ s2, const void* __restrict__ s3,
                        const void* __restrict__ s4, const void* __restrict__ s5,
                        float* __restrict__ d0, float* __restrict__ d1, float* __restrict__ d2,
                        float* __restrict__ d3, float* __restrict__ d4, float* __restrict__ d5,
                        const int* __restrict__ flag){
    int isb = flag[0];
    for (int i = blockIdx.x*blockDim.x + threadIdx.x; i < S_ALL; i += gridDim.x*blockDim.x){
        int j = i;
        if (j < S_BIOU){ d0[j] = cvt1f(s0, j, isb); continue; } j -= S_BIOU;
        if (j < S_BF){ d1[j] = cvt1f(s1, j, isb); continue; } j -= S_BF;
        if (j < S_F1W){ d2[j] = cvt1f(s2, j, isb); continue; } j -= S_F1W;
        if (j < S_F1B){ d3[j] = cvt1f(s3, j, isb); continue; } j -= S_F1B;
        if (j < S_F2W){ d4[j] = cvt1f(s4, j, isb); continue; } j -= S_F2W;
        d5[j] = cvt1f(s5, j, isb);
    }
}

__device__ __forceinline__ s8 ldB16(const u16* p){
    union { uint4 q; s8 v; } u;
    u.q = *(const uint4*)p;
    return u.v;
}
__device__ __forceinline__ s8 ldsA(const u16* p){
    union { unsigned w[4]; s8 v; } u;
    u.w[0] = *(const unsigned*)(p);
    u.w[1] = *(const unsigned*)(p+2);
    u.w[2] = *(const unsigned*)(p+4);
    u.w[3] = *(const unsigned*)(p+6);
    return u.v;
}
#define MFMA(acc,a,b) acc = __builtin_amdgcn_mfma_f32_16x16x32_bf16(a, b, acc, 0, 0, 0)

// ---------------- vocab-space precompute (packed E4[vocab][256][4] = {i,o,u,f}) ----------------
__global__ __launch_bounds__(512, 4)
void k_vocab2(const u16* __restrict__ embb,
              const u16* __restrict__ Wiou, const u16* __restrict__ Wfm,
              const u16* __restrict__ Ufm,  const float* __restrict__ biou_f,
              u16* __restrict__ E4, u16* __restrict__ E_f,
              u16* __restrict__ H0, u16* __restrict__ C0, u16* __restrict__ HU0)
{
    __shared__ u16 hs[32*PAD];    // h0 for the HU0 GEMM
    const int t = threadIdx.x, w = t>>6, lane = t&63, ln = lane&15, q = lane>>4;
    const int r0 = blockIdx.x*32, d0 = w*32;

    const u16* Bp[8];
    #pragma unroll
    for (int g = 0; g < 4; g++)
      #pragma unroll
      for (int nc = 0; nc < 2; nc++){
        int nn = d0 + nc*16 + ln;
        Bp[g*2+nc] = (g < 3) ? (Wiou + (size_t)(g*256+nn)*DD) : (Wfm + (size_t)nn*DD);
      }
    const u16* a0p = embb + (size_t)(r0+ln)*DD;
    const u16* a1p = embb + (size_t)(r0+16+ln)*DD;
    f4 acc[8][2];
    #pragma unroll
    for (int nt = 0; nt < 8; nt++){ acc[nt][0] = (f4){0,0,0,0}; acc[nt][1] = (f4){0,0,0,0}; }
    #pragma unroll 2
    for (int ks = 0; ks < 8; ks++){
        int ko = ks*32 + q*8;
        s8 a0 = ldB16(a0p + ko);
        s8 a1 = ldB16(a1p + ko);
        #pragma unroll
        for (int nt = 0; nt < 8; nt++){
            s8 bb = ldB16(Bp[nt] + ko);
            MFMA(acc[nt][0], a0, bb);
            MFMA(acc[nt][1], a1, bb);
        }
    }
    #pragma unroll
    for (int nc = 0; nc < 2; nc++){
        int d = d0 + nc*16 + ln;
        float bi = biou_f[d], bo = biou_f[256+d], bu = biou_f[512+d];
        #pragma unroll
        for (int ms = 0; ms < 2; ms++)
          #pragma unroll
          for (int r = 0; r < 4; r++){
            int vrow = r0 + ms*16 + q*4 + r;
            float ei = acc[0*2+nc][ms][r];
            float eo = acc[1*2+nc][ms][r];
            float eu = acc[2*2+nc][ms][r];
            float ef = acc[3*2+nc][ms][r];
            union { u16 a[4]; uint2 q2; } pk;
            pk.a[0] = f2bits(ei);
            pk.a[1] = f2bits(eo);
            pk.a[2] = f2bits(eu);
            pk.a[3] = f2bits(ef);
            *(uint2*)(E4 + ((size_t)vrow*DD + d)*4) = pk.q2;
            E_f[(size_t)vrow*DD + d] = f2bits(ef);
            float cc = sigm(ei + bi)*tanh_(eu + bu);
            float hh = sigm(eo + bo)*tanh_(cc);
            C0[(size_t)vrow*DD + d] = f2bits(cc);
            H0[(size_t)vrow*DD + d] = f2bits(hh);
            hs[(ms*16 + q*4 + r)*PAD + d] = f2bits(hh);
        }
    }
    __syncthreads();

    f4 hacc[2][2];
    #pragma unroll
    for (int nt = 0; nt < 2; nt++){ hacc[nt][0] = (f4){0,0,0,0}; hacc[nt][1] = (f4){0,0,0,0}; }
    const u16* Bf0 = Ufm + (size_t)(d0 + ln)*DD;
    const u16* Bf1 = Ufm + (size_t)(d0 + 16 + ln)*DD;
    #pragma unroll 2
    for (int ks = 0; ks < 8; ks++){
        int ko = ks*32 + q*8;
        s8 a0 = ldsA(&hs[ln*PAD + ko]);
        s8 a1 = ldsA(&hs[(16+ln)*PAD + ko]);
        s8 b0 = ldB16(Bf0 + ko);
        s8 b1 = ldB16(Bf1 + ko);
        MFMA(hacc[0][0], a0, b0); MFMA(hacc[0][1], a1, b0);
        MFMA(hacc[1][0], a0, b1); MFMA(hacc[1][1], a1, b1);
    }
    #pragma unroll
    for (int nc = 0; nc < 2; nc++){
        int d = d0 + nc*16 + ln;
        #pragma unroll
        for (int ms = 0; ms < 2; ms++)
          #pragma unroll
          for (int r = 0; r < 4; r++){
            int vrow = r0 + ms*16 + q*4 + r;
            HU0[(size_t)vrow*DD + d] = f2bits(hacc[nc][ms][r]);
        }
    }
}

// ---------------- k_edge0: assemble lvl-1 inputs from vocab tables (proven) ----------------
__global__ __launch_bounds__(512, 4)
void k_edge0(const int* __restrict__ f0, const int* __restrict__ f1, const int* __restrict__ f2,
             const u16* __restrict__ E_f, const u16* __restrict__ H0,
             const u16* __restrict__ C0,  const u16* __restrict__ HU0,
             const float* __restrict__ bf_f,
             u16* __restrict__ hsum_out, u16* __restrict__ fcsum_out)
{
    int gid = blockIdx.x*512 + threadIdx.x;
    int row = gid >> 5, ch = gid & 31, d = ch*8;
    int run = row >> 13, rem = row & 8191, b = rem >> 6, jj = rem & 63;
    const int* fp = (run==0) ? f0 : ((run==1) ? f1 : f2);
    int fo = fp[b*TT + 128 + jj];
    int v1 = fp[b*TT + 2*jj];
    int v2 = fp[b*TT + 2*jj + 1];
    s8 ef  = ldB16(E_f + (size_t)fo*DD + d);
    s8 hu1 = ldB16(HU0 + (size_t)v1*DD + d);
    s8 hu2 = ldB16(HU0 + (size_t)v2*DD + d);
    s8 c1  = ldB16(C0  + (size_t)v1*DD + d);
    s8 c2  = ldB16(C0  + (size_t)v2*DD + d);
    s8 h1  = ldB16(H0  + (size_t)v1*DD + d);
    s8 h2  = ldB16(H0  + (size_t)v2*DD + d);
    union { u16 a[8]; uint4 q4; } uh, uf;
    #pragma unroll
    for (int j = 0; j < 8; j++){
        float e  = bits2f((u16)ef[j]) + bf_f[d+j];
        float fa = sigm(e + bits2f((u16)hu1[j]));
        float fb = sigm(e + bits2f((u16)hu2[j]));
        float fc = fa*bits2f((u16)c1[j]) + fb*bits2f((u16)c2[j]);
        float hsv = bits2f((u16)h1[j]) + bits2f((u16)h2[j]);
        uf.a[j] = f2bits(fc);
        uh.a[j] = f2bits(hsv);
    }
    *(uint4*)(hsum_out  + (size_t)row*DD + d) = uh.q4;
    *(uint4*)(fcsum_out + (size_t)row*DD + d) = uf.q4;
}

// ---------------- per-level kernel (v6 == R5 proven: 81us lvl-1, VGPR 64) ----------------
__global__ __launch_bounds__(512, 4)
void k_lvl(int lvl, int cLog,
           const int* __restrict__ f0, const int* __restrict__ f1, const int* __restrict__ f2,
           const u16* __restrict__ E4, const u16* __restrict__ E_f,
           const u16* __restrict__ Uiou, const u16* __restrict__ Ufm,
           const float* __restrict__ biou_f, const float* __restrict__ bf_f,
           const u16* __restrict__ hsum_in, const u16* __restrict__ fcsum_in,
           u16* __restrict__ hsum_out, u16* __restrict__ fcsum_out,
           u16* __restrict__ hroot)
{
    __shared__ u16 hs[32*PAD];     // 16.5 KB: h transpose for GEMM-C
    __shared__ u16 hso[16*OPAD];   // 8.4 KB: staged hsum_out rows
    __shared__ u16 fco[16*OPAD];   // 8.4 KB: staged fcsum_out rows
    __shared__ int sfr[32];        // this block's 32 node feats (epilogue E4 rows)
    const int t = threadIdx.x, w = t>>6, lane = t&63, ln = lane&15, q = lane>>4;
    const int cnt = 1 << cLog, S = 256 - 2*cnt;
    const int r0 = blockIdx.x*32, d0 = w*32;
    const bool haveP = (lvl < 7);

    // ---- stage this block's 32 node feats into LDS (128 B) ----
    if (t < 32){
        int rho = r0 + t;
        int run = rho >> (7+cLog);
        int rem = rho & ((1<<(7+cLog)) - 1);
        int b = rem >> cLog, jj = rem & (cnt-1);
        const int* fp = (run==0) ? f0 : ((run==1) ? f1 : f2);
        sfr[t] = fp[b*TT + S + jj];
    }

    // parent feats for GEMM-C epilogue
    int featp[2][2];
    if (haveP){
        #pragma unroll
        for (int ms = 0; ms < 2; ms++)
          #pragma unroll
          for (int rr = 0; rr < 2; rr++){
            int rho = r0 + ms*16 + q*4 + rr*2;
            int run = rho >> (7+cLog);
            int rem = rho & ((1<<(7+cLog)) - 1);
            int b = rem >> cLog, jj = rem & (cnt-1);
            const int* fp = (run==0) ? f0 : ((run==1) ? f1 : f2);
            featp[ms][rr] = fp[b*TT + (256-cnt) + (jj>>1)];
          }
    }
    __syncthreads();   // sfr visible to all

    // ---- GEMM-U: hsum_in @ Uiou^T ----
    f4 acc[6][2];
    #pragma unroll
    for (int nt = 0; nt < 6; nt++){ acc[nt][0] = (f4){0,0,0,0}; acc[nt][1] = (f4){0,0,0,0}; }
    {
        const u16* a0p = hsum_in + (size_t)(r0+ln)*DD;
        const u16* a1p = hsum_in + (size_t)(r0+16+ln)*DD;
        const u16* Bp[6];
        #pragma unroll
        for (int nt = 0; nt < 6; nt++){
            int n = (nt>>1)*256 + d0 + (nt&1)*16 + ln;
            Bp[nt] = Uiou + (size_t)n*DD;
        }
        #pragma unroll 2
        for (int ks = 0; ks < 8; ks++){
            int ko = ks*32 + q*8;
            s8 a0 = ldB16(a0p + ko);
            s8 a1 = ldB16(a1p + ko);
            #pragma unroll
            for (int nt = 0; nt < 6; nt++){
                s8 bb = ldB16(Bp[nt] + ko);
                MFMA(acc[nt][0], a0, bb);
                MFMA(acc[nt][1], a1, bb);
            }
        }
    }

    // ---- epilogue: cell update with packed E4 read (one uint2/thread/iter) ----
    float cv[2][2][4];
    #pragma unroll
    for (int nc = 0; nc < 2; nc++){
        int d = d0 + nc*16 + ln;
        float bi = biou_f[d], bo = biou_f[256+d], bu = biou_f[512+d];
        #pragma unroll
        for (int ms = 0; ms < 2; ms++){
            float hv[4];
            #pragma unroll
            for (int r = 0; r < 4; r++){
                int m   = ms*16 + q*4 + r;
                int rho = r0 + m;
                union { uint2 q2; u16 a[4]; } ev;
                ev.q2 = *(const uint2*)(E4 + ((size_t)sfr[m]*DD + d)*4);
                float iv = acc[0+nc][ms][r] + bits2f(ev.a[0]) + bi;
                float ov = acc[2+nc][ms][r] + bits2f(ev.a[1]) + bo;
                float uv = acc[4+nc][ms][r] + bits2f(ev.a[2]) + bu;
                float cs = bits2f(fcsum_in[(size_t)rho*DD + d]);
                float c = sigm(iv)*tanh_(uv) + cs;
                float h = sigm(ov)*tanh_(c);
                cv[nc][ms][r] = c;
                hv[r] = h;
                if (haveP) hs[m*PAD + d] = f2bits(h);
                else       hroot[(size_t)rho*DD + d] = f2bits(h);
            }
            if (haveP){
                int lr = ms*8 + q*2;
                hso[lr*OPAD + d]     = f2bits(hv[0] + hv[1]);
                hso[(lr+1)*OPAD + d] = f2bits(hv[2] + hv[3]);
            }
        }
    }

    // ---- GEMM-C: hU = h@Uf^T, fc = sig(E_f[parent]+bf+hU)*c, pair-reduce ----
    if (haveP){
        __syncthreads();
        f4 hacc[2][2];
        #pragma unroll
        for (int nt = 0; nt < 2; nt++){ hacc[nt][0] = (f4){0,0,0,0}; hacc[nt][1] = (f4){0,0,0,0}; }
        const u16* Bf0 = Ufm + (size_t)(d0 + ln)*DD;
        const u16* Bf1 = Ufm + (size_t)(d0 + 16 + ln)*DD;
        #pragma unroll 2
        for (int ks = 0; ks < 8; ks++){
            int ko = ks*32 + q*8;
            s8 a0 = ldsA(&hs[ln*PAD + ko]);
            s8 a1 = ldsA(&hs[(16+ln)*PAD + ko]);
            s8 b0 = ldB16(Bf0 + ko);
            s8 b1 = ldB16(Bf1 + ko);
            MFMA(hacc[0][0], a0, b0); MFMA(hacc[0][1], a1, b0);
            MFMA(hacc[1][0], a0, b1); MFMA(hacc[1][1], a1, b1);
        }
        #pragma unroll
        for (int nc = 0; nc < 2; nc++){
            int d = d0 + nc*16 + ln;
            float bfv = bf_f[d];
            #pragma unroll
            for (int ms = 0; ms < 2; ms++){
                float fs0, fs1;
                #pragma unroll
                for (int r = 0; r < 4; r++){
                    float ef = bits2f(E_f[(size_t)featp[ms][r>>1]*DD + d]);
                    float fc = sigm(ef + bfv + hacc[nc][ms][r]) * cv[nc][ms][r];
                    if (r == 0) fs0 = fc;
                    else if (r == 1) fs0 += fc;
                    else if (r == 2) fs1 = fc;
                    else fs1 += fc;
                }
                int lr = ms*8 + q*2;
                fco[lr*OPAD + d]     = f2bits(fs0);
                fco[(lr+1)*OPAD + d] = f2bits(fs1);
            }
        }

        // ---- single coalesced write pass: full 128B lines, written once ----
        __syncthreads();
        {
            int row = t >> 5, c = (t & 31) * 8;
            int prow = (r0 >> 1) + row;
            uint4 vh = *(const uint4*)&hso[row*OPAD + c];
            uint4 vf = *(const uint4*)&fco[row*OPAD + c];
            *(uint4*)(hsum_out  + (size_t)prow*DD + c) = vh;
            *(uint4*)(fcsum_out + (size_t)prow*DD + c) = vf;
        }
    }
}

// ---------------- k_tail: levels 4..7 fused, block = 4 trees, 1024 thr / 16 waves ----------------
// R9 post-mortem: batching gained only 8us (VGPR 92->100: compiler held ~4 of 16
// loads; acc[6][2]=48 AGPR pinned across the phase boundary forced re-fusion).
// Root condition across R5-R9: every level-step costs ~22-27us of WAIT at 2
// waves/SIMD (MfmaUtil 2.5%, VALUBusy 10%) -- latency chains with no TLP to hide
// them (R6: occupancy 37->22% cost proportional time). Fix: split the N(d)-axis
// in half -> 1024 threads, 16 waves, d0=w*16. Same 32-row tile, same LDS, same
// total MFMA; per-wave state halves (acc[3][2]=24 AGPR, ev[2][4]) so the
// (1024,4)-mandated 128-reg budget fits; 4 waves/SIMD overlap 2x the independent
// gather/B-load streams in every phase.
__global__ __launch_bounds__(1024, 4)
void k_tail(const int* __restrict__ f0, const int* __restrict__ f1, const int* __restrict__ f2,
            const u16* __restrict__ E4, const u16* __restrict__ E_f,
            const u16* __restrict__ Uiou, const u16* __restrict__ Ufm,
            const float* __restrict__ biou_f, const float* __restrict__ bf_f,
            const u16* __restrict__ hsum_in, const u16* __restrict__ fcsum_in,
            u16* __restrict__ hroot)
{
    __shared__ u16 hs[32*PAD];        // 16.5 KB: h transpose for GEMM-C
    __shared__ u16 hsP[2][32*PAD];    // 33 KB: hsum carry ping-pong
    __shared__ u16 fcP[2][32*FPAD];   // 33.8 KB: fcsum carry ping-pong
    __shared__ int sf[64];            // 4 trees x 16 feats (heap slots 240..254)
    const int t = threadIdx.x, w = t>>6, lane = t&63, ln = lane&15, q = lane>>4;
    const int d0 = w*16;              // 16 waves x 16 d-cols = 256
    const int d  = d0 + ln;
    const int r0 = blockIdx.x*32;                 // lvl-4 global row base
    const int run = (blockIdx.x*4) >> 7;          // all 4 trees share one run
    const int* __restrict__ fp = (run==0) ? f0 : ((run==1) ? f1 : f2);

    if (t < 64){
        int ti = t >> 4, idx = t & 15;
        int b = (blockIdx.x*4 + ti) & 127;
        sf[t] = (idx < 15) ? fp[b*TT + 240 + idx] : 0;
    }
    __syncthreads();

    // B pointers constant across levels (3 gate tiles of 16 cols each)
    const u16* Bp[3];
    #pragma unroll
    for (int g = 0; g < 3; g++)
        Bp[g] = Uiou + (size_t)(g*256 + d0 + ln)*DD;
    const u16* Bf0 = Ufm + (size_t)(d0 + ln)*DD;

    const float bi = biou_f[d], bo = biou_f[256+d], bu = biou_f[512+d];
    const float bfv = bf_f[d];

    for (int l = 4; l <= 7; l++){
        const int nl = 128 >> l;        // nodes per tree at this level (8,4,2,1)
        const int nrows = 4*nl;         // valid rows in block (32,16,8,4)
        const int sh = 7 - l;           // local m -> tree index shift
        const int inb = (l-1) & 1, outb = l & 1;
        const bool haveP = (l < 7);

        // ---- GEMM-U: A from global (lvl4) or LDS carry ----
        f4 acc[3][2];
        #pragma unroll
        for (int nt = 0; nt < 3; nt++){ acc[nt][0] = (f4){0,0,0,0}; acc[nt][1] = (f4){0,0,0,0}; }
        if (l == 4){
            const u16* a0p = hsum_in + (size_t)(r0+ln)*DD;
            const u16* a1p = hsum_in + (size_t)(r0+16+ln)*DD;
            #pragma unroll 2
            for (int ks = 0; ks < 8; ks++){
                int ko = ks*32 + q*8;
                s8 a0 = ldB16(a0p + ko);
                s8 a1 = ldB16(a1p + ko);
                #pragma unroll
                for (int nt = 0; nt < 3; nt++){
                    s8 bb = ldB16(Bp[nt] + ko);
                    MFMA(acc[nt][0], a0, bb);
                    MFMA(acc[nt][1], a1, bb);
                }
            }
        } else {
            const u16* a0l = &hsP[inb][ln*PAD];
            const u16* a1l = &hsP[inb][(16+ln)*PAD];
            #pragma unroll 2
            for (int ks = 0; ks < 8; ks++){
                int ko = ks*32 + q*8;
                s8 a0 = ldsA(a0l + ko);
                s8 a1 = ldsA(a1l + ko);
                #pragma unroll
                for (int nt = 0; nt < 3; nt++){
                    s8 bb = ldB16(Bp[nt] + ko);
                    MFMA(acc[nt][0], a0, bb);
                    MFMA(acc[nt][1], a1, bb);
                }
            }
        }

        // ---- BATCHED LOAD PHASE: all E4 gathers + carry reads issued together ----
        uint2 ev[2][4];    // static-indexed -> VGPRs (16 regs; budget 128)
        float csv[2][4];
        #pragma unroll
        for (int ms = 0; ms < 2; ms++)
          #pragma unroll
          for (int r = 0; r < 4; r++){
            int m = ms*16 + q*4 + r;
            int mc = (m < nrows) ? m : 0;
            int ti = mc >> sh, jj = mc & (nl-1);
            int fidx = sf[ti*16 + (16 - 2*nl) + jj];
            ev[ms][r] = *(const uint2*)(E4 + ((size_t)fidx*DD + d)*4);
            csv[ms][r] = (l == 4) ? bits2f(fcsum_in[(size_t)(r0+m)*DD + d])
                                  : bits2f(fcP[inb][m*FPAD + d]);
        }

        // ---- COMPUTE PHASE: cell update; hsum pair-reduce into hsP[outb] ----
        float cv[2][4];
        #pragma unroll
        for (int ms = 0; ms < 2; ms++){
            float hv[4];
            #pragma unroll
            for (int r = 0; r < 4; r++){
                int m = ms*16 + q*4 + r;
                bool vld = (m < nrows);
                union { uint2 q2; u16 a[4]; } u2;
                u2.q2 = ev[ms][r];
                float iv = acc[0][ms][r] + bits2f(u2.a[0]) + bi;
                float ov = acc[1][ms][r] + bits2f(u2.a[1]) + bo;
                float uv = acc[2][ms][r] + bits2f(u2.a[2]) + bu;
                float c = sigm(iv)*tanh_(uv) + csv[ms][r];
                float h = sigm(ov)*tanh_(c);
                cv[ms][r] = c;
                hv[r] = h;
                if (haveP) hs[m*PAD + d] = f2bits(h);
                else if (vld) hroot[(size_t)(blockIdx.x*4 + m)*DD + d] = f2bits(h);
            }
            if (haveP){
                int lr = ms*8 + q*2;
                hsP[outb][lr*PAD + d]     = f2bits(hv[0] + hv[1]);
                hsP[outb][(lr+1)*PAD + d] = f2bits(hv[2] + hv[3]);
            }
        }

        // ---- GEMM-C -> fcP[outb] ----
        if (haveP){
            __syncthreads();
            f4 hacc[2];
            hacc[0] = (f4){0,0,0,0}; hacc[1] = (f4){0,0,0,0};
            #pragma unroll 2
            for (int ks = 0; ks < 8; ks++){
                int ko = ks*32 + q*8;
                s8 a0 = ldsA(&hs[ln*PAD + ko]);
                s8 a1 = ldsA(&hs[(16+ln)*PAD + ko]);
                s8 b0 = ldB16(Bf0 + ko);
                MFMA(hacc[0], a0, b0);
                MFMA(hacc[1], a1, b0);
            }

            // batched E_f gather (4 loads issued together)
            float efv[2][2];
            #pragma unroll
            for (int ms = 0; ms < 2; ms++)
              #pragma unroll
              for (int rr = 0; rr < 2; rr++){
                int m2 = ms*16 + q*4 + rr*2;
                int mc2 = (m2 < nrows) ? m2 : 0;
                int ti2 = mc2 >> sh, jj2 = mc2 & (nl-1);
                int fpar = sf[ti2*16 + (16 - nl) + (jj2 >> 1)];
                efv[ms][rr] = bits2f(E_f[(size_t)fpar*DD + d]);
            }
            #pragma unroll
            for (int ms = 0; ms < 2; ms++){
                float fs0, fs1;
                #pragma unroll
                for (int r = 0; r < 4; r++){
                    float ef = efv[ms][r>>1];
                    float fc = sigm(ef + bfv + hacc[ms][r]) * cv[ms][r];
                    if (r == 0) fs0 = fc;
                    else if (r == 1) fs0 += fc;
                    else if (r == 2) fs1 = fc;
                    else fs1 += fc;
                }
                int lr = ms*8 + q*2;
                fcP[outb][lr*FPAD + d]     = f2bits(fs0);
                fcP[outb][(lr+1)*FPAD + d] = f2bits(fs1);
            }
            __syncthreads();   // carry buffers ready for next level
        }
    }
}

// ---------------- final: bilinear combine + MLP (proven epilogue) ----------------
__global__ __launch_bounds__(256)
void k_final(const u16* __restrict__ hroot,
             const float* __restrict__ fc1w, const float* __restrict__ fc1b,
             const float* __restrict__ fc2w, const float* __restrict__ fc2b,
             void* __restrict__ out, const int* __restrict__ flag)
{
    int b = blockIdx.x, t = threadIdx.x;
    __shared__ float sprod[DD];
    __shared__ float shb[DD];
    __shared__ float shid[128];
    float hc  = bits2f(hroot[(0*NTREE + b)*DD + t]);
    float ha  = bits2f(hroot[(1*NTREE + b)*DD + t]);
    float hbv = bits2f(hroot[(2*NTREE + b)*DD + t]);
    sprod[t] = hc * ha;
    shb[t]   = hbv;
    __syncthreads();
    for (int s = 128; s > 0; s >>= 1){
        if (t < s) sprod[t] += sprod[t + s];
        __syncthreads();
    }
    float dot = sprod[0];
    if (t < 128){
        float acc = fc1b[t];
        for (int k = 0; k < DD; k++)
            acc = fmaf(dot * shb[k], fc1w[t*DD + k], acc);
        shid[t] = fmaxf(acc, 0.f);
    }
    __syncthreads();
    if (t < 3){
        float acc = fc2b[t];
        for (int j = 0; j < 128; j++)
            acc = fmaf(fc2w[t*128 + j], shid[j], acc);
        float v = fmaxf(acc, 0.f);
        if (flag[0]) ((bf16*)out)[b*3 + t] = __float2bfloat16(v);
        else         ((float*)out)[b*3 + t] = v;
    }
}

extern "C" void kernel_launch(void* const* d_in, const int* in_sizes, int n_in,
                              void* d_out, int out_size, void* d_ws, size_t ws_size,
                              hipStream_t stream)
{
    const int* f0 = (const int*)d_in[0];
    const int* f1 = (const int*)d_in[1];
    const int* f2 = (const int*)d_in[2];
    // d_in[3..7] static forest metadata — unused (structure compile-time known)
    const void* emb  = d_in[8];
    const void* Wiou = d_in[9];
    const void* biou = d_in[10];
    const void* Uiou = d_in[11];
    const void* Wf   = d_in[12];
    const void* bfv  = d_in[13];
    const void* Uf   = d_in[14];
    const void* fc1w = d_in[15];
    const void* fc1b = d_in[16];
    const void* fc2w = d_in[17];
    const void* fc2b = d_in[18];

    char* base = (char*)d_ws;
    size_t off = 0;
    auto take = [&](size_t bytes) -> char* {
        char* p = base + off;
        off = (off + bytes + 255) & ~(size_t)255;
        return p;
    };
    int*   flag   = (int*)  take(256);
    u16*   embb   = (u16*)  take((size_t)L_EMBP*2);
    u16*   wioub  = (u16*)  take((size_t)L_WIOU*2);
    u16*   uioub  = (u16*)  take((size_t)L_UIOU*2);
    u16*   wfb    = (u16*)  take((size_t)L_WF*2);
    u16*   ufb    = (u16*)  take((size_t)L_UF*2);
    float* biou_f = (float*)take(S_BIOU*4);
    float* bf_f   = (float*)take(S_BF*4);
    float* fc1w_f = (float*)take(S_F1W*4);
    float* fc1b_f = (float*)take(S_F1B*4);
    float* fc2w_f = (float*)take(S_F2W*4);
    float* fc2b_f = (float*)take(S_F2B*4);
    u16*   E4     = (u16*)  take((size_t)VPAD*DD*4*2);     // 20.5 MB packed {i,o,u,f}
    u16*   E_f    = (u16*)  take((size_t)VPAD*DD*2);       // 5.13 MB
    u16*   H0     = (u16*)  take((size_t)VPAD*DD*2);
    u16*   C0     = (u16*)  take((size_t)VPAD*DD*2);
    u16*   HU0    = (u16*)  take((size_t)VPAD*DD*2);
    u16*   HA     = (u16*)  take((size_t)24576*DD*2);
    u16*   HB     = (u16*)  take((size_t)12288*DD*2);
    u16*   FA     = (u16*)  take((size_t)24576*DD*2);
    u16*   FB     = (u16*)  take((size_t)12288*DD*2);
    u16*   hroot  = (u16*)  take((size_t)NRUNS*NTREE*DD*2);
    // total ~85 MB (< proven 119 MB)

    k_detect<<<1, 256, 0, stream>>>((const u16*)emb, flag);
    k_cvtb<<<2048, 256, 0, stream>>>(emb, Wiou, Uiou, Wf, Uf,
                                     embb, wioub, uioub, wfb, ufb, flag);
    k_small<<<135, 256, 0, stream>>>(biou, bfv, fc1w, fc1b, fc2w, fc2b,
                                     biou_f, bf_f, fc1w_f, fc1b_f, fc2w_f, fc2b_f, flag);
    k_vocab2<<<VPAD/32, 512, 0, stream>>>(embb, wioub, wfb, ufb, biou_f,
                                          E4, E_f, H0, C0, HU0);
    k_edge0<<<24576*32/512, 512, 0, stream>>>(f0, f1, f2, E_f, H0, C0, HU0, bf_f, HA, FA);

    for (int lvl = 1; lvl <= 3; lvl++){
        int cLog = 7 - lvl;
        int rows = NRUNS*NTREE*(128 >> lvl);
        int blocks = rows / 32;
        int pe = lvl & 1;
        u16* hs_o = pe ? HB : HA;
        u16* fc_o = pe ? FB : FA;
        const u16* hs_i = pe ? HA : HB;
        const u16* fc_i = pe ? FA : FB;
        k_lvl<<<blocks, 512, 0, stream>>>(lvl, cLog, f0, f1, f2,
                                          E4, E_f, uioub, ufb,
                                          biou_f, bf_f,
                                          hs_i, fc_i, hs_o, fc_o, hroot);
    }
    // lvl3 (pe=1) wrote HB/FB -> k_tail consumes them for lvl4..7
    k_tail<<<(NRUNS*NTREE)/4, 1024, 0, stream>>>(f0, f1, f2, E4, E_f, uioub, ufb,
                                                 biou_f, bf_f, HB, FB, hroot);
    k_final<<<NTREE, 256, 0, stream>>>(hroot, fc1w_f, fc1b_f, fc2w_f, fc2b_f, d_out, flag);
}

// Round 12
// 419.126 us; speedup vs baseline: 1.1089x; 1.0052x over previous
//
#include <hip/hip_runtime.h>
#include <hip/hip_bf16.h>

typedef __hip_bfloat16 bf16;
typedef unsigned short u16;
typedef __attribute__((ext_vector_type(8))) short s8;   // 8 bf16 = one MFMA A/B fragment
typedef __attribute__((ext_vector_type(4))) float f4;   // MFMA C/D fragment

#define NRUNS 3
#define NTREE 128
#define TT    255
#define DD    256
#define VPAD  10016    /* vocab padded to 32 */
#define PAD   258      /* LDS row stride in u16 for 256-wide rows */
#define OPAD  264      /* output-staging stride: uint4-aligned (528B), bank-staggered */
#define FPAD  264      /* fcP carry stride in k_tail (528B breaks 512B bank aliasing) */

__device__ __forceinline__ float bits2f(u16 b){ union{unsigned u; float f;} x; x.u = ((unsigned)b)<<16; return x.f; }
__device__ __forceinline__ u16   f2bits(float f){ bf16 h = __float2bfloat16(f); return *(u16*)&h; }
__device__ __forceinline__ float sigm(float x){ return 1.f/(1.f+__expf(-x)); }
__device__ __forceinline__ float tanh_(float x){ return 1.f - 2.f/(__expf(2.f*x)+1.f); }

// ---------------- dtype autodetect (proven) ----------------
__global__ void k_detect(const u16* __restrict__ raw, int* __restrict__ flag){
    int t = threadIdx.x;
    int hit = 0;
    if (t < 128){
        u16 w = raw[2*t];
        int e = (w >> 7) & 0xFF;
        hit = (e >= 100 && e <= 141) ? 1 : 0;
    }
    __shared__ int cnt;
    if (t == 0) cnt = 0;
    __syncthreads();
    atomicAdd(&cnt, hit);
    __syncthreads();
    if (t == 0) flag[0] = (cnt >= 64) ? 1 : 0;
}

__device__ __forceinline__ u16 cvt1b(const void* p, int i, int isb){
    return isb ? ((const u16*)p)[i] : f2bits(((const float*)p)[i]);
}
__device__ __forceinline__ float cvt1f(const void* p, int i, int isb){
    return isb ? bits2f(((const u16*)p)[i]) : ((const float*)p)[i];
}

// fused any->bf16 conversion: emb (zero-padded to VPAD rows) + 4 weights
#define L_EMB  (10000*256)
#define L_EMBP (VPAD*256)
#define L_WIOU (768*256)
#define L_UIOU (768*256)
#define L_WF   (256*256)
#define L_UF   (256*256)
#define L_ALL  (L_EMBP + L_WIOU + L_UIOU + L_WF + L_UF)
__global__ void k_cvtb(const void* __restrict__ s0, const void* __restrict__ s1,
                       const void* __restrict__ s2, const void* __restrict__ s3,
                       const void* __restrict__ s4,
                       u16* __restrict__ d0, u16* __restrict__ d1, u16* __restrict__ d2,
                       u16* __restrict__ d3, u16* __restrict__ d4,
                       const int* __restrict__ flag){
    int isb = flag[0];
    for (int i = blockIdx.x*blockDim.x + threadIdx.x; i < L_ALL; i += gridDim.x*blockDim.x){
        int j = i;
        if (j < L_EMBP){ d0[j] = (j < L_EMB) ? cvt1b(s0, j, isb) : (u16)0; continue; } j -= L_EMBP;
        if (j < L_WIOU){ d1[j] = cvt1b(s1, j, isb); continue; } j -= L_WIOU;
        if (j < L_UIOU){ d2[j] = cvt1b(s2, j, isb); continue; } j -= L_UIOU;
        if (j < L_WF){ d3[j] = cvt1b(s3, j, isb); continue; } j -= L_WF;
        d4[j] = cvt1b(s4, j, isb);
    }
}

// fused any->f32 conversion of biases + FC weights
#define S_BIOU 768
#define S_BF   256
#define S_F1W  (128*256)
#define S_F1B  128
#define S_F2W  (3*128)
#define S_F2B  3
#define S_ALL  (S_BIOU+S_BF+S_F1W+S_F1B+S_F2W+S_F2B)
__global__ void k_small(const void* __restrict__ s0, const void* __restrict__ s1,
                        const void* __restrict__ s2, const void* __restrict__ s3,
                        const void* __restrict__ s4, const void* __restrict__ s5,
                        float* __restrict__ d0, float* __restrict__ d1, float* __restrict__ d2,
                        float* __restrict__ d3, float* __restrict__ d4, float* __restrict__ d5,
                        const int* __restrict__ flag){
    int isb = flag[0];
    for (int i = blockIdx.x*blockDim.x + threadIdx.x; i < S_ALL; i += gridDim.x*blockDim.x){
        int j = i;
        if (j < S_BIOU){ d0[j] = cvt1f(s0, j, isb); continue; } j -= S_BIOU;
        if (j < S_BF){ d1[j] = cvt1f(s1, j, isb); continue; } j -= S_BF;
        if (j < S_F1W){ d2[j] = cvt1f(s2, j, isb); continue; } j -= S_F1W;
        if (j < S_F1B){ d3[j] = cvt1f(s3, j, isb); continue; } j -= S_F1B;
        if (j < S_F2W){ d4[j] = cvt1f(s4, j, isb); continue; } j -= S_F2W;
        d5[j] = cvt1f(s5, j, isb);
    }
}

__device__ __forceinline__ s8 ldB16(const u16* p){
    union { uint4 q; s8 v; } u;
    u.q = *(const uint4*)p;
    return u.v;
}
__device__ __forceinline__ s8 ldsA(const u16* p){
    union { unsigned w[4]; s8 v; } u;
    u.w[0] = *(const unsigned*)(p);
    u.w[1] = *(const unsigned*)(p+2);
    u.w[2] = *(const unsigned*)(p+4);
    u.w[3] = *(const unsigned*)(p+6);
    return u.v;
}
#define MFMA(acc,a,b) acc = __builtin_amdgcn_mfma_f32_16x16x32_bf16(a, b, acc, 0, 0, 0)

// ---------------- vocab-space precompute (packed E4[vocab][256][4] = {i,o,u,f}) ----------------
__global__ __launch_bounds__(512, 4)
void k_vocab2(const u16* __restrict__ embb,
              const u16* __restrict__ Wiou, const u16* __restrict__ Wfm,
              const u16* __restrict__ Ufm,  const float* __restrict__ biou_f,
              u16* __restrict__ E4, u16* __restrict__ E_f,
              u16* __restrict__ H0, u16* __restrict__ C0, u16* __restrict__ HU0)
{
    __shared__ u16 hs[32*PAD];    // h0 for the HU0 GEMM
    const int t = threadIdx.x, w = t>>6, lane = t&63, ln = lane&15, q = lane>>4;
    const int r0 = blockIdx.x*32, d0 = w*32;

    const u16* Bp[8];
    #pragma unroll
    for (int g = 0; g < 4; g++)
      #pragma unroll
      for (int nc = 0; nc < 2; nc++){
        int nn = d0 + nc*16 + ln;
        Bp[g*2+nc] = (g < 3) ? (Wiou + (size_t)(g*256+nn)*DD) : (Wfm + (size_t)nn*DD);
      }
    const u16* a0p = embb + (size_t)(r0+ln)*DD;
    const u16* a1p = embb + (size_t)(r0+16+ln)*DD;
    f4 acc[8][2];
    #pragma unroll
    for (int nt = 0; nt < 8; nt++){ acc[nt][0] = (f4){0,0,0,0}; acc[nt][1] = (f4){0,0,0,0}; }
    #pragma unroll 2
    for (int ks = 0; ks < 8; ks++){
        int ko = ks*32 + q*8;
        s8 a0 = ldB16(a0p + ko);
        s8 a1 = ldB16(a1p + ko);
        #pragma unroll
        for (int nt = 0; nt < 8; nt++){
            s8 bb = ldB16(Bp[nt] + ko);
            MFMA(acc[nt][0], a0, bb);
            MFMA(acc[nt][1], a1, bb);
        }
    }
    #pragma unroll
    for (int nc = 0; nc < 2; nc++){
        int d = d0 + nc*16 + ln;
        float bi = biou_f[d], bo = biou_f[256+d], bu = biou_f[512+d];
        #pragma unroll
        for (int ms = 0; ms < 2; ms++)
          #pragma unroll
          for (int r = 0; r < 4; r++){
            int vrow = r0 + ms*16 + q*4 + r;
            float ei = acc[0*2+nc][ms][r];
            float eo = acc[1*2+nc][ms][r];
            float eu = acc[2*2+nc][ms][r];
            float ef = acc[3*2+nc][ms][r];
            union { u16 a[4]; uint2 q2; } pk;
            pk.a[0] = f2bits(ei);
            pk.a[1] = f2bits(eo);
            pk.a[2] = f2bits(eu);
            pk.a[3] = f2bits(ef);
            *(uint2*)(E4 + ((size_t)vrow*DD + d)*4) = pk.q2;
            E_f[(size_t)vrow*DD + d] = f2bits(ef);
            float cc = sigm(ei + bi)*tanh_(eu + bu);
            float hh = sigm(eo + bo)*tanh_(cc);
            C0[(size_t)vrow*DD + d] = f2bits(cc);
            H0[(size_t)vrow*DD + d] = f2bits(hh);
            hs[(ms*16 + q*4 + r)*PAD + d] = f2bits(hh);
        }
    }
    __syncthreads();

    f4 hacc[2][2];
    #pragma unroll
    for (int nt = 0; nt < 2; nt++){ hacc[nt][0] = (f4){0,0,0,0}; hacc[nt][1] = (f4){0,0,0,0}; }
    const u16* Bf0 = Ufm + (size_t)(d0 + ln)*DD;
    const u16* Bf1 = Ufm + (size_t)(d0 + 16 + ln)*DD;
    #pragma unroll 2
    for (int ks = 0; ks < 8; ks++){
        int ko = ks*32 + q*8;
        s8 a0 = ldsA(&hs[ln*PAD + ko]);
        s8 a1 = ldsA(&hs[(16+ln)*PAD + ko]);
        s8 b0 = ldB16(Bf0 + ko);
        s8 b1 = ldB16(Bf1 + ko);
        MFMA(hacc[0][0], a0, b0); MFMA(hacc[0][1], a1, b0);
        MFMA(hacc[1][0], a0, b1); MFMA(hacc[1][1], a1, b1);
    }
    #pragma unroll
    for (int nc = 0; nc < 2; nc++){
        int d = d0 + nc*16 + ln;
        #pragma unroll
        for (int ms = 0; ms < 2; ms++)
          #pragma unroll
          for (int r = 0; r < 4; r++){
            int vrow = r0 + ms*16 + q*4 + r;
            HU0[(size_t)vrow*DD + d] = f2bits(hacc[nc][ms][r]);
        }
    }
}

// ---------------- k_edge0: assemble lvl-1 inputs from vocab tables (proven) ----------------
__global__ __launch_bounds__(512, 4)
void k_edge0(const int* __restrict__ f0, const int* __restrict__ f1, const int* __restrict__ f2,
             const u16* __restrict__ E_f, const u16* __restrict__ H0,
             const u16* __restrict__ C0,  const u16* __restrict__ HU0,
             const float* __restrict__ bf_f,
             u16* __restrict__ hsum_out, u16* __restrict__ fcsum_out)
{
    int gid = blockIdx.x*512 + threadIdx.x;
    int row = gid >> 5, ch = gid & 31, d = ch*8;
    int run = row >> 13, rem = row & 8191, b = rem >> 6, jj = rem & 63;
    const int* fp = (run==0) ? f0 : ((run==1) ? f1 : f2);
    int fo = fp[b*TT + 128 + jj];
    int v1 = fp[b*TT + 2*jj];
    int v2 = fp[b*TT + 2*jj + 1];
    s8 ef  = ldB16(E_f + (size_t)fo*DD + d);
    s8 hu1 = ldB16(HU0 + (size_t)v1*DD + d);
    s8 hu2 = ldB16(HU0 + (size_t)v2*DD + d);
    s8 c1  = ldB16(C0  + (size_t)v1*DD + d);
    s8 c2  = ldB16(C0  + (size_t)v2*DD + d);
    s8 h1  = ldB16(H0  + (size_t)v1*DD + d);
    s8 h2  = ldB16(H0  + (size_t)v2*DD + d);
    union { u16 a[8]; uint4 q4; } uh, uf;
    #pragma unroll
    for (int j = 0; j < 8; j++){
        float e  = bits2f((u16)ef[j]) + bf_f[d+j];
        float fa = sigm(e + bits2f((u16)hu1[j]));
        float fb = sigm(e + bits2f((u16)hu2[j]));
        float fc = fa*bits2f((u16)c1[j]) + fb*bits2f((u16)c2[j]);
        float hsv = bits2f((u16)h1[j]) + bits2f((u16)h2[j]);
        uf.a[j] = f2bits(fc);
        uh.a[j] = f2bits(hsv);
    }
    *(uint4*)(hsum_out  + (size_t)row*DD + d) = uh.q4;
    *(uint4*)(fcsum_out + (size_t)row*DD + d) = uf.q4;
}

// ---------------- per-level kernel (v6 == R5 proven: 81us lvl-1, VGPR 64) ----------------
__global__ __launch_bounds__(512, 4)
void k_lvl(int lvl, int cLog,
           const int* __restrict__ f0, const int* __restrict__ f1, const int* __restrict__ f2,
           const u16* __restrict__ E4, const u16* __restrict__ E_f,
           const u16* __restrict__ Uiou, const u16* __restrict__ Ufm,
           const float* __restrict__ biou_f, const float* __restrict__ bf_f,
           const u16* __restrict__ hsum_in, const u16* __restrict__ fcsum_in,
           u16* __restrict__ hsum_out, u16* __restrict__ fcsum_out,
           u16* __restrict__ hroot)
{
    __shared__ u16 hs[32*PAD];     // 16.5 KB: h transpose for GEMM-C
    __shared__ u16 hso[16*OPAD];   // 8.4 KB: staged hsum_out rows
    __shared__ u16 fco[16*OPAD];   // 8.4 KB: staged fcsum_out rows
    __shared__ int sfr[32];        // this block's 32 node feats (epilogue E4 rows)
    const int t = threadIdx.x, w = t>>6, lane = t&63, ln = lane&15, q = lane>>4;
    const int cnt = 1 << cLog, S = 256 - 2*cnt;
    const int r0 = blockIdx.x*32, d0 = w*32;
    const bool haveP = (lvl < 7);

    // ---- stage this block's 32 node feats into LDS (128 B) ----
    if (t < 32){
        int rho = r0 + t;
        int run = rho >> (7+cLog);
        int rem = rho & ((1<<(7+cLog)) - 1);
        int b = rem >> cLog, jj = rem & (cnt-1);
        const int* fp = (run==0) ? f0 : ((run==1) ? f1 : f2);
        sfr[t] = fp[b*TT + S + jj];
    }

    // parent feats for GEMM-C epilogue
    int featp[2][2];
    if (haveP){
        #pragma unroll
        for (int ms = 0; ms < 2; ms++)
          #pragma unroll
          for (int rr = 0; rr < 2; rr++){
            int rho = r0 + ms*16 + q*4 + rr*2;
            int run = rho >> (7+cLog);
            int rem = rho & ((1<<(7+cLog)) - 1);
            int b = rem >> cLog, jj = rem & (cnt-1);
            const int* fp = (run==0) ? f0 : ((run==1) ? f1 : f2);
            featp[ms][rr] = fp[b*TT + (256-cnt) + (jj>>1)];
          }
    }
    __syncthreads();   // sfr visible to all

    // ---- GEMM-U: hsum_in @ Uiou^T ----
    f4 acc[6][2];
    #pragma unroll
    for (int nt = 0; nt < 6; nt++){ acc[nt][0] = (f4){0,0,0,0}; acc[nt][1] = (f4){0,0,0,0}; }
    {
        const u16* a0p = hsum_in + (size_t)(r0+ln)*DD;
        const u16* a1p = hsum_in + (size_t)(r0+16+ln)*DD;
        const u16* Bp[6];
        #pragma unroll
        for (int nt = 0; nt < 6; nt++){
            int n = (nt>>1)*256 + d0 + (nt&1)*16 + ln;
            Bp[nt] = Uiou + (size_t)n*DD;
        }
        #pragma unroll 2
        for (int ks = 0; ks < 8; ks++){
            int ko = ks*32 + q*8;
            s8 a0 = ldB16(a0p + ko);
            s8 a1 = ldB16(a1p + ko);
            #pragma unroll
            for (int nt = 0; nt < 6; nt++){
                s8 bb = ldB16(Bp[nt] + ko);
                MFMA(acc[nt][0], a0, bb);
                MFMA(acc[nt][1], a1, bb);
            }
        }
    }

    // ---- epilogue: cell update with packed E4 read (one uint2/thread/iter) ----
    float cv[2][2][4];
    #pragma unroll
    for (int nc = 0; nc < 2; nc++){
        int d = d0 + nc*16 + ln;
        float bi = biou_f[d], bo = biou_f[256+d], bu = biou_f[512+d];
        #pragma unroll
        for (int ms = 0; ms < 2; ms++){
            float hv[4];
            #pragma unroll
            for (int r = 0; r < 4; r++){
                int m   = ms*16 + q*4 + r;
                int rho = r0 + m;
                union { uint2 q2; u16 a[4]; } ev;
                ev.q2 = *(const uint2*)(E4 + ((size_t)sfr[m]*DD + d)*4);
                float iv = acc[0+nc][ms][r] + bits2f(ev.a[0]) + bi;
                float ov = acc[2+nc][ms][r] + bits2f(ev.a[1]) + bo;
                float uv = acc[4+nc][ms][r] + bits2f(ev.a[2]) + bu;
                float cs = bits2f(fcsum_in[(size_t)rho*DD + d]);
                float c = sigm(iv)*tanh_(uv) + cs;
                float h = sigm(ov)*tanh_(c);
                cv[nc][ms][r] = c;
                hv[r] = h;
                if (haveP) hs[m*PAD + d] = f2bits(h);
                else       hroot[(size_t)rho*DD + d] = f2bits(h);
            }
            if (haveP){
                int lr = ms*8 + q*2;
                hso[lr*OPAD + d]     = f2bits(hv[0] + hv[1]);
                hso[(lr+1)*OPAD + d] = f2bits(hv[2] + hv[3]);
            }
        }
    }

    // ---- GEMM-C: hU = h@Uf^T, fc = sig(E_f[parent]+bf+hU)*c, pair-reduce ----
    if (haveP){
        __syncthreads();
        f4 hacc[2][2];
        #pragma unroll
        for (int nt = 0; nt < 2; nt++){ hacc[nt][0] = (f4){0,0,0,0}; hacc[nt][1] = (f4){0,0,0,0}; }
        const u16* Bf0 = Ufm + (size_t)(d0 + ln)*DD;
        const u16* Bf1 = Ufm + (size_t)(d0 + 16 + ln)*DD;
        #pragma unroll 2
        for (int ks = 0; ks < 8; ks++){
            int ko = ks*32 + q*8;
            s8 a0 = ldsA(&hs[ln*PAD + ko]);
            s8 a1 = ldsA(&hs[(16+ln)*PAD + ko]);
            s8 b0 = ldB16(Bf0 + ko);
            s8 b1 = ldB16(Bf1 + ko);
            MFMA(hacc[0][0], a0, b0); MFMA(hacc[0][1], a1, b0);
            MFMA(hacc[1][0], a0, b1); MFMA(hacc[1][1], a1, b1);
        }
        #pragma unroll
        for (int nc = 0; nc < 2; nc++){
            int d = d0 + nc*16 + ln;
            float bfv = bf_f[d];
            #pragma unroll
            for (int ms = 0; ms < 2; ms++){
                float fs0, fs1;
                #pragma unroll
                for (int r = 0; r < 4; r++){
                    float ef = bits2f(E_f[(size_t)featp[ms][r>>1]*DD + d]);
                    float fc = sigm(ef + bfv + hacc[nc][ms][r]) * cv[nc][ms][r];
                    if (r == 0) fs0 = fc;
                    else if (r == 1) fs0 += fc;
                    else if (r == 2) fs1 = fc;
                    else fs1 += fc;
                }
                int lr = ms*8 + q*2;
                fco[lr*OPAD + d]     = f2bits(fs0);
                fco[(lr+1)*OPAD + d] = f2bits(fs1);
            }
        }

        // ---- single coalesced write pass: full 128B lines, written once ----
        __syncthreads();
        {
            int row = t >> 5, c = (t & 31) * 8;
            int prow = (r0 >> 1) + row;
            uint4 vh = *(const uint4*)&hso[row*OPAD + c];
            uint4 vf = *(const uint4*)&fco[row*OPAD + c];
            *(uint4*)(hsum_out  + (size_t)prow*DD + c) = vh;
            *(uint4*)(fcsum_out + (size_t)prow*DD + c) = vf;
        }
    }
}

// ---------------- k_tail: levels 4..7 fused, merged-GEMM phases ----------------
// R10 post-mortem: doubling intra-block TLP (16 waves) gained 3% -- waves are
// lock-stepped by barriers, so the cost is the SERIAL PHASE STRUCTURE, not
// per-wave latency. R11: GEMM-C(l) and GEMM-U(l+1) both depend only on epi(l)
// (hs and hsP resp.) -> merge them into ONE fused MFMA phase per level (5 LDS
// A-loads + 4 B-loads + 8 MFMA per k-step). E4 gathers for epi(l+1) and E_f
// gathers for fc(l) are issued in the same phase; the barrier's vmcnt(0) drain
// completes them under the MFMAs (cannot be sunk past the barrier). cv carries
// in registers across the barrier. Chain per level: {U||C} -> epi (2 segments,
// was 3). Double-buffering no longer needed (all hazards barrier-separated):
// LDS 84 -> 50 KB.
__global__ __launch_bounds__(1024, 4)
void k_tail(const int* __restrict__ f0, const int* __restrict__ f1, const int* __restrict__ f2,
            const u16* __restrict__ E4, const u16* __restrict__ E_f,
            const u16* __restrict__ Uiou, const u16* __restrict__ Ufm,
            const float* __restrict__ biou_f, const float* __restrict__ bf_f,
            const u16* __restrict__ hsum_in, const u16* __restrict__ fcsum_in,
            u16* __restrict__ hroot)
{
    __shared__ u16 hs[32*PAD];        // 16.5 KB: h of current level (GEMM-C A-operand)
    __shared__ u16 hsP[32*PAD];       // 16.5 KB: hsum carry (GEMM-U A-operand)
    __shared__ u16 fcP[32*FPAD];      // 16.9 KB: fcsum carry
    __shared__ int sf[64];            // 4 trees x 16 feats (heap slots 240..254)
    const int t = threadIdx.x, w = t>>6, lane = t&63, ln = lane&15, q = lane>>4;
    const int d0 = w*16;              // 16 waves x 16 d-cols = 256
    const int d  = d0 + ln;
    const int r0 = blockIdx.x*32;                 // lvl-4 global row base
    const int run = (blockIdx.x*4) >> 7;          // all 4 trees share one run
    const int* __restrict__ fp = (run==0) ? f0 : ((run==1) ? f1 : f2);

    if (t < 64){
        int ti = t >> 4, idx = t & 15;
        int b = (blockIdx.x*4 + ti) & 127;
        sf[t] = (idx < 15) ? fp[b*TT + 240 + idx] : 0;
    }
    __syncthreads();

    const u16* Bp[3];
    #pragma unroll
    for (int g = 0; g < 3; g++)
        Bp[g] = Uiou + (size_t)(g*256 + d0 + ln)*DD;
    const u16* Bf0 = Ufm + (size_t)(d0 + ln)*DD;

    const float bi = biou_f[d], bo = biou_f[256+d], bu = biou_f[512+d];
    const float bfv = bf_f[d];

    f4 acc[3][2];
    float cv[2][4];

    // ================= prologue: level 4 =================
    #pragma unroll
    for (int nt = 0; nt < 3; nt++){ acc[nt][0] = (f4){0,0,0,0}; acc[nt][1] = (f4){0,0,0,0}; }
    {
        const u16* a0p = hsum_in + (size_t)(r0+ln)*DD;
        const u16* a1p = hsum_in + (size_t)(r0+16+ln)*DD;
        #pragma unroll 2
        for (int ks = 0; ks < 8; ks++){
            int ko = ks*32 + q*8;
            s8 a0 = ldB16(a0p + ko);
            s8 a1 = ldB16(a1p + ko);
            #pragma unroll
            for (int nt = 0; nt < 3; nt++){
                s8 bb = ldB16(Bp[nt] + ko);
                MFMA(acc[nt][0], a0, bb);
                MFMA(acc[nt][1], a1, bb);
            }
        }
    }
    {
        // batched ev/csv for level 4 (nl=8, sh=3, all 32 rows valid)
        uint2 ev[2][4];
        float csv[2][4];
        #pragma unroll
        for (int ms = 0; ms < 2; ms++)
          #pragma unroll
          for (int r = 0; r < 4; r++){
            int m = ms*16 + q*4 + r;
            int fidx = sf[(m>>3)*16 + (m&7)];           // 16-2*8 = 0 offset
            ev[ms][r] = *(const uint2*)(E4 + ((size_t)fidx*DD + d)*4);
            csv[ms][r] = bits2f(fcsum_in[(size_t)(r0+m)*DD + d]);
        }
        // epi(4): write hs + hsP; cv carries to fc(4)
        #pragma unroll
        for (int ms = 0; ms < 2; ms++){
            float hv[4];
            #pragma unroll
            for (int r = 0; r < 4; r++){
                int m = ms*16 + q*4 + r;
                union { uint2 q2; u16 a[4]; } u2;
                u2.q2 = ev[ms][r];
                float iv = acc[0][ms][r] + bits2f(u2.a[0]) + bi;
                float ov = acc[1][ms][r] + bits2f(u2.a[1]) + bo;
                float uv = acc[2][ms][r] + bits2f(u2.a[2]) + bu;
                float c = sigm(iv)*tanh_(uv) + csv[ms][r];
                float h = sigm(ov)*tanh_(c);
                cv[ms][r] = c;
                hv[r] = h;
                hs[m*PAD + d] = f2bits(h);
            }
            int lr = ms*8 + q*2;
            hsP[lr*PAD + d]     = f2bits(hv[0] + hv[1]);
            hsP[(lr+1)*PAD + d] = f2bits(hv[2] + hv[3]);
        }
    }
    __syncthreads();

    // ================= levels 4->5, 5->6, 6->7 =================
    for (int l = 4; l <= 6; l++){
        const int nlc = 128 >> l, nrows_c = 4*nlc, shc = 7 - l;   // level l (GEMM-C side)
        const int nlu = nlc >> 1, nrows_u = 4*nlu, shu = shc - 1; // level l+1 (GEMM-U side)
        const bool lastU = (l == 6);

        // ---- phase 1: fused GEMM-C(l) + GEMM-U(l+1) ----
        f4 hacc[2];
        hacc[0] = (f4){0,0,0,0}; hacc[1] = (f4){0,0,0,0};
        #pragma unroll
        for (int nt = 0; nt < 3; nt++){ acc[nt][0] = (f4){0,0,0,0}; acc[nt][1] = (f4){0,0,0,0}; }
        #pragma unroll 2
        for (int ks = 0; ks < 8; ks++){
            int ko = ks*32 + q*8;
            s8 a0c = ldsA(&hs[ln*PAD + ko]);
            s8 a1c = ldsA(&hs[(16+ln)*PAD + ko]);
            s8 a0u = ldsA(&hsP[ln*PAD + ko]);
            s8 a1u = ldsA(&hsP[(16+ln)*PAD + ko]);
            s8 bfm = ldB16(Bf0 + ko);
            MFMA(hacc[0], a0c, bfm);
            MFMA(hacc[1], a1c, bfm);
            #pragma unroll
            for (int nt = 0; nt < 3; nt++){
                s8 bb = ldB16(Bp[nt] + ko);
                MFMA(acc[nt][0], a0u, bb);
                MFMA(acc[nt][1], a1u, bb);
            }
        }

        // batched E4 gathers for epi(l+1) — complete at the barrier, under the MFMAs
        uint2 ev2[2][4];
        #pragma unroll
        for (int ms = 0; ms < 2; ms++)
          #pragma unroll
          for (int r = 0; r < 4; r++){
            int m = ms*16 + q*4 + r;
            int mc = (m < nrows_u) ? m : 0;
            int ti = mc >> shu, jj = mc & (nlu-1);
            int fidx = sf[ti*16 + (16 - 2*nlu) + jj];
            ev2[ms][r] = *(const uint2*)(E4 + ((size_t)fidx*DD + d)*4);
        }
        // batched E_f gathers for fc(l)
        float efv[2][2];
        #pragma unroll
        for (int ms = 0; ms < 2; ms++)
          #pragma unroll
          for (int rr = 0; rr < 2; rr++){
            int m2 = ms*16 + q*4 + rr*2;
            int mc2 = (m2 < nrows_c) ? m2 : 0;
            int ti2 = mc2 >> shc, jj2 = mc2 & (nlc-1);
            int fpar = sf[ti2*16 + (16 - nlc) + (jj2 >> 1)];
            efv[ms][rr] = bits2f(E_f[(size_t)fpar*DD + d]);
        }
        // fc-epi(l): cv held in registers from epi(l)
        #pragma unroll
        for (int ms = 0; ms < 2; ms++){
            float fs0, fs1;
            #pragma unroll
            for (int r = 0; r < 4; r++){
                float ef = efv[ms][r>>1];
                float fc = sigm(ef + bfv + hacc[ms][r]) * cv[ms][r];
                if (r == 0) fs0 = fc;
                else if (r == 1) fs0 += fc;
                else if (r == 2) fs1 = fc;
                else fs1 += fc;
            }
            int lr = ms*8 + q*2;
            fcP[lr*FPAD + d]     = f2bits(fs0);
            fcP[(lr+1)*FPAD + d] = f2bits(fs1);
        }
        __syncthreads();   // fcP visible; hs/hsP reads done -> epi may overwrite

        // ---- phase 2: epi(l+1) ----
        #pragma unroll
        for (int ms = 0; ms < 2; ms++){
            float hv[4];
            #pragma unroll
            for (int r = 0; r < 4; r++){
                int m = ms*16 + q*4 + r;
                bool vld = (m < nrows_u);
                union { uint2 q2; u16 a[4]; } u2;
                u2.q2 = ev2[ms][r];
                float iv = acc[0][ms][r] + bits2f(u2.a[0]) + bi;
                float ov = acc[1][ms][r] + bits2f(u2.a[1]) + bo;
                float uv = acc[2][ms][r] + bits2f(u2.a[2]) + bu;
                float cs = bits2f(fcP[m*FPAD + d]);
                float c = sigm(iv)*tanh_(uv) + cs;
                float h = sigm(ov)*tanh_(c);
                cv[ms][r] = c;
                hv[r] = h;
                if (!lastU) hs[m*PAD + d] = f2bits(h);
                else if (vld) hroot[(size_t)(blockIdx.x*4 + m)*DD + d] = f2bits(h);
            }
            if (!lastU){
                int lr = ms*8 + q*2;
                hsP[lr*PAD + d]     = f2bits(hv[0] + hv[1]);
                hsP[(lr+1)*PAD + d] = f2bits(hv[2] + hv[3]);
            }
        }
        if (!lastU) __syncthreads();   // hs/hsP visible for next phase 1
    }
}

// ---------------- final: bilinear combine + MLP (proven epilogue) ----------------
__global__ __launch_bounds__(256)
void k_final(const u16* __restrict__ hroot,
             const float* __restrict__ fc1w, const float* __restrict__ fc1b,
             const float* __restrict__ fc2w, const float* __restrict__ fc2b,
             void* __restrict__ out, const int* __restrict__ flag)
{
    int b = blockIdx.x, t = threadIdx.x;
    __shared__ float sprod[DD];
    __shared__ float shb[DD];
    __shared__ float shid[128];
    float hc  = bits2f(hroot[(0*NTREE + b)*DD + t]);
    float ha  = bits2f(hroot[(1*NTREE + b)*DD + t]);
    float hbv = bits2f(hroot[(2*NTREE + b)*DD + t]);
    sprod[t] = hc * ha;
    shb[t]   = hbv;
    __syncthreads();
    for (int s = 128; s > 0; s >>= 1){
        if (t < s) sprod[t] += sprod[t + s];
        __syncthreads();
    }
    float dot = sprod[0];
    if (t < 128){
        float acc = fc1b[t];
        for (int k = 0; k < DD; k++)
            acc = fmaf(dot * shb[k], fc1w[t*DD + k], acc);
        shid[t] = fmaxf(acc, 0.f);
    }
    __syncthreads();
    if (t < 3){
        float acc = fc2b[t];
        for (int j = 0; j < 128; j++)
            acc = fmaf(fc2w[t*128 + j], shid[j], acc);
        float v = fmaxf(acc, 0.f);
        if (flag[0]) ((bf16*)out)[b*3 + t] = __float2bfloat16(v);
        else         ((float*)out)[b*3 + t] = v;
    }
}

extern "C" void kernel_launch(void* const* d_in, const int* in_sizes, int n_in,
                              void* d_out, int out_size, void* d_ws, size_t ws_size,
                              hipStream_t stream)
{
    const int* f0 = (const int*)d_in[0];
    const int* f1 = (const int*)d_in[1];
    const int* f2 = (const int*)d_in[2];
    // d_in[3..7] static forest metadata — unused (structure compile-time known)
    const void* emb  = d_in[8];
    const void* Wiou = d_in[9];
    const void* biou = d_in[10];
    const void* Uiou = d_in[11];
    const void* Wf   = d_in[12];
    const void* bfv  = d_in[13];
    const void* Uf   = d_in[14];
    const void* fc1w = d_in[15];
    const void* fc1b = d_in[16];
    const void* fc2w = d_in[17];
    const void* fc2b = d_in[18];

    char* base = (char*)d_ws;
    size_t off = 0;
    auto take = [&](size_t bytes) -> char* {
        char* p = base + off;
        off = (off + bytes + 255) & ~(size_t)255;
        return p;
    };
    int*   flag   = (int*)  take(256);
    u16*   embb   = (u16*)  take((size_t)L_EMBP*2);
    u16*   wioub  = (u16*)  take((size_t)L_WIOU*2);
    u16*   uioub  = (u16*)  take((size_t)L_UIOU*2);
    u16*   wfb    = (u16*)  take((size_t)L_WF*2);
    u16*   ufb    = (u16*)  take((size_t)L_UF*2);
    float* biou_f = (float*)take(S_BIOU*4);
    float* bf_f   = (float*)take(S_BF*4);
    float* fc1w_f = (float*)take(S_F1W*4);
    float* fc1b_f = (float*)take(S_F1B*4);
    float* fc2w_f = (float*)take(S_F2W*4);
    float* fc2b_f = (float*)take(S_F2B*4);
    u16*   E4     = (u16*)  take((size_t)VPAD*DD*4*2);     // 20.5 MB packed {i,o,u,f}
    u16*   E_f    = (u16*)  take((size_t)VPAD*DD*2);       // 5.13 MB
    u16*   H0     = (u16*)  take((size_t)VPAD*DD*2);
    u16*   C0     = (u16*)  take((size_t)VPAD*DD*2);
    u16*   HU0    = (u16*)  take((size_t)VPAD*DD*2);
    u16*   HA     = (u16*)  take((size_t)24576*DD*2);
    u16*   HB     = (u16*)  take((size_t)12288*DD*2);
    u16*   FA     = (u16*)  take((size_t)24576*DD*2);
    u16*   FB     = (u16*)  take((size_t)12288*DD*2);
    u16*   hroot  = (u16*)  take((size_t)NRUNS*NTREE*DD*2);
    // total ~85 MB (< proven 119 MB)

    k_detect<<<1, 256, 0, stream>>>((const u16*)emb, flag);
    k_cvtb<<<2048, 256, 0, stream>>>(emb, Wiou, Uiou, Wf, Uf,
                                     embb, wioub, uioub, wfb, ufb, flag);
    k_small<<<135, 256, 0, stream>>>(biou, bfv, fc1w, fc1b, fc2w, fc2b,
                                     biou_f, bf_f, fc1w_f, fc1b_f, fc2w_f, fc2b_f, flag);
    k_vocab2<<<VPAD/32, 512, 0, stream>>>(embb, wioub, wfb, ufb, biou_f,
                                          E4, E_f, H0, C0, HU0);
    k_edge0<<<24576*32/512, 512, 0, stream>>>(f0, f1, f2, E_f, H0, C0, HU0, bf_f, HA, FA);

    for (int lvl = 1; lvl <= 3; lvl++){
        int cLog = 7 - lvl;
        int rows = NRUNS*NTREE*(128 >> lvl);
        int blocks = rows / 32;
        int pe = lvl & 1;
        u16* hs_o = pe ? HB : HA;
        u16* fc_o = pe ? FB : FA;
        const u16* hs_i = pe ? HA : HB;
        const u16* fc_i = pe ? FA : FB;
        k_lvl<<<blocks, 512, 0, stream>>>(lvl, cLog, f0, f1, f2,
                                          E4, E_f, uioub, ufb,
                                          biou_f, bf_f,
                                          hs_i, fc_i, hs_o, fc_o, hroot);
    }
    // lvl3 (pe=1) wrote HB/FB -> k_tail consumes them for lvl4..7
    k_tail<<<(NRUNS*NTREE)/4, 1024, 0, stream>>>(f0, f1, f2, E4, E_f, uioub, ufb,
                                                 biou_f, bf_f, HB, FB, hroot);
    k_final<<<NTREE, 256, 0, stream>>>(hroot, fc1w_f, fc1b_f, fc2w_f, fc2b_f, d_out, flag);
}